// Round 1
// baseline (1604.403 us; speedup 1.0000x reference)
//
#include <hip/hip_runtime.h>
#include <cstdint>

#define N_NODES 50000
#define N_EDGES 1600000
#define HDIM 128
#define L_LAYERS 4
#define BN_EPS 1e-5f

// ---------------- mask layout detection ----------------
// jax bool may arrive as uint8 (1B/elem) or int32 (4B/elem). If uint8, reading
// the first 12500 words packs 4 bools/word -> some word > 1 almost surely
// (P ~ 1 - 1e-2000). If int32, all words are exactly 0 or 1.
__global__ void detect_mask_kernel(const uint32_t* __restrict__ mw, int* __restrict__ flag) {
    __shared__ int f;
    if (threadIdx.x == 0) f = 0;
    __syncthreads();
    int found = 0;
    for (int i = threadIdx.x; i < 12500; i += blockDim.x)
        if (mw[i] > 1u) found = 1;
    if (found) f = 1;
    __syncthreads();
    if (threadIdx.x == 0) *flag = f;
}

__device__ __forceinline__ int read_mask(const void* mask, int i, int bytelayout) {
    if (bytelayout) return ((const unsigned char*)mask)[i] != 0;
    return ((const int*)mask)[i] != 0;
}

// ---------------- embed: h = (mask? token : x) @ W + b ----------------
__global__ void embed_kernel(const float* __restrict__ x, const void* __restrict__ mask,
                             const int* __restrict__ flag, const float* __restrict__ tok,
                             const float* __restrict__ W, const float* __restrict__ b,
                             float* __restrict__ h) {
    int idx = blockIdx.x * blockDim.x + threadIdx.x;
    if (idx >= N_NODES * HDIM) return;
    int i = idx >> 7, c = idx & 127;
    int fl = *flag;
    int m = read_mask(mask, i, fl);
    float x0 = m ? tok[0] : x[i * 3 + 0];
    float x1 = m ? tok[1] : x[i * 3 + 1];
    float x2 = m ? tok[2] : x[i * 3 + 2];
    h[idx] = x0 * W[c] + x1 * W[HDIM + c] + x2 * W[2 * HDIM + c] + b[c];
}

// ---------------- CSR build ----------------
__global__ void deg_kernel(const int* __restrict__ dst, int* __restrict__ deg) {
    int e = blockIdx.x * blockDim.x + threadIdx.x;
    if (e < N_EDGES) atomicAdd(&deg[dst[e]], 1);
}

// single-block exclusive scan of deg[0..N) -> rowptr, also writes cursor copy.
__global__ __launch_bounds__(1024) void scan_kernel(int* __restrict__ rowptr,
                                                    int* __restrict__ cursor) {
    __shared__ int sums[1024];
    const int CH = (N_NODES + 1023) >> 10;  // 49
    int t = threadIdx.x;
    int lo = t * CH, hi = min(lo + CH, N_NODES);
    int s = 0;
    for (int i = lo; i < hi; ++i) s += rowptr[i];
    sums[t] = s;
    __syncthreads();
    for (int o = 1; o < 1024; o <<= 1) {
        int v = (t >= o) ? sums[t - o] : 0;
        __syncthreads();
        sums[t] += v;
        __syncthreads();
    }
    int run = sums[t] - s;  // exclusive prefix
    for (int i = lo; i < hi; ++i) {
        int d = rowptr[i];
        rowptr[i] = run;
        cursor[i] = run;
        run += d;
    }
    if (t == 1023) rowptr[N_NODES] = sums[1023];
}

__global__ void fill_kernel(const int* __restrict__ src, const int* __restrict__ dst,
                            int* __restrict__ cursor, int* __restrict__ col) {
    int e = blockIdx.x * blockDim.x + threadIdx.x;
    if (e < N_EDGES) {
        int pos = atomicAdd(&cursor[dst[e]], 1);
        col[pos] = src[e];
    }
}

// ---------------- aggregation: z[i] = h[i] + sum_{j in N(i)} h[j] ----------------
// one wave per node; lane owns channels (2*lane, 2*lane+1)
__global__ __launch_bounds__(256) void agg_kernel(const float* __restrict__ h,
                                                  const int* __restrict__ rowptr,
                                                  const int* __restrict__ col,
                                                  float* __restrict__ z) {
    int wid = __builtin_amdgcn_readfirstlane((int)(threadIdx.x >> 6));
    int lane = threadIdx.x & 63;
    int i = blockIdx.x * 4 + wid;
    if (i >= N_NODES) return;
    int start = rowptr[i], end = rowptr[i + 1];
    float2 acc = *(const float2*)&h[(size_t)i * HDIM + 2 * lane];
    for (int base = start; base < end; base += 64) {
        int e = base + lane;
        int jv = (e < end) ? col[e] : 0;
        int cnt = min(end - base, 64);
        for (int t = 0; t < cnt; ++t) {
            int j = __builtin_amdgcn_readlane(jv, t);
            float2 v = *(const float2*)&h[(size_t)j * HDIM + 2 * lane];
            acc.x += v.x;
            acc.y += v.y;
        }
    }
    *(float2*)&z[(size_t)i * HDIM + 2 * lane] = acc;
}

// ---------------- fp32 tiled GEMM: C = [relu](A[N,K] @ W[K,NCOLS] + b) ----------------
template <int K, int NCOLS, bool RELU>
__global__ __launch_bounds__(256) void gemm_kernel(const float* __restrict__ A,
                                                   const float* __restrict__ W,
                                                   const float* __restrict__ bias,
                                                   float* __restrict__ C, int nrows) {
    __shared__ float Alds[16][68];  // [k][row], padded
    __shared__ float Wlds[16][68];  // [k][col], padded
    const int t = threadIdx.x;
    const int tx = t & 15, ty = t >> 4;
    const int row0 = blockIdx.y * 64;
    const int col0 = blockIdx.x * 64;
    float acc[4][4] = {};
    for (int k0 = 0; k0 < K; k0 += 16) {
        {
            int e = t * 4;
            int r = e >> 4, kk = e & 15;  // A tile 64 rows x 16 k
            int row = row0 + r;
            float4 v = make_float4(0.f, 0.f, 0.f, 0.f);
            if (row < nrows) v = *(const float4*)&A[(size_t)row * K + k0 + kk];
            Alds[kk + 0][r] = v.x;
            Alds[kk + 1][r] = v.y;
            Alds[kk + 2][r] = v.z;
            Alds[kk + 3][r] = v.w;
            int kw = e >> 6, cw = e & 63;  // W tile 16 k x 64 cols
            *(float4*)&Wlds[kw][cw] = *(const float4*)&W[(size_t)(k0 + kw) * NCOLS + col0 + cw];
        }
        __syncthreads();
#pragma unroll
        for (int kk = 0; kk < 16; ++kk) {
            const float4 a = *(const float4*)&Alds[kk][ty * 4];
            const float4 w = *(const float4*)&Wlds[kk][tx * 4];
            float av[4] = {a.x, a.y, a.z, a.w};
            float wv[4] = {w.x, w.y, w.z, w.w};
#pragma unroll
            for (int i2 = 0; i2 < 4; ++i2)
#pragma unroll
                for (int j = 0; j < 4; ++j) acc[i2][j] = fmaf(av[i2], wv[j], acc[i2][j]);
        }
        __syncthreads();
    }
    const float4 bv = *(const float4*)&bias[col0 + tx * 4];
    float bvv[4] = {bv.x, bv.y, bv.z, bv.w};
#pragma unroll
    for (int i2 = 0; i2 < 4; ++i2) {
        int row = row0 + ty * 4 + i2;
        if (row < nrows) {
            float o[4];
#pragma unroll
            for (int j = 0; j < 4; ++j) {
                o[j] = acc[i2][j] + bvv[j];
                if (RELU) o[j] = fmaxf(o[j], 0.f);
            }
            *(float4*)&C[(size_t)row * NCOLS + col0 + tx * 4] = make_float4(o[0], o[1], o[2], o[3]);
        }
    }
}

// ---------------- BatchNorm ----------------
__global__ void bnstats_kernel(const float* __restrict__ z, float* __restrict__ stats) {
    int c = threadIdx.x & 127;
    int r0 = blockIdx.x * 2 + (threadIdx.x >> 7);
    float s = 0.f, ss = 0.f;
    for (int r = r0; r < N_NODES; r += gridDim.x * 2) {
        float v = z[(size_t)r * HDIM + c];
        s += v;
        ss += v * v;
    }
    atomicAdd(&stats[c], s);
    atomicAdd(&stats[HDIM + c], ss);
}

__global__ void bnfin_kernel(const float* __restrict__ stats, const float* __restrict__ gamma,
                             const float* __restrict__ beta, float* __restrict__ sc) {
    int c = threadIdx.x;
    float mean = stats[c] * (1.f / N_NODES);
    float var = stats[HDIM + c] * (1.f / N_NODES) - mean * mean;
    float rstd = rsqrtf(fmaxf(var, 0.f) + BN_EPS);
    float s = gamma[c] * rstd;
    sc[c] = s;
    sc[HDIM + c] = beta[c] - mean * s;
}

__global__ void bnapply_kernel(const float* __restrict__ z, const float* __restrict__ sc,
                               float* __restrict__ h) {
    int idx = blockIdx.x * blockDim.x + threadIdx.x;
    if (idx >= N_NODES * HDIM) return;
    int c = idx & 127;
    h[idx] = fmaxf(z[idx] * sc[c] + sc[HDIM + c], 0.f);
}

// ---------------- decoder stage2 + loss ----------------
// one wave per node: recon[i] = d1[i] @ W2[128,3] + b2 ; loss accumulation
__global__ __launch_bounds__(256) void dec2_loss_kernel(
    const float* __restrict__ d1, const float* __restrict__ W2, const float* __restrict__ b2,
    const float* __restrict__ x, const void* __restrict__ mask, const int* __restrict__ flag,
    float* __restrict__ recon, float* __restrict__ acc) {
    int wid = __builtin_amdgcn_readfirstlane((int)(threadIdx.x >> 6));
    int lane = threadIdx.x & 63;
    int i = blockIdx.x * 4 + wid;
    if (i >= N_NODES) return;
    float a0 = d1[(size_t)i * HDIM + lane];
    float a1 = d1[(size_t)i * HDIM + 64 + lane];
    float s0 = a0 * W2[lane * 3 + 0] + a1 * W2[(lane + 64) * 3 + 0];
    float s1 = a0 * W2[lane * 3 + 1] + a1 * W2[(lane + 64) * 3 + 1];
    float s2 = a0 * W2[lane * 3 + 2] + a1 * W2[(lane + 64) * 3 + 2];
    for (int o = 32; o > 0; o >>= 1) {
        s0 += __shfl_down(s0, o);
        s1 += __shfl_down(s1, o);
        s2 += __shfl_down(s2, o);
    }
    if (lane == 0) {
        float r0 = s0 + b2[0], r1 = s1 + b2[1], r2 = s2 + b2[2];
        recon[(size_t)i * 3 + 0] = r0;
        recon[(size_t)i * 3 + 1] = r1;
        recon[(size_t)i * 3 + 2] = r2;
        if (read_mask(mask, i, *flag)) {
            float rn = fmaxf(sqrtf(r0 * r0 + r1 * r1 + r2 * r2), 1e-12f);
            float x0 = x[i * 3 + 0], x1 = x[i * 3 + 1], x2 = x[i * 3 + 2];
            float xn = fmaxf(sqrtf(x0 * x0 + x1 * x1 + x2 * x2), 1e-12f);
            float cs = (r0 * x0 + r1 * x1 + r2 * x2) / (rn * xn);
            float d = 1.f - cs;
            atomicAdd(&acc[0], d * d);
            atomicAdd(&acc[1], 1.f);
        }
    }
}

__global__ void finalize_kernel(const float* __restrict__ acc, float* __restrict__ out) {
    out[0] = acc[0] / fmaxf(acc[1], 1.f);
}

// ---------------- launcher ----------------
extern "C" void kernel_launch(void* const* d_in, const int* in_sizes, int n_in, void* d_out,
                              int out_size, void* d_ws, size_t ws_size, hipStream_t stream) {
    const float* x = (const float*)d_in[0];
    const int* ei = (const int*)d_in[1];
    const int* src = ei;
    const int* dst = ei + N_EDGES;
    const void* mask = d_in[3];
    const float* tok = (const float*)d_in[4];
    const float* eW = (const float*)d_in[5];
    const float* eb = (const float*)d_in[6];
    const float* W1 = (const float*)d_in[7];
    const float* b1 = (const float*)d_in[8];
    const float* W2 = (const float*)d_in[9];
    const float* b2 = (const float*)d_in[10];
    const float* gm = (const float*)d_in[11];
    const float* bt = (const float*)d_in[12];
    const float* dW1 = (const float*)d_in[13];
    const float* db1 = (const float*)d_in[14];
    const float* dW2 = (const float*)d_in[15];
    const float* db2 = (const float*)d_in[16];
    float* out = (float*)d_out;

    char* ws = (char*)d_ws;
    size_t off = 0;
    auto alloc = [&](size_t bytes) -> void* {
        void* p = ws + off;
        off = (off + bytes + 255) & ~(size_t)255;
        return p;
    };
    float* h = (float*)alloc((size_t)N_NODES * HDIM * 4);
    float* zin = (float*)alloc((size_t)N_NODES * HDIM * 4);
    float* z1 = (float*)alloc((size_t)N_NODES * 2 * HDIM * 4);
    int* rowptr = (int*)alloc((size_t)(N_NODES + 1) * 4);
    int* cursor = (int*)alloc((size_t)N_NODES * 4);
    int* col = (int*)alloc((size_t)N_EDGES * 4);
    float* stats = (float*)alloc(2 * HDIM * 4);
    float* sc = (float*)alloc(2 * HDIM * 4);
    float* lacc = (float*)alloc(8);
    int* flag = (int*)alloc(4);

    detect_mask_kernel<<<1, 256, 0, stream>>>((const uint32_t*)mask, flag);
    embed_kernel<<<(N_NODES * HDIM + 255) / 256, 256, 0, stream>>>(x, mask, flag, tok, eW, eb, h);

    hipMemsetAsync(rowptr, 0, (size_t)(N_NODES + 1) * 4, stream);
    deg_kernel<<<(N_EDGES + 255) / 256, 256, 0, stream>>>(dst, rowptr);
    scan_kernel<<<1, 1024, 0, stream>>>(rowptr, cursor);
    fill_kernel<<<(N_EDGES + 255) / 256, 256, 0, stream>>>(src, dst, cursor, col);

    for (int l = 0; l < L_LAYERS; ++l) {
        agg_kernel<<<(N_NODES + 3) / 4, 256, 0, stream>>>(h, rowptr, col, zin);
        gemm_kernel<128, 256, true><<<dim3(4, 782), 256, 0, stream>>>(
            zin, W1 + (size_t)l * HDIM * 2 * HDIM, b1 + (size_t)l * 2 * HDIM, z1, N_NODES);
        gemm_kernel<256, 128, false><<<dim3(2, 782), 256, 0, stream>>>(
            z1, W2 + (size_t)l * 2 * HDIM * HDIM, b2 + (size_t)l * HDIM, zin, N_NODES);
        hipMemsetAsync(stats, 0, 2 * HDIM * 4, stream);
        bnstats_kernel<<<256, 256, 0, stream>>>(zin, stats);
        bnfin_kernel<<<1, 128, 0, stream>>>(stats, gm + l * HDIM, bt + l * HDIM, sc);
        bnapply_kernel<<<(N_NODES * HDIM + 255) / 256, 256, 0, stream>>>(zin, sc, h);
    }

    gemm_kernel<128, 128, true><<<dim3(2, 782), 256, 0, stream>>>(h, dW1, db1, z1, N_NODES);
    hipMemsetAsync(lacc, 0, 8, stream);
    dec2_loss_kernel<<<(N_NODES + 3) / 4, 256, 0, stream>>>(z1, dW2, db2, x, mask, flag, out + 1,
                                                            lacc);
    finalize_kernel<<<1, 1, 0, stream>>>(lacc, out);
}

// Round 2
// 1499.156 us; speedup vs baseline: 1.0702x; 1.0702x over previous
//
#include <hip/hip_runtime.h>
#include <cstdint>

#define N_NODES 50000
#define N_EDGES 1600000
#define HDIM 128
#define L_LAYERS 4
#define BN_EPS 1e-5f

// ---------------- mask layout detection ----------------
// jax bool may arrive as uint8 (1B/elem) or int32 (4B/elem). If uint8, reading
// the first 12500 words packs 4 bools/word -> some word > 1 almost surely.
// If int32, all words are exactly 0 or 1.
__global__ void detect_mask_kernel(const uint32_t* __restrict__ mw, int* __restrict__ flag) {
    __shared__ int f;
    if (threadIdx.x == 0) f = 0;
    __syncthreads();
    int found = 0;
    for (int i = threadIdx.x; i < 12500; i += blockDim.x)
        if (mw[i] > 1u) found = 1;
    if (found) f = 1;
    __syncthreads();
    if (threadIdx.x == 0) *flag = f;
}

__device__ __forceinline__ int read_mask(const void* mask, int i, int bytelayout) {
    if (bytelayout) return ((const unsigned char*)mask)[i] != 0;
    return ((const int*)mask)[i] != 0;
}

// ---------------- embed: h = (mask? token : x) @ W + b ----------------
__global__ void embed_kernel(const float* __restrict__ x, const void* __restrict__ mask,
                             const int* __restrict__ flag, const float* __restrict__ tok,
                             const float* __restrict__ W, const float* __restrict__ b,
                             float* __restrict__ h) {
    int idx = blockIdx.x * blockDim.x + threadIdx.x;
    if (idx >= N_NODES * HDIM) return;
    int i = idx >> 7, c = idx & 127;
    int fl = *flag;
    int m = read_mask(mask, i, fl);
    float x0 = m ? tok[0] : x[i * 3 + 0];
    float x1 = m ? tok[1] : x[i * 3 + 1];
    float x2 = m ? tok[2] : x[i * 3 + 2];
    h[idx] = x0 * W[c] + x1 * W[HDIM + c] + x2 * W[2 * HDIM + c] + b[c];
}

// ---------------- CSR build ----------------
__global__ void deg_kernel(const int* __restrict__ dst, int* __restrict__ deg) {
    int e = blockIdx.x * blockDim.x + threadIdx.x;
    if (e < N_EDGES) atomicAdd(&deg[dst[e]], 1);
}

// single-block exclusive scan of deg[0..N) -> rowptr, also writes cursor copy.
__global__ __launch_bounds__(1024) void scan_kernel(int* __restrict__ rowptr,
                                                    int* __restrict__ cursor) {
    __shared__ int sums[1024];
    const int CH = (N_NODES + 1023) >> 10;  // 49
    int t = threadIdx.x;
    int lo = t * CH, hi = min(lo + CH, N_NODES);
    int s = 0;
    for (int i = lo; i < hi; ++i) s += rowptr[i];
    sums[t] = s;
    __syncthreads();
    for (int o = 1; o < 1024; o <<= 1) {
        int v = (t >= o) ? sums[t - o] : 0;
        __syncthreads();
        sums[t] += v;
        __syncthreads();
    }
    int run = sums[t] - s;  // exclusive prefix
    for (int i = lo; i < hi; ++i) {
        int d = rowptr[i];
        rowptr[i] = run;
        cursor[i] = run;
        run += d;
    }
    if (t == 1023) rowptr[N_NODES] = sums[1023];
}

__global__ void fill_kernel(const int* __restrict__ src, const int* __restrict__ dst,
                            int* __restrict__ cursor, int* __restrict__ col) {
    int e = blockIdx.x * blockDim.x + threadIdx.x;
    if (e < N_EDGES) {
        int pos = atomicAdd(&cursor[dst[e]], 1);
        col[pos] = src[e];
    }
}

// ---------------- aggregation: z[i] = h[i] + sum_{j in N(i)} h[j] ----------------
// one wave per node; lane owns channels (2*lane, 2*lane+1)
__global__ __launch_bounds__(256) void agg_kernel(const float* __restrict__ h,
                                                  const int* __restrict__ rowptr,
                                                  const int* __restrict__ col,
                                                  float* __restrict__ z) {
    int wid = __builtin_amdgcn_readfirstlane((int)(threadIdx.x >> 6));
    int lane = threadIdx.x & 63;
    int i = blockIdx.x * 4 + wid;
    if (i >= N_NODES) return;
    int start = rowptr[i], end = rowptr[i + 1];
    float2 acc = *(const float2*)&h[(size_t)i * HDIM + 2 * lane];
    for (int base = start; base < end; base += 64) {
        int e = base + lane;
        int jv = (e < end) ? col[e] : 0;
        int cnt = min(end - base, 64);
        for (int t = 0; t < cnt; ++t) {
            int j = __builtin_amdgcn_readlane(jv, t);
            float2 v = *(const float2*)&h[(size_t)j * HDIM + 2 * lane];
            acc.x += v.x;
            acc.y += v.y;
        }
    }
    *(float2*)&z[(size_t)i * HDIM + 2 * lane] = acc;
}

// ---------------- fp32 tiled GEMM: C = [relu](A[N,K] @ W[K,NCOLS] + b) ----------------
template <int K, int NCOLS, bool RELU>
__global__ __launch_bounds__(256) void gemm_kernel(const float* __restrict__ A,
                                                   const float* __restrict__ W,
                                                   const float* __restrict__ bias,
                                                   float* __restrict__ C, int nrows) {
    __shared__ float Alds[16][68];  // [k][row], padded
    __shared__ float Wlds[16][68];  // [k][col], padded
    const int t = threadIdx.x;
    const int tx = t & 15, ty = t >> 4;
    const int row0 = blockIdx.y * 64;
    const int col0 = blockIdx.x * 64;
    float acc[4][4] = {};
    for (int k0 = 0; k0 < K; k0 += 16) {
        {
            int e = t * 4;
            int r = e >> 4, kk = e & 15;  // A tile 64 rows x 16 k
            int row = row0 + r;
            float4 v = make_float4(0.f, 0.f, 0.f, 0.f);
            if (row < nrows) v = *(const float4*)&A[(size_t)row * K + k0 + kk];
            Alds[kk + 0][r] = v.x;
            Alds[kk + 1][r] = v.y;
            Alds[kk + 2][r] = v.z;
            Alds[kk + 3][r] = v.w;
            int kw = e >> 6, cw = e & 63;  // W tile 16 k x 64 cols
            *(float4*)&Wlds[kw][cw] = *(const float4*)&W[(size_t)(k0 + kw) * NCOLS + col0 + cw];
        }
        __syncthreads();
#pragma unroll
        for (int kk = 0; kk < 16; ++kk) {
            const float4 a = *(const float4*)&Alds[kk][ty * 4];
            const float4 w = *(const float4*)&Wlds[kk][tx * 4];
            float av[4] = {a.x, a.y, a.z, a.w};
            float wv[4] = {w.x, w.y, w.z, w.w};
#pragma unroll
            for (int i2 = 0; i2 < 4; ++i2)
#pragma unroll
                for (int j = 0; j < 4; ++j) acc[i2][j] = fmaf(av[i2], wv[j], acc[i2][j]);
        }
        __syncthreads();
    }
    const float4 bv = *(const float4*)&bias[col0 + tx * 4];
    float bvv[4] = {bv.x, bv.y, bv.z, bv.w};
#pragma unroll
    for (int i2 = 0; i2 < 4; ++i2) {
        int row = row0 + ty * 4 + i2;
        if (row < nrows) {
            float o[4];
#pragma unroll
            for (int j = 0; j < 4; ++j) {
                o[j] = acc[i2][j] + bvv[j];
                if (RELU) o[j] = fmaxf(o[j], 0.f);
            }
            *(float4*)&C[(size_t)row * NCOLS + col0 + tx * 4] = make_float4(o[0], o[1], o[2], o[3]);
        }
    }
}

// ---------------- BatchNorm ----------------
__global__ void bnstats_kernel(const float* __restrict__ z, float* __restrict__ stats) {
    int c = threadIdx.x & 127;
    int r0 = blockIdx.x * 2 + (threadIdx.x >> 7);
    float s = 0.f, ss = 0.f;
    for (int r = r0; r < N_NODES; r += gridDim.x * 2) {
        float v = z[(size_t)r * HDIM + c];
        s += v;
        ss += v * v;
    }
    atomicAdd(&stats[c], s);
    atomicAdd(&stats[HDIM + c], ss);
}

__global__ void bnfin_kernel(const float* __restrict__ stats, const float* __restrict__ gamma,
                             const float* __restrict__ beta, float* __restrict__ sc) {
    int c = threadIdx.x;
    float mean = stats[c] * (1.f / N_NODES);
    float var = stats[HDIM + c] * (1.f / N_NODES) - mean * mean;
    float rstd = rsqrtf(fmaxf(var, 0.f) + BN_EPS);
    float s = gamma[c] * rstd;
    sc[c] = s;
    sc[HDIM + c] = beta[c] - mean * s;
}

__global__ void bnapply_kernel(const float* __restrict__ z, const float* __restrict__ sc,
                               float* __restrict__ h) {
    int idx = blockIdx.x * blockDim.x + threadIdx.x;
    if (idx >= N_NODES * HDIM) return;
    int c = idx & 127;
    h[idx] = fmaxf(z[idx] * sc[c] + sc[HDIM + c], 0.f);
}

// ---------------- decoder stage2 + loss ----------------
// grid-stride waves: each wave handles many nodes (ILP), loss accumulated in
// registers, <=2 atomics per wave at the end (spread, no same-address storm).
__global__ __launch_bounds__(256) void dec2_loss_kernel(
    const float* __restrict__ d1, const float* __restrict__ W2, const float* __restrict__ b2,
    const float* __restrict__ x, const void* __restrict__ mask, const int* __restrict__ flag,
    float* __restrict__ recon, float* __restrict__ acc) {
    int lane = threadIdx.x & 63;
    int wid = threadIdx.x >> 6;
    int gwave = blockIdx.x * 4 + wid;
    int nwaves = gridDim.x * 4;
    int fl = *flag;
    // preload W2 rows for this lane's two channels (lane, lane+64)
    float w00 = W2[lane * 3 + 0], w01 = W2[lane * 3 + 1], w02 = W2[lane * 3 + 2];
    float w10 = W2[(lane + 64) * 3 + 0], w11 = W2[(lane + 64) * 3 + 1],
          w12 = W2[(lane + 64) * 3 + 2];
    float bb0 = b2[0], bb1 = b2[1], bb2 = b2[2];
    float lsum = 0.f, lcnt = 0.f;
    for (int i = gwave; i < N_NODES; i += nwaves) {
        float a0 = d1[(size_t)i * HDIM + lane];
        float a1 = d1[(size_t)i * HDIM + 64 + lane];
        float s0 = a0 * w00 + a1 * w10;
        float s1 = a0 * w01 + a1 * w11;
        float s2 = a0 * w02 + a1 * w12;
#pragma unroll
        for (int o = 32; o > 0; o >>= 1) {
            s0 += __shfl_xor(s0, o);
            s1 += __shfl_xor(s1, o);
            s2 += __shfl_xor(s2, o);
        }
        float r0 = s0 + bb0, r1 = s1 + bb1, r2 = s2 + bb2;
        if (lane < 3) recon[(size_t)i * 3 + lane] = (lane == 0) ? r0 : ((lane == 1) ? r1 : r2);
        if (lane == 0 && read_mask(mask, i, fl)) {
            float rn = fmaxf(sqrtf(r0 * r0 + r1 * r1 + r2 * r2), 1e-12f);
            float x0 = x[i * 3 + 0], x1 = x[i * 3 + 1], x2 = x[i * 3 + 2];
            float xn = fmaxf(sqrtf(x0 * x0 + x1 * x1 + x2 * x2), 1e-12f);
            float cs = (r0 * x0 + r1 * x1 + r2 * x2) / (rn * xn);
            float d = 1.f - cs;
            lsum += d * d;
            lcnt += 1.f;
        }
    }
    if (lane == 0 && lcnt != 0.f) {
        atomicAdd(&acc[0], lsum);
        atomicAdd(&acc[1], lcnt);
    }
}

__global__ void finalize_kernel(const float* __restrict__ acc, float* __restrict__ out) {
    out[0] = acc[0] / fmaxf(acc[1], 1.f);
}

// ---------------- launcher ----------------
extern "C" void kernel_launch(void* const* d_in, const int* in_sizes, int n_in, void* d_out,
                              int out_size, void* d_ws, size_t ws_size, hipStream_t stream) {
    const float* x = (const float*)d_in[0];
    const int* ei = (const int*)d_in[1];
    const int* src = ei;
    const int* dst = ei + N_EDGES;
    const void* mask = d_in[3];
    const float* tok = (const float*)d_in[4];
    const float* eW = (const float*)d_in[5];
    const float* eb = (const float*)d_in[6];
    const float* W1 = (const float*)d_in[7];
    const float* b1 = (const float*)d_in[8];
    const float* W2 = (const float*)d_in[9];
    const float* b2 = (const float*)d_in[10];
    const float* gm = (const float*)d_in[11];
    const float* bt = (const float*)d_in[12];
    const float* dW1 = (const float*)d_in[13];
    const float* db1 = (const float*)d_in[14];
    const float* dW2 = (const float*)d_in[15];
    const float* db2 = (const float*)d_in[16];
    float* out = (float*)d_out;

    char* ws = (char*)d_ws;
    size_t off = 0;
    auto alloc = [&](size_t bytes) -> void* {
        void* p = ws + off;
        off = (off + bytes + 255) & ~(size_t)255;
        return p;
    };
    float* h = (float*)alloc((size_t)N_NODES * HDIM * 4);
    float* zin = (float*)alloc((size_t)N_NODES * HDIM * 4);
    float* z1 = (float*)alloc((size_t)N_NODES * 2 * HDIM * 4);
    int* rowptr = (int*)alloc((size_t)(N_NODES + 1) * 4);
    int* cursor = (int*)alloc((size_t)N_NODES * 4);
    int* col = (int*)alloc((size_t)N_EDGES * 4);
    float* stats = (float*)alloc(2 * HDIM * 4);
    float* sc = (float*)alloc(2 * HDIM * 4);
    float* lacc = (float*)alloc(8);
    int* flag = (int*)alloc(4);

    detect_mask_kernel<<<1, 256, 0, stream>>>((const uint32_t*)mask, flag);
    embed_kernel<<<(N_NODES * HDIM + 255) / 256, 256, 0, stream>>>(x, mask, flag, tok, eW, eb, h);

    hipMemsetAsync(rowptr, 0, (size_t)(N_NODES + 1) * 4, stream);
    deg_kernel<<<(N_EDGES + 255) / 256, 256, 0, stream>>>(dst, rowptr);
    scan_kernel<<<1, 1024, 0, stream>>>(rowptr, cursor);
    fill_kernel<<<(N_EDGES + 255) / 256, 256, 0, stream>>>(src, dst, cursor, col);

    for (int l = 0; l < L_LAYERS; ++l) {
        agg_kernel<<<(N_NODES + 3) / 4, 256, 0, stream>>>(h, rowptr, col, zin);
        gemm_kernel<128, 256, true><<<dim3(4, 782), 256, 0, stream>>>(
            zin, W1 + (size_t)l * HDIM * 2 * HDIM, b1 + (size_t)l * 2 * HDIM, z1, N_NODES);
        gemm_kernel<256, 128, false><<<dim3(2, 782), 256, 0, stream>>>(
            z1, W2 + (size_t)l * 2 * HDIM * HDIM, b2 + (size_t)l * HDIM, zin, N_NODES);
        hipMemsetAsync(stats, 0, 2 * HDIM * 4, stream);
        bnstats_kernel<<<256, 256, 0, stream>>>(zin, stats);
        bnfin_kernel<<<1, 128, 0, stream>>>(stats, gm + l * HDIM, bt + l * HDIM, sc);
        bnapply_kernel<<<(N_NODES * HDIM + 255) / 256, 256, 0, stream>>>(zin, sc, h);
    }

    gemm_kernel<128, 128, true><<<dim3(2, 782), 256, 0, stream>>>(h, dW1, db1, z1, N_NODES);
    hipMemsetAsync(lacc, 0, 8, stream);
    dec2_loss_kernel<<<1024, 256, 0, stream>>>(z1, dW2, db2, x, mask, flag, out + 1, lacc);
    finalize_kernel<<<1, 1, 0, stream>>>(lacc, out);
}

// Round 3
// 1472.035 us; speedup vs baseline: 1.0899x; 1.0184x over previous
//
#include <hip/hip_runtime.h>
#include <cstdint>

#define N_NODES 50000
#define N_EDGES 1600000
#define HDIM 128
#define L_LAYERS 4
#define BN_EPS 1e-5f

// ---------------- mask layout detection ----------------
// jax bool may arrive as uint8 (1B/elem) or int32 (4B/elem). If uint8, reading
// the first 12500 words packs 4 bools/word -> some word > 1 almost surely.
// If int32, all words are exactly 0 or 1.
__global__ void detect_mask_kernel(const uint32_t* __restrict__ mw, int* __restrict__ flag) {
    __shared__ int f;
    if (threadIdx.x == 0) f = 0;
    __syncthreads();
    int found = 0;
    for (int i = threadIdx.x; i < 12500; i += blockDim.x)
        if (mw[i] > 1u) found = 1;
    if (found) f = 1;
    __syncthreads();
    if (threadIdx.x == 0) *flag = f;
}

__device__ __forceinline__ int read_mask(const void* mask, int i, int bytelayout) {
    if (bytelayout) return ((const unsigned char*)mask)[i] != 0;
    return ((const int*)mask)[i] != 0;
}

// ---------------- embed: h = (mask? token : x) @ W + b ----------------
__global__ void embed_kernel(const float* __restrict__ x, const void* __restrict__ mask,
                             const int* __restrict__ flag, const float* __restrict__ tok,
                             const float* __restrict__ W, const float* __restrict__ b,
                             float* __restrict__ h) {
    int idx = blockIdx.x * blockDim.x + threadIdx.x;
    if (idx >= N_NODES * HDIM) return;
    int i = idx >> 7, c = idx & 127;
    int fl = *flag;
    int m = read_mask(mask, i, fl);
    float x0 = m ? tok[0] : x[i * 3 + 0];
    float x1 = m ? tok[1] : x[i * 3 + 1];
    float x2 = m ? tok[2] : x[i * 3 + 2];
    h[idx] = x0 * W[c] + x1 * W[HDIM + c] + x2 * W[2 * HDIM + c] + b[c];
}

// ---------------- CSR build ----------------
__global__ void deg_kernel(const int* __restrict__ dst, int* __restrict__ deg) {
    int e = blockIdx.x * blockDim.x + threadIdx.x;
    if (e < N_EDGES) atomicAdd(&deg[dst[e]], 1);
}

// single-block exclusive scan of deg[0..N) -> rowptr, also writes cursor copy.
__global__ __launch_bounds__(1024) void scan_kernel(int* __restrict__ rowptr,
                                                    int* __restrict__ cursor) {
    __shared__ int sums[1024];
    const int CH = (N_NODES + 1023) >> 10;  // 49
    int t = threadIdx.x;
    int lo = t * CH, hi = min(lo + CH, N_NODES);
    int s = 0;
    for (int i = lo; i < hi; ++i) s += rowptr[i];
    sums[t] = s;
    __syncthreads();
    for (int o = 1; o < 1024; o <<= 1) {
        int v = (t >= o) ? sums[t - o] : 0;
        __syncthreads();
        sums[t] += v;
        __syncthreads();
    }
    int run = sums[t] - s;  // exclusive prefix
    for (int i = lo; i < hi; ++i) {
        int d = rowptr[i];
        rowptr[i] = run;
        cursor[i] = run;
        run += d;
    }
    if (t == 1023) rowptr[N_NODES] = sums[1023];
}

__global__ void fill_kernel(const int* __restrict__ src, const int* __restrict__ dst,
                            int* __restrict__ cursor, int* __restrict__ col) {
    int e = blockIdx.x * blockDim.x + threadIdx.x;
    if (e < N_EDGES) {
        int pos = atomicAdd(&cursor[dst[e]], 1);
        col[pos] = src[e];
    }
}

// ---------------- aggregation: z[i] = h[i] + sum_{j in N(i)} h[j] ----------------
// one wave per node; lane owns channels (2*lane, 2*lane+1).
// col[e] is wave-uniform -> broadcast load (no readlane). Unroll x4 with
// independent accumulators: 4 outstanding 512B gathers per wave.
__global__ __launch_bounds__(256) void agg_kernel(const float* __restrict__ h,
                                                  const int* __restrict__ rowptr,
                                                  const int* __restrict__ col,
                                                  float* __restrict__ z) {
    int wid = threadIdx.x >> 6;
    int lane = threadIdx.x & 63;
    int i = blockIdx.x * 4 + wid;
    if (i >= N_NODES) return;
    int start = rowptr[i], end = rowptr[i + 1];
    const size_t loff = 2 * lane;
    float2 a0 = *(const float2*)&h[(size_t)i * HDIM + loff];
    float2 a1 = make_float2(0.f, 0.f);
    float2 a2 = make_float2(0.f, 0.f);
    float2 a3 = make_float2(0.f, 0.f);
    int e = start;
    for (; e + 4 <= end; e += 4) {
        int j0 = col[e + 0];
        int j1 = col[e + 1];
        int j2 = col[e + 2];
        int j3 = col[e + 3];
        float2 v0 = *(const float2*)&h[(size_t)j0 * HDIM + loff];
        float2 v1 = *(const float2*)&h[(size_t)j1 * HDIM + loff];
        float2 v2 = *(const float2*)&h[(size_t)j2 * HDIM + loff];
        float2 v3 = *(const float2*)&h[(size_t)j3 * HDIM + loff];
        a0.x += v0.x;
        a0.y += v0.y;
        a1.x += v1.x;
        a1.y += v1.y;
        a2.x += v2.x;
        a2.y += v2.y;
        a3.x += v3.x;
        a3.y += v3.y;
    }
    for (; e < end; ++e) {
        int j = col[e];
        float2 v = *(const float2*)&h[(size_t)j * HDIM + loff];
        a0.x += v.x;
        a0.y += v.y;
    }
    a0.x += a1.x + a2.x + a3.x;
    a0.y += a1.y + a2.y + a3.y;
    *(float2*)&z[(size_t)i * HDIM + loff] = a0;
}

// ---------------- fp32 tiled GEMM: C = [relu](A[N,K] @ W[K,NCOLS] + b) ----------------
template <int K, int NCOLS, bool RELU>
__global__ __launch_bounds__(256) void gemm_kernel(const float* __restrict__ A,
                                                   const float* __restrict__ W,
                                                   const float* __restrict__ bias,
                                                   float* __restrict__ C, int nrows) {
    __shared__ float Alds[16][68];  // [k][row], padded
    __shared__ float Wlds[16][68];  // [k][col], padded
    const int t = threadIdx.x;
    const int tx = t & 15, ty = t >> 4;
    const int row0 = blockIdx.y * 64;
    const int col0 = blockIdx.x * 64;
    float acc[4][4] = {};
    for (int k0 = 0; k0 < K; k0 += 16) {
        {
            int e = t * 4;
            int r = e >> 4, kk = e & 15;  // A tile 64 rows x 16 k
            int row = row0 + r;
            float4 v = make_float4(0.f, 0.f, 0.f, 0.f);
            if (row < nrows) v = *(const float4*)&A[(size_t)row * K + k0 + kk];
            Alds[kk + 0][r] = v.x;
            Alds[kk + 1][r] = v.y;
            Alds[kk + 2][r] = v.z;
            Alds[kk + 3][r] = v.w;
            int kw = e >> 6, cw = e & 63;  // W tile 16 k x 64 cols
            *(float4*)&Wlds[kw][cw] = *(const float4*)&W[(size_t)(k0 + kw) * NCOLS + col0 + cw];
        }
        __syncthreads();
#pragma unroll
        for (int kk = 0; kk < 16; ++kk) {
            const float4 a = *(const float4*)&Alds[kk][ty * 4];
            const float4 w = *(const float4*)&Wlds[kk][tx * 4];
            float av[4] = {a.x, a.y, a.z, a.w};
            float wv[4] = {w.x, w.y, w.z, w.w};
#pragma unroll
            for (int i2 = 0; i2 < 4; ++i2)
#pragma unroll
                for (int j = 0; j < 4; ++j) acc[i2][j] = fmaf(av[i2], wv[j], acc[i2][j]);
        }
        __syncthreads();
    }
    const float4 bv = *(const float4*)&bias[col0 + tx * 4];
    float bvv[4] = {bv.x, bv.y, bv.z, bv.w};
#pragma unroll
    for (int i2 = 0; i2 < 4; ++i2) {
        int row = row0 + ty * 4 + i2;
        if (row < nrows) {
            float o[4];
#pragma unroll
            for (int j = 0; j < 4; ++j) {
                o[j] = acc[i2][j] + bvv[j];
                if (RELU) o[j] = fmaxf(o[j], 0.f);
            }
            *(float4*)&C[(size_t)row * NCOLS + col0 + tx * 4] = make_float4(o[0], o[1], o[2], o[3]);
        }
    }
}

// ---------------- BatchNorm ----------------
__global__ void bnstats_kernel(const float* __restrict__ z, float* __restrict__ stats) {
    int c = threadIdx.x & 127;
    int r0 = blockIdx.x * 2 + (threadIdx.x >> 7);
    float s = 0.f, ss = 0.f;
    for (int r = r0; r < N_NODES; r += gridDim.x * 2) {
        float v = z[(size_t)r * HDIM + c];
        s += v;
        ss += v * v;
    }
    atomicAdd(&stats[c], s);
    atomicAdd(&stats[HDIM + c], ss);
}

__global__ void bnfin_kernel(const float* __restrict__ stats, const float* __restrict__ gamma,
                             const float* __restrict__ beta, float* __restrict__ sc) {
    int c = threadIdx.x;
    float mean = stats[c] * (1.f / N_NODES);
    float var = stats[HDIM + c] * (1.f / N_NODES) - mean * mean;
    float rstd = rsqrtf(fmaxf(var, 0.f) + BN_EPS);
    float s = gamma[c] * rstd;
    sc[c] = s;
    sc[HDIM + c] = beta[c] - mean * s;
}

__global__ void bnapply_kernel(const float* __restrict__ z, const float* __restrict__ sc,
                               float* __restrict__ h) {
    int idx = blockIdx.x * blockDim.x + threadIdx.x;
    if (idx >= N_NODES * HDIM) return;
    int c = idx & 127;
    h[idx] = fmaxf(z[idx] * sc[c] + sc[HDIM + c], 0.f);
}

// ---------------- decoder stage2 + loss ----------------
// grid-stride waves: each wave handles many nodes (ILP), loss accumulated in
// registers, <=2 atomics per wave at the end.
__global__ __launch_bounds__(256) void dec2_loss_kernel(
    const float* __restrict__ d1, const float* __restrict__ W2, const float* __restrict__ b2,
    const float* __restrict__ x, const void* __restrict__ mask, const int* __restrict__ flag,
    float* __restrict__ recon, float* __restrict__ acc) {
    int lane = threadIdx.x & 63;
    int wid = threadIdx.x >> 6;
    int gwave = blockIdx.x * 4 + wid;
    int nwaves = gridDim.x * 4;
    int fl = *flag;
    float w00 = W2[lane * 3 + 0], w01 = W2[lane * 3 + 1], w02 = W2[lane * 3 + 2];
    float w10 = W2[(lane + 64) * 3 + 0], w11 = W2[(lane + 64) * 3 + 1],
          w12 = W2[(lane + 64) * 3 + 2];
    float bb0 = b2[0], bb1 = b2[1], bb2 = b2[2];
    float lsum = 0.f, lcnt = 0.f;
    for (int i = gwave; i < N_NODES; i += nwaves) {
        float a0 = d1[(size_t)i * HDIM + lane];
        float a1 = d1[(size_t)i * HDIM + 64 + lane];
        float s0 = a0 * w00 + a1 * w10;
        float s1 = a0 * w01 + a1 * w11;
        float s2 = a0 * w02 + a1 * w12;
#pragma unroll
        for (int o = 32; o > 0; o >>= 1) {
            s0 += __shfl_xor(s0, o);
            s1 += __shfl_xor(s1, o);
            s2 += __shfl_xor(s2, o);
        }
        float r0 = s0 + bb0, r1 = s1 + bb1, r2 = s2 + bb2;
        if (lane < 3) recon[(size_t)i * 3 + lane] = (lane == 0) ? r0 : ((lane == 1) ? r1 : r2);
        if (lane == 0 && read_mask(mask, i, fl)) {
            float rn = fmaxf(sqrtf(r0 * r0 + r1 * r1 + r2 * r2), 1e-12f);
            float x0 = x[i * 3 + 0], x1 = x[i * 3 + 1], x2 = x[i * 3 + 2];
            float xn = fmaxf(sqrtf(x0 * x0 + x1 * x1 + x2 * x2), 1e-12f);
            float cs = (r0 * x0 + r1 * x1 + r2 * x2) / (rn * xn);
            float d = 1.f - cs;
            lsum += d * d;
            lcnt += 1.f;
        }
    }
    if (lane == 0 && lcnt != 0.f) {
        atomicAdd(&acc[0], lsum);
        atomicAdd(&acc[1], lcnt);
    }
}

__global__ void finalize_kernel(const float* __restrict__ acc, float* __restrict__ out) {
    out[0] = acc[0] / fmaxf(acc[1], 1.f);
}

// ---------------- launcher ----------------
extern "C" void kernel_launch(void* const* d_in, const int* in_sizes, int n_in, void* d_out,
                              int out_size, void* d_ws, size_t ws_size, hipStream_t stream) {
    const float* x = (const float*)d_in[0];
    const int* ei = (const int*)d_in[1];
    const int* src = ei;
    const int* dst = ei + N_EDGES;
    const void* mask = d_in[3];
    const float* tok = (const float*)d_in[4];
    const float* eW = (const float*)d_in[5];
    const float* eb = (const float*)d_in[6];
    const float* W1 = (const float*)d_in[7];
    const float* b1 = (const float*)d_in[8];
    const float* W2 = (const float*)d_in[9];
    const float* b2 = (const float*)d_in[10];
    const float* gm = (const float*)d_in[11];
    const float* bt = (const float*)d_in[12];
    const float* dW1 = (const float*)d_in[13];
    const float* db1 = (const float*)d_in[14];
    const float* dW2 = (const float*)d_in[15];
    const float* db2 = (const float*)d_in[16];
    float* out = (float*)d_out;

    char* ws = (char*)d_ws;
    size_t off = 0;
    auto alloc = [&](size_t bytes) -> void* {
        void* p = ws + off;
        off = (off + bytes + 255) & ~(size_t)255;
        return p;
    };
    float* h = (float*)alloc((size_t)N_NODES * HDIM * 4);
    float* zin = (float*)alloc((size_t)N_NODES * HDIM * 4);
    float* z1 = (float*)alloc((size_t)N_NODES * 2 * HDIM * 4);
    int* rowptr = (int*)alloc((size_t)(N_NODES + 1) * 4);
    int* cursor = (int*)alloc((size_t)N_NODES * 4);
    int* col = (int*)alloc((size_t)N_EDGES * 4);
    float* stats = (float*)alloc(2 * HDIM * 4);
    float* sc = (float*)alloc(2 * HDIM * 4);
    float* lacc = (float*)alloc(8);
    int* flag = (int*)alloc(4);

    detect_mask_kernel<<<1, 256, 0, stream>>>((const uint32_t*)mask, flag);
    embed_kernel<<<(N_NODES * HDIM + 255) / 256, 256, 0, stream>>>(x, mask, flag, tok, eW, eb, h);

    hipMemsetAsync(rowptr, 0, (size_t)(N_NODES + 1) * 4, stream);
    deg_kernel<<<(N_EDGES + 255) / 256, 256, 0, stream>>>(dst, rowptr);
    scan_kernel<<<1, 1024, 0, stream>>>(rowptr, cursor);
    fill_kernel<<<(N_EDGES + 255) / 256, 256, 0, stream>>>(src, dst, cursor, col);

    for (int l = 0; l < L_LAYERS; ++l) {
        agg_kernel<<<(N_NODES + 3) / 4, 256, 0, stream>>>(h, rowptr, col, zin);
        gemm_kernel<128, 256, true><<<dim3(4, 782), 256, 0, stream>>>(
            zin, W1 + (size_t)l * HDIM * 2 * HDIM, b1 + (size_t)l * 2 * HDIM, z1, N_NODES);
        gemm_kernel<256, 128, false><<<dim3(2, 782), 256, 0, stream>>>(
            z1, W2 + (size_t)l * 2 * HDIM * HDIM, b2 + (size_t)l * HDIM, zin, N_NODES);
        hipMemsetAsync(stats, 0, 2 * HDIM * 4, stream);
        bnstats_kernel<<<256, 256, 0, stream>>>(zin, stats);
        bnfin_kernel<<<1, 128, 0, stream>>>(stats, gm + l * HDIM, bt + l * HDIM, sc);
        bnapply_kernel<<<(N_NODES * HDIM + 255) / 256, 256, 0, stream>>>(zin, sc, h);
    }

    gemm_kernel<128, 128, true><<<dim3(2, 782), 256, 0, stream>>>(h, dW1, db1, z1, N_NODES);
    hipMemsetAsync(lacc, 0, 8, stream);
    dec2_loss_kernel<<<1024, 256, 0, stream>>>(z1, dW2, db2, x, mask, flag, out + 1, lacc);
    finalize_kernel<<<1, 1, 0, stream>>>(lacc, out);
}

// Round 4
// 1138.533 us; speedup vs baseline: 1.4092x; 1.2929x over previous
//
#include <hip/hip_runtime.h>
#include <cstdint>

#define N_NODES 50000
#define N_EDGES 1600000
#define HDIM 128
#define L_LAYERS 4
#define BN_EPS 1e-5f

typedef __attribute__((ext_vector_type(8))) short short8v;
typedef __attribute__((ext_vector_type(4))) float f32x4;

__device__ __forceinline__ unsigned short f2bf(float f) {
    uint32_t u = __builtin_bit_cast(uint32_t, f);
    u += 0x7fff + ((u >> 16) & 1);
    return (unsigned short)(u >> 16);
}
__device__ __forceinline__ float bf2f(unsigned short b) {
    return __builtin_bit_cast(float, (uint32_t)b << 16);
}

// ---------------- mask layout detection ----------------
__global__ void detect_mask_kernel(const uint32_t* __restrict__ mw, int* __restrict__ flag) {
    __shared__ int f;
    if (threadIdx.x == 0) f = 0;
    __syncthreads();
    int found = 0;
    for (int i = threadIdx.x; i < 12500; i += blockDim.x)
        if (mw[i] > 1u) found = 1;
    if (found) f = 1;
    __syncthreads();
    if (threadIdx.x == 0) *flag = f;
}

__device__ __forceinline__ int read_mask(const void* mask, int i, int bytelayout) {
    if (bytelayout) return ((const unsigned char*)mask)[i] != 0;
    return ((const int*)mask)[i] != 0;
}

// ---------------- weight prep: Wt[n][k] = bf16(W[k][n]) ----------------
__global__ void wprep_kernel(const float* __restrict__ W, unsigned short* __restrict__ Wt, int K,
                             int nshift) {
    int idx = blockIdx.x * 256 + threadIdx.x;
    if (idx >= (K << nshift)) return;
    int k = idx >> nshift, n = idx & ((1 << nshift) - 1);
    Wt[n * K + k] = f2bf(W[idx]);
}

// ---------------- embed: h = (mask? token : x) @ W + b  (bf16 out) ----------------
__global__ void embed_kernel(const float* __restrict__ x, const void* __restrict__ mask,
                             const int* __restrict__ flag, const float* __restrict__ tok,
                             const float* __restrict__ W, const float* __restrict__ b,
                             unsigned short* __restrict__ h) {
    int idx = blockIdx.x * blockDim.x + threadIdx.x;
    if (idx >= N_NODES * HDIM) return;
    int i = idx >> 7, c = idx & 127;
    int fl = *flag;
    int m = read_mask(mask, i, fl);
    float x0 = m ? tok[0] : x[i * 3 + 0];
    float x1 = m ? tok[1] : x[i * 3 + 1];
    float x2 = m ? tok[2] : x[i * 3 + 2];
    h[idx] = f2bf(x0 * W[c] + x1 * W[HDIM + c] + x2 * W[2 * HDIM + c] + b[c]);
}

// ---------------- CSR build ----------------
__global__ void deg_kernel(const int* __restrict__ dst, int* __restrict__ deg) {
    int e = blockIdx.x * blockDim.x + threadIdx.x;
    if (e < N_EDGES) atomicAdd(&deg[dst[e]], 1);
}

__global__ __launch_bounds__(1024) void scan_kernel(int* __restrict__ rowptr,
                                                    int* __restrict__ cursor) {
    __shared__ int sums[1024];
    const int CH = (N_NODES + 1023) >> 10;  // 49
    int t = threadIdx.x;
    int lo = t * CH, hi = min(lo + CH, N_NODES);
    int s = 0;
    for (int i = lo; i < hi; ++i) s += rowptr[i];
    sums[t] = s;
    __syncthreads();
    for (int o = 1; o < 1024; o <<= 1) {
        int v = (t >= o) ? sums[t - o] : 0;
        __syncthreads();
        sums[t] += v;
        __syncthreads();
    }
    int run = sums[t] - s;
    for (int i = lo; i < hi; ++i) {
        int d = rowptr[i];
        rowptr[i] = run;
        cursor[i] = run;
        run += d;
    }
    if (t == 1023) rowptr[N_NODES] = sums[1023];
}

// bucketed fill: group g = blockIdx&7 (~XCD) owns dst range [g*6250,(g+1)*6250);
// each group scans all edges -> col writes are contiguous-region-local per group.
__global__ __launch_bounds__(256) void fill_bucket_kernel(const int* __restrict__ src,
                                                          const int* __restrict__ dst,
                                                          int* __restrict__ cursor,
                                                          int* __restrict__ col) {
    int g = blockIdx.x & 7;
    int nb = gridDim.x >> 3;
    int bg = blockIdx.x >> 3;
    int lo = g * (N_NODES / 8), hi = lo + (N_NODES / 8);
    for (int e = bg * 256 + (int)threadIdx.x; e < N_EDGES; e += nb * 256) {
        int d = dst[e];
        if (d >= lo && d < hi) {
            int pos = atomicAdd(&cursor[d], 1);
            col[pos] = src[e];
        }
    }
}

// ---------------- aggregation (bf16 h): z[i] = h[i] + sum_{j} h[j] ----------------
// lane owns channels (2*lane, 2*lane+1) as one packed u32; fp32 accumulate.
__global__ __launch_bounds__(256) void agg_kernel(const unsigned short* __restrict__ h,
                                                  const int* __restrict__ rowptr,
                                                  const int* __restrict__ col,
                                                  unsigned short* __restrict__ z) {
    int wid = threadIdx.x >> 6;
    int lane = threadIdx.x & 63;
    int i = blockIdx.x * 4 + wid;
    if (i >= N_NODES) return;
    int start = rowptr[i], end = rowptr[i + 1];
    const uint32_t* h32 = (const uint32_t*)h;
    uint32_t u = h32[(size_t)i * 64 + lane];
    float ax = __builtin_bit_cast(float, u << 16);
    float ay = __builtin_bit_cast(float, u & 0xffff0000u);
    float bx = 0.f, by = 0.f, cx = 0.f, cy = 0.f, dx = 0.f, dy = 0.f;
    int e = start;
    for (; e + 4 <= end; e += 4) {
        int j0 = col[e + 0], j1 = col[e + 1], j2 = col[e + 2], j3 = col[e + 3];
        uint32_t u0 = h32[(size_t)j0 * 64 + lane];
        uint32_t u1 = h32[(size_t)j1 * 64 + lane];
        uint32_t u2 = h32[(size_t)j2 * 64 + lane];
        uint32_t u3 = h32[(size_t)j3 * 64 + lane];
        ax += __builtin_bit_cast(float, u0 << 16);
        ay += __builtin_bit_cast(float, u0 & 0xffff0000u);
        bx += __builtin_bit_cast(float, u1 << 16);
        by += __builtin_bit_cast(float, u1 & 0xffff0000u);
        cx += __builtin_bit_cast(float, u2 << 16);
        cy += __builtin_bit_cast(float, u2 & 0xffff0000u);
        dx += __builtin_bit_cast(float, u3 << 16);
        dy += __builtin_bit_cast(float, u3 & 0xffff0000u);
    }
    for (; e < end; ++e) {
        uint32_t u0 = h32[(size_t)col[e] * 64 + lane];
        ax += __builtin_bit_cast(float, u0 << 16);
        ay += __builtin_bit_cast(float, u0 & 0xffff0000u);
    }
    ax += bx + cx + dx;
    ay += by + cy + dy;
    uint32_t o = (uint32_t)f2bf(ax) | ((uint32_t)f2bf(ay) << 16);
    ((uint32_t*)z)[(size_t)i * 64 + lane] = o;
}

// ---------------- bf16 MFMA GEMM: C = [relu](A[M,K]bf16 @ Wt[N,K]^T + bias) ----------------
// block = 4 waves; wave w -> rows [by*64+w*16, +16), cols [bx*64, +64) via 4 16x16 frags.
// A-frag & B-frags loaded directly from global (A streams; Wt is L1/L2-resident).
template <int K, bool OUT_BF16, bool RELU>
__global__ __launch_bounds__(256) void mfma_gemm_kernel(const unsigned short* __restrict__ A,
                                                        const unsigned short* __restrict__ Wt,
                                                        const float* __restrict__ bias,
                                                        void* __restrict__ C, int M, int ldc) {
    const int lane = threadIdx.x & 63;
    const int w = threadIdx.x >> 6;
    const int row0 = blockIdx.y * 64 + w * 16;
    const int col0 = blockIdx.x * 64;
    const int r = lane & 15;   // A-row / B-col / D-col within 16
    const int ks = lane >> 4;  // k-segment (8 bf16 each)
    const int arow = min(row0 + r, M - 1);
    f32x4 acc[4];
#pragma unroll
    for (int n = 0; n < 4; ++n) acc[n] = (f32x4){0.f, 0.f, 0.f, 0.f};
#pragma unroll
    for (int k0 = 0; k0 < K; k0 += 32) {
        short8v a = *(const short8v*)&A[(size_t)arow * K + k0 + ks * 8];
#pragma unroll
        for (int n = 0; n < 4; ++n) {
            short8v b = *(const short8v*)&Wt[(size_t)(col0 + n * 16 + r) * K + k0 + ks * 8];
            acc[n] = __builtin_amdgcn_mfma_f32_16x16x32_bf16(a, b, acc[n], 0, 0, 0);
        }
    }
#pragma unroll
    for (int n = 0; n < 4; ++n) {
        const int col = col0 + n * 16 + r;
        const float bv = bias[col];
#pragma unroll
        for (int i = 0; i < 4; ++i) {
            int row = row0 + ks * 4 + i;
            if (row < M) {
                float o = acc[n][i] + bv;
                if (RELU) o = fmaxf(o, 0.f);
                if (OUT_BF16)
                    ((unsigned short*)C)[(size_t)row * ldc + col] = f2bf(o);
                else
                    ((float*)C)[(size_t)row * ldc + col] = o;
            }
        }
    }
}

// ---------------- BatchNorm ----------------
__global__ void bnstats_kernel(const float* __restrict__ z, float* __restrict__ stats) {
    int c = threadIdx.x & 127;
    int r0 = blockIdx.x * 2 + (threadIdx.x >> 7);
    float s = 0.f, ss = 0.f;
    for (int r = r0; r < N_NODES; r += gridDim.x * 2) {
        float v = z[(size_t)r * HDIM + c];
        s += v;
        ss += v * v;
    }
    atomicAdd(&stats[c], s);
    atomicAdd(&stats[HDIM + c], ss);
}

__global__ void bnfin_kernel(const float* __restrict__ stats, const float* __restrict__ gamma,
                             const float* __restrict__ beta, float* __restrict__ sc) {
    int c = threadIdx.x;
    float mean = stats[c] * (1.f / N_NODES);
    float var = stats[HDIM + c] * (1.f / N_NODES) - mean * mean;
    float rstd = rsqrtf(fmaxf(var, 0.f) + BN_EPS);
    float s = gamma[c] * rstd;
    sc[c] = s;
    sc[HDIM + c] = beta[c] - mean * s;
}

// h = relu(z*scale + shift) -> bf16, 4 elems/thread
__global__ void bnapply_kernel(const float* __restrict__ z, const float* __restrict__ sc,
                               unsigned short* __restrict__ h) {
    int idx = blockIdx.x * blockDim.x + threadIdx.x;
    if (idx >= N_NODES * HDIM / 4) return;
    float4 v = ((const float4*)z)[idx];
    int c = (idx * 4) & 127;
    float o0 = fmaxf(v.x * sc[c + 0] + sc[HDIM + c + 0], 0.f);
    float o1 = fmaxf(v.y * sc[c + 1] + sc[HDIM + c + 1], 0.f);
    float o2 = fmaxf(v.z * sc[c + 2] + sc[HDIM + c + 2], 0.f);
    float o3 = fmaxf(v.w * sc[c + 3] + sc[HDIM + c + 3], 0.f);
    uint2 p;
    p.x = (uint32_t)f2bf(o0) | ((uint32_t)f2bf(o1) << 16);
    p.y = (uint32_t)f2bf(o2) | ((uint32_t)f2bf(o3) << 16);
    ((uint2*)h)[idx] = p;
}

// ---------------- decoder stage2 + loss ----------------
__global__ __launch_bounds__(256) void dec2_loss_kernel(
    const unsigned short* __restrict__ d1, const float* __restrict__ W2,
    const float* __restrict__ b2, const float* __restrict__ x, const void* __restrict__ mask,
    const int* __restrict__ flag, float* __restrict__ recon, float* __restrict__ acc) {
    int lane = threadIdx.x & 63;
    int wid = threadIdx.x >> 6;
    int gwave = blockIdx.x * 4 + wid;
    int nwaves = gridDim.x * 4;
    int fl = *flag;
    float w00 = W2[lane * 3 + 0], w01 = W2[lane * 3 + 1], w02 = W2[lane * 3 + 2];
    float w10 = W2[(lane + 64) * 3 + 0], w11 = W2[(lane + 64) * 3 + 1],
          w12 = W2[(lane + 64) * 3 + 2];
    float bb0 = b2[0], bb1 = b2[1], bb2 = b2[2];
    float lsum = 0.f, lcnt = 0.f;
    for (int i = gwave; i < N_NODES; i += nwaves) {
        float a0 = bf2f(d1[(size_t)i * HDIM + lane]);
        float a1 = bf2f(d1[(size_t)i * HDIM + 64 + lane]);
        float s0 = a0 * w00 + a1 * w10;
        float s1 = a0 * w01 + a1 * w11;
        float s2 = a0 * w02 + a1 * w12;
#pragma unroll
        for (int o = 32; o > 0; o >>= 1) {
            s0 += __shfl_xor(s0, o);
            s1 += __shfl_xor(s1, o);
            s2 += __shfl_xor(s2, o);
        }
        float r0 = s0 + bb0, r1 = s1 + bb1, r2 = s2 + bb2;
        if (lane < 3) recon[(size_t)i * 3 + lane] = (lane == 0) ? r0 : ((lane == 1) ? r1 : r2);
        if (lane == 0 && read_mask(mask, i, fl)) {
            float rn = fmaxf(sqrtf(r0 * r0 + r1 * r1 + r2 * r2), 1e-12f);
            float x0 = x[i * 3 + 0], x1 = x[i * 3 + 1], x2 = x[i * 3 + 2];
            float xn = fmaxf(sqrtf(x0 * x0 + x1 * x1 + x2 * x2), 1e-12f);
            float cs = (r0 * x0 + r1 * x1 + r2 * x2) / (rn * xn);
            float d = 1.f - cs;
            lsum += d * d;
            lcnt += 1.f;
        }
    }
    if (lane == 0 && lcnt != 0.f) {
        atomicAdd(&acc[0], lsum);
        atomicAdd(&acc[1], lcnt);
    }
}

__global__ void finalize_kernel(const float* __restrict__ acc, float* __restrict__ out) {
    out[0] = acc[0] / fmaxf(acc[1], 1.f);
}

// ---------------- launcher ----------------
extern "C" void kernel_launch(void* const* d_in, const int* in_sizes, int n_in, void* d_out,
                              int out_size, void* d_ws, size_t ws_size, hipStream_t stream) {
    const float* x = (const float*)d_in[0];
    const int* ei = (const int*)d_in[1];
    const int* src = ei;
    const int* dst = ei + N_EDGES;
    const void* mask = d_in[3];
    const float* tok = (const float*)d_in[4];
    const float* eW = (const float*)d_in[5];
    const float* eb = (const float*)d_in[6];
    const float* W1 = (const float*)d_in[7];
    const float* b1 = (const float*)d_in[8];
    const float* W2 = (const float*)d_in[9];
    const float* b2 = (const float*)d_in[10];
    const float* gm = (const float*)d_in[11];
    const float* bt = (const float*)d_in[12];
    const float* dW1 = (const float*)d_in[13];
    const float* db1 = (const float*)d_in[14];
    const float* dW2 = (const float*)d_in[15];
    const float* db2 = (const float*)d_in[16];
    float* out = (float*)d_out;

    char* ws = (char*)d_ws;
    size_t off = 0;
    auto alloc = [&](size_t bytes) -> void* {
        void* p = ws + off;
        off = (off + bytes + 255) & ~(size_t)255;
        return p;
    };
    unsigned short* h = (unsigned short*)alloc((size_t)N_NODES * HDIM * 2);
    unsigned short* z = (unsigned short*)alloc((size_t)N_NODES * HDIM * 2);
    unsigned short* z1 = (unsigned short*)alloc((size_t)N_NODES * 2 * HDIM * 2);
    float* zin = (float*)alloc((size_t)N_NODES * HDIM * 4);
    unsigned short* Wt1 = (unsigned short*)alloc((size_t)L_LAYERS * HDIM * 2 * HDIM * 2);
    unsigned short* Wt2 = (unsigned short*)alloc((size_t)L_LAYERS * HDIM * 2 * HDIM * 2);
    unsigned short* Wtd = (unsigned short*)alloc((size_t)HDIM * HDIM * 2);
    int* rowptr = (int*)alloc((size_t)(N_NODES + 1) * 4);
    int* cursor = (int*)alloc((size_t)N_NODES * 4);
    int* col = (int*)alloc((size_t)N_EDGES * 4);
    float* stats = (float*)alloc(2 * HDIM * 4);
    float* sc = (float*)alloc(2 * HDIM * 4);
    float* lacc = (float*)alloc(8);
    int* flag = (int*)alloc(4);

    detect_mask_kernel<<<1, 256, 0, stream>>>((const uint32_t*)mask, flag);

    // weight prep (tiny)
    for (int l = 0; l < L_LAYERS; ++l) {
        wprep_kernel<<<128, 256, 0, stream>>>(W1 + (size_t)l * HDIM * 2 * HDIM,
                                              Wt1 + (size_t)l * HDIM * 2 * HDIM, HDIM, 8);
        wprep_kernel<<<128, 256, 0, stream>>>(W2 + (size_t)l * HDIM * 2 * HDIM,
                                              Wt2 + (size_t)l * HDIM * 2 * HDIM, 2 * HDIM, 7);
    }
    wprep_kernel<<<64, 256, 0, stream>>>(dW1, Wtd, HDIM, 7);

    embed_kernel<<<(N_NODES * HDIM + 255) / 256, 256, 0, stream>>>(x, mask, flag, tok, eW, eb, h);

    hipMemsetAsync(rowptr, 0, (size_t)(N_NODES + 1) * 4, stream);
    deg_kernel<<<(N_EDGES + 255) / 256, 256, 0, stream>>>(dst, rowptr);
    scan_kernel<<<1, 1024, 0, stream>>>(rowptr, cursor);
    fill_bucket_kernel<<<2048, 256, 0, stream>>>(src, dst, cursor, col);

    for (int l = 0; l < L_LAYERS; ++l) {
        agg_kernel<<<(N_NODES + 3) / 4, 256, 0, stream>>>(h, rowptr, col, z);
        mfma_gemm_kernel<HDIM, true, true><<<dim3(4, 782), 256, 0, stream>>>(
            z, Wt1 + (size_t)l * HDIM * 2 * HDIM, b1 + (size_t)l * 2 * HDIM, z1, N_NODES,
            2 * HDIM);
        mfma_gemm_kernel<2 * HDIM, false, false><<<dim3(2, 782), 256, 0, stream>>>(
            z1, Wt2 + (size_t)l * HDIM * 2 * HDIM, b2 + (size_t)l * HDIM, zin, N_NODES, HDIM);
        hipMemsetAsync(stats, 0, 2 * HDIM * 4, stream);
        bnstats_kernel<<<256, 256, 0, stream>>>(zin, stats);
        bnfin_kernel<<<1, 128, 0, stream>>>(stats, gm + l * HDIM, bt + l * HDIM, sc);
        bnapply_kernel<<<(N_NODES * HDIM / 4 + 255) / 256, 256, 0, stream>>>(zin, sc, h);
    }

    mfma_gemm_kernel<HDIM, true, true><<<dim3(2, 782), 256, 0, stream>>>(h, Wtd, db1, z1, N_NODES,
                                                                         HDIM);
    hipMemsetAsync(lacc, 0, 8, stream);
    dec2_loss_kernel<<<1024, 256, 0, stream>>>(z1, dW2, db2, x, mask, flag, out + 1, lacc);
    finalize_kernel<<<1, 1, 0, stream>>>(lacc, out);
}

// Round 5
// 1035.970 us; speedup vs baseline: 1.5487x; 1.0990x over previous
//
#include <hip/hip_runtime.h>
#include <cstdint>

#define N_NODES 50000
#define N_EDGES 1600000
#define HDIM 128
#define L_LAYERS 4
#define BN_EPS 1e-5f
#define SCAN_NB 98
#define SCAN_CHUNK 512

typedef __attribute__((ext_vector_type(8))) short short8v;
typedef __attribute__((ext_vector_type(4))) float f32x4;

__device__ __forceinline__ unsigned short f2bf(float f) {
    uint32_t u = __builtin_bit_cast(uint32_t, f);
    u += 0x7fff + ((u >> 16) & 1);
    return (unsigned short)(u >> 16);
}
__device__ __forceinline__ float bf2f(unsigned short b) {
    return __builtin_bit_cast(float, (uint32_t)b << 16);
}

// ---------------- mask layout detection ----------------
__global__ void detect_mask_kernel(const uint32_t* __restrict__ mw, int* __restrict__ flag) {
    __shared__ int f;
    if (threadIdx.x == 0) f = 0;
    __syncthreads();
    int found = 0;
    for (int i = threadIdx.x; i < 12500; i += blockDim.x)
        if (mw[i] > 1u) found = 1;
    if (found) f = 1;
    __syncthreads();
    if (threadIdx.x == 0) *flag = f;
}

__device__ __forceinline__ int read_mask(const void* mask, int i, int bytelayout) {
    if (bytelayout) return ((const unsigned char*)mask)[i] != 0;
    return ((const int*)mask)[i] != 0;
}

// ---------------- weight prep: Wt[n][k] = bf16(W[k][n]) ----------------
__global__ void wprep_kernel(const float* __restrict__ W, unsigned short* __restrict__ Wt, int K,
                             int nshift) {
    int idx = blockIdx.x * 256 + threadIdx.x;
    if (idx >= (K << nshift)) return;
    int k = idx >> nshift, n = idx & ((1 << nshift) - 1);
    Wt[n * K + k] = f2bf(W[idx]);
}

// ---------------- embed: h = (mask? token : x) @ W + b  (bf16 out) ----------------
__global__ void embed_kernel(const float* __restrict__ x, const void* __restrict__ mask,
                             const int* __restrict__ flag, const float* __restrict__ tok,
                             const float* __restrict__ W, const float* __restrict__ b,
                             unsigned short* __restrict__ h) {
    int idx = blockIdx.x * blockDim.x + threadIdx.x;
    if (idx >= N_NODES * HDIM) return;
    int i = idx >> 7, c = idx & 127;
    int fl = *flag;
    int m = read_mask(mask, i, fl);
    float x0 = m ? tok[0] : x[i * 3 + 0];
    float x1 = m ? tok[1] : x[i * 3 + 1];
    float x2 = m ? tok[2] : x[i * 3 + 2];
    h[idx] = f2bf(x0 * W[c] + x1 * W[HDIM + c] + x2 * W[2 * HDIM + c] + b[c]);
}

// ---------------- CSR build ----------------
__global__ void deg_kernel(const int* __restrict__ dst, int* __restrict__ deg) {
    int e = blockIdx.x * blockDim.x + threadIdx.x;
    if (e < N_EDGES) atomicAdd(&deg[dst[e]], 1);
}

// hierarchical scan: partial sums -> scan of block sums -> final per-tile scan
__global__ __launch_bounds__(256) void scan_partial_kernel(const int* __restrict__ deg,
                                                           int* __restrict__ bsum) {
    __shared__ int red[256];
    int b = blockIdx.x, t = threadIdx.x;
    int base = b * SCAN_CHUNK;
    int s = 0;
    for (int i = t; i < SCAN_CHUNK; i += 256) {
        int idx = base + i;
        if (idx < N_NODES) s += deg[idx];
    }
    red[t] = s;
    __syncthreads();
    for (int o = 128; o > 0; o >>= 1) {
        if (t < o) red[t] += red[t + o];
        __syncthreads();
    }
    if (t == 0) bsum[b] = red[0];
}

__global__ __launch_bounds__(128) void scan_bsum_kernel(const int* __restrict__ bsum,
                                                        int* __restrict__ ebsum,
                                                        int* __restrict__ rowptr) {
    __shared__ int sh[128];
    int t = threadIdx.x;
    int v = (t < SCAN_NB) ? bsum[t] : 0;
    sh[t] = v;
    __syncthreads();
    for (int o = 1; o < 128; o <<= 1) {
        int u = (t >= o) ? sh[t - o] : 0;
        __syncthreads();
        sh[t] += u;
        __syncthreads();
    }
    if (t < SCAN_NB) ebsum[t] = sh[t] - v;
    if (t == 127) rowptr[N_NODES] = sh[127];
}

__global__ __launch_bounds__(256) void scan_final_kernel(const int* __restrict__ deg,
                                                         const int* __restrict__ ebsum,
                                                         int* __restrict__ rowptr,
                                                         int* __restrict__ cursor) {
    __shared__ int sh[256];
    int b = blockIdx.x, t = threadIdx.x;
    int running = ebsum[b];
    for (int t0 = 0; t0 < SCAN_CHUNK; t0 += 256) {
        int idx = b * SCAN_CHUNK + t0 + t;
        int v = (idx < N_NODES) ? deg[idx] : 0;
        sh[t] = v;
        __syncthreads();
        for (int o = 1; o < 256; o <<= 1) {
            int u = (t >= o) ? sh[t - o] : 0;
            __syncthreads();
            sh[t] += u;
            __syncthreads();
        }
        int excl = sh[t] - v + running;
        if (idx < N_NODES) {
            rowptr[idx] = excl;
            cursor[idx] = excl;
        }
        running += sh[255];
        __syncthreads();
    }
}

// bucketed fill: group g = blockIdx&7 (~XCD) owns dst range [g*6250,(g+1)*6250);
// each group scans all edges -> col writes are contiguous-region-local per group.
__global__ __launch_bounds__(256) void fill_bucket_kernel(const int* __restrict__ src,
                                                          const int* __restrict__ dst,
                                                          int* __restrict__ cursor,
                                                          int* __restrict__ col) {
    int g = blockIdx.x & 7;
    int nb = gridDim.x >> 3;
    int bg = blockIdx.x >> 3;
    int lo = g * (N_NODES / 8), hi = lo + (N_NODES / 8);
    for (int e = bg * 256 + (int)threadIdx.x; e < N_EDGES; e += nb * 256) {
        int d = dst[e];
        if (d >= lo && d < hi) {
            int pos = atomicAdd(&cursor[d], 1);
            col[pos] = src[e];
        }
    }
}

// ---------------- aggregation (bf16 h): z[i] = h[i] + sum_{j} h[j] ----------------
__global__ __launch_bounds__(256) void agg_kernel(const unsigned short* __restrict__ h,
                                                  const int* __restrict__ rowptr,
                                                  const int* __restrict__ col,
                                                  unsigned short* __restrict__ z) {
    int wid = threadIdx.x >> 6;
    int lane = threadIdx.x & 63;
    int i = blockIdx.x * 4 + wid;
    if (i >= N_NODES) return;
    int start = rowptr[i], end = rowptr[i + 1];
    const uint32_t* h32 = (const uint32_t*)h;
    uint32_t u = h32[(size_t)i * 64 + lane];
    float ax = __builtin_bit_cast(float, u << 16);
    float ay = __builtin_bit_cast(float, u & 0xffff0000u);
    float bx = 0.f, by = 0.f, cx = 0.f, cy = 0.f, dx = 0.f, dy = 0.f;
    int e = start;
    for (; e + 4 <= end; e += 4) {
        int j0 = col[e + 0], j1 = col[e + 1], j2 = col[e + 2], j3 = col[e + 3];
        uint32_t u0 = h32[(size_t)j0 * 64 + lane];
        uint32_t u1 = h32[(size_t)j1 * 64 + lane];
        uint32_t u2 = h32[(size_t)j2 * 64 + lane];
        uint32_t u3 = h32[(size_t)j3 * 64 + lane];
        ax += __builtin_bit_cast(float, u0 << 16);
        ay += __builtin_bit_cast(float, u0 & 0xffff0000u);
        bx += __builtin_bit_cast(float, u1 << 16);
        by += __builtin_bit_cast(float, u1 & 0xffff0000u);
        cx += __builtin_bit_cast(float, u2 << 16);
        cy += __builtin_bit_cast(float, u2 & 0xffff0000u);
        dx += __builtin_bit_cast(float, u3 << 16);
        dy += __builtin_bit_cast(float, u3 & 0xffff0000u);
    }
    for (; e < end; ++e) {
        uint32_t u0 = h32[(size_t)col[e] * 64 + lane];
        ax += __builtin_bit_cast(float, u0 << 16);
        ay += __builtin_bit_cast(float, u0 & 0xffff0000u);
    }
    ax += bx + cx + dx;
    ay += by + cy + dy;
    uint32_t o = (uint32_t)f2bf(ax) | ((uint32_t)f2bf(ay) << 16);
    ((uint32_t*)z)[(size_t)i * 64 + lane] = o;
}

// ---------------- bf16 MFMA GEMM: C = [relu](A[M,K]bf16 @ Wt[N,K]^T + bias) ----------------
template <int K, bool OUT_BF16, bool RELU>
__global__ __launch_bounds__(256) void mfma_gemm_kernel(const unsigned short* __restrict__ A,
                                                        const unsigned short* __restrict__ Wt,
                                                        const float* __restrict__ bias,
                                                        void* __restrict__ C, int M, int ldc) {
    const int lane = threadIdx.x & 63;
    const int w = threadIdx.x >> 6;
    const int row0 = blockIdx.y * 64 + w * 16;
    const int col0 = blockIdx.x * 64;
    const int r = lane & 15;   // A-row / B-col / D-col within 16
    const int ks = lane >> 4;  // k-segment (8 bf16 each)
    const int arow = min(row0 + r, M - 1);
    f32x4 acc[4];
#pragma unroll
    for (int n = 0; n < 4; ++n) acc[n] = (f32x4){0.f, 0.f, 0.f, 0.f};
#pragma unroll
    for (int k0 = 0; k0 < K; k0 += 32) {
        short8v a = *(const short8v*)&A[(size_t)arow * K + k0 + ks * 8];
#pragma unroll
        for (int n = 0; n < 4; ++n) {
            short8v b = *(const short8v*)&Wt[(size_t)(col0 + n * 16 + r) * K + k0 + ks * 8];
            acc[n] = __builtin_amdgcn_mfma_f32_16x16x32_bf16(a, b, acc[n], 0, 0, 0);
        }
    }
#pragma unroll
    for (int n = 0; n < 4; ++n) {
        const int col = col0 + n * 16 + r;
        const float bv = bias[col];
#pragma unroll
        for (int i = 0; i < 4; ++i) {
            int row = row0 + ks * 4 + i;
            if (row < M) {
                float o = acc[n][i] + bv;
                if (RELU) o = fmaxf(o, 0.f);
                if (OUT_BF16)
                    ((unsigned short*)C)[(size_t)row * ldc + col] = f2bf(o);
                else
                    ((float*)C)[(size_t)row * ldc + col] = o;
            }
        }
    }
}

// ---------------- BatchNorm ----------------
__global__ void bnstats_kernel(const float* __restrict__ z, float* __restrict__ stats) {
    int c = threadIdx.x & 127;
    int r0 = blockIdx.x * 2 + (threadIdx.x >> 7);
    float s = 0.f, ss = 0.f;
    for (int r = r0; r < N_NODES; r += gridDim.x * 2) {
        float v = z[(size_t)r * HDIM + c];
        s += v;
        ss += v * v;
    }
    atomicAdd(&stats[c], s);
    atomicAdd(&stats[HDIM + c], ss);
}

__global__ void bnfin_kernel(const float* __restrict__ stats, const float* __restrict__ gamma,
                             const float* __restrict__ beta, float* __restrict__ sc) {
    int c = threadIdx.x;
    float mean = stats[c] * (1.f / N_NODES);
    float var = stats[HDIM + c] * (1.f / N_NODES) - mean * mean;
    float rstd = rsqrtf(fmaxf(var, 0.f) + BN_EPS);
    float s = gamma[c] * rstd;
    sc[c] = s;
    sc[HDIM + c] = beta[c] - mean * s;
}

// h = relu(z*scale + shift) -> bf16, 4 elems/thread
__global__ void bnapply_kernel(const float* __restrict__ z, const float* __restrict__ sc,
                               unsigned short* __restrict__ h) {
    int idx = blockIdx.x * blockDim.x + threadIdx.x;
    if (idx >= N_NODES * HDIM / 4) return;
    float4 v = ((const float4*)z)[idx];
    int c = (idx * 4) & 127;
    float o0 = fmaxf(v.x * sc[c + 0] + sc[HDIM + c + 0], 0.f);
    float o1 = fmaxf(v.y * sc[c + 1] + sc[HDIM + c + 1], 0.f);
    float o2 = fmaxf(v.z * sc[c + 2] + sc[HDIM + c + 2], 0.f);
    float o3 = fmaxf(v.w * sc[c + 3] + sc[HDIM + c + 3], 0.f);
    uint2 p;
    p.x = (uint32_t)f2bf(o0) | ((uint32_t)f2bf(o1) << 16);
    p.y = (uint32_t)f2bf(o2) | ((uint32_t)f2bf(o3) << 16);
    ((uint2*)h)[idx] = p;
}

// ---------------- decoder stage2 + loss ----------------
__global__ __launch_bounds__(256) void dec2_loss_kernel(
    const unsigned short* __restrict__ d1, const float* __restrict__ W2,
    const float* __restrict__ b2, const float* __restrict__ x, const void* __restrict__ mask,
    const int* __restrict__ flag, float* __restrict__ recon, float* __restrict__ acc) {
    int lane = threadIdx.x & 63;
    int wid = threadIdx.x >> 6;
    int gwave = blockIdx.x * 4 + wid;
    int nwaves = gridDim.x * 4;
    int fl = *flag;
    float w00 = W2[lane * 3 + 0], w01 = W2[lane * 3 + 1], w02 = W2[lane * 3 + 2];
    float w10 = W2[(lane + 64) * 3 + 0], w11 = W2[(lane + 64) * 3 + 1],
          w12 = W2[(lane + 64) * 3 + 2];
    float bb0 = b2[0], bb1 = b2[1], bb2 = b2[2];
    float lsum = 0.f, lcnt = 0.f;
    for (int i = gwave; i < N_NODES; i += nwaves) {
        float a0 = bf2f(d1[(size_t)i * HDIM + lane]);
        float a1 = bf2f(d1[(size_t)i * HDIM + 64 + lane]);
        float s0 = a0 * w00 + a1 * w10;
        float s1 = a0 * w01 + a1 * w11;
        float s2 = a0 * w02 + a1 * w12;
#pragma unroll
        for (int o = 32; o > 0; o >>= 1) {
            s0 += __shfl_xor(s0, o);
            s1 += __shfl_xor(s1, o);
            s2 += __shfl_xor(s2, o);
        }
        float r0 = s0 + bb0, r1 = s1 + bb1, r2 = s2 + bb2;
        if (lane < 3) recon[(size_t)i * 3 + lane] = (lane == 0) ? r0 : ((lane == 1) ? r1 : r2);
        if (lane == 0 && read_mask(mask, i, fl)) {
            float rn = fmaxf(sqrtf(r0 * r0 + r1 * r1 + r2 * r2), 1e-12f);
            float x0 = x[i * 3 + 0], x1 = x[i * 3 + 1], x2 = x[i * 3 + 2];
            float xn = fmaxf(sqrtf(x0 * x0 + x1 * x1 + x2 * x2), 1e-12f);
            float cs = (r0 * x0 + r1 * x1 + r2 * x2) / (rn * xn);
            float d = 1.f - cs;
            lsum += d * d;
            lcnt += 1.f;
        }
    }
    if (lane == 0 && lcnt != 0.f) {
        atomicAdd(&acc[0], lsum);
        atomicAdd(&acc[1], lcnt);
    }
}

__global__ void finalize_kernel(const float* __restrict__ acc, float* __restrict__ out) {
    out[0] = acc[0] / fmaxf(acc[1], 1.f);
}

// ---------------- launcher ----------------
extern "C" void kernel_launch(void* const* d_in, const int* in_sizes, int n_in, void* d_out,
                              int out_size, void* d_ws, size_t ws_size, hipStream_t stream) {
    const float* x = (const float*)d_in[0];
    const int* ei = (const int*)d_in[1];
    const int* src = ei;
    const int* dst = ei + N_EDGES;
    const void* mask = d_in[3];
    const float* tok = (const float*)d_in[4];
    const float* eW = (const float*)d_in[5];
    const float* eb = (const float*)d_in[6];
    const float* W1 = (const float*)d_in[7];
    const float* b1 = (const float*)d_in[8];
    const float* W2 = (const float*)d_in[9];
    const float* b2 = (const float*)d_in[10];
    const float* gm = (const float*)d_in[11];
    const float* bt = (const float*)d_in[12];
    const float* dW1 = (const float*)d_in[13];
    const float* db1 = (const float*)d_in[14];
    const float* dW2 = (const float*)d_in[15];
    const float* db2 = (const float*)d_in[16];
    float* out = (float*)d_out;

    char* ws = (char*)d_ws;
    size_t off = 0;
    auto alloc = [&](size_t bytes) -> void* {
        void* p = ws + off;
        off = (off + bytes + 255) & ~(size_t)255;
        return p;
    };
    unsigned short* h = (unsigned short*)alloc((size_t)N_NODES * HDIM * 2);
    unsigned short* z = (unsigned short*)alloc((size_t)N_NODES * HDIM * 2);
    unsigned short* z1 = (unsigned short*)alloc((size_t)N_NODES * 2 * HDIM * 2);
    float* zin = (float*)alloc((size_t)N_NODES * HDIM * 4);
    unsigned short* Wt1 = (unsigned short*)alloc((size_t)L_LAYERS * HDIM * 2 * HDIM * 2);
    unsigned short* Wt2 = (unsigned short*)alloc((size_t)L_LAYERS * HDIM * 2 * HDIM * 2);
    unsigned short* Wtd = (unsigned short*)alloc((size_t)HDIM * HDIM * 2);
    int* deg = (int*)alloc((size_t)N_NODES * 4);
    int* rowptr = (int*)alloc((size_t)(N_NODES + 1) * 4);
    int* cursor = (int*)alloc((size_t)N_NODES * 4);
    int* col = (int*)alloc((size_t)N_EDGES * 4);
    int* bsum = (int*)alloc((size_t)SCAN_NB * 4);
    int* ebsum = (int*)alloc((size_t)SCAN_NB * 4);
    float* stats = (float*)alloc(2 * HDIM * 4);
    float* sc = (float*)alloc(2 * HDIM * 4);
    float* lacc = (float*)alloc(8);
    int* flag = (int*)alloc(4);

    detect_mask_kernel<<<1, 256, 0, stream>>>((const uint32_t*)mask, flag);

    // weight prep (tiny)
    for (int l = 0; l < L_LAYERS; ++l) {
        wprep_kernel<<<128, 256, 0, stream>>>(W1 + (size_t)l * HDIM * 2 * HDIM,
                                              Wt1 + (size_t)l * HDIM * 2 * HDIM, HDIM, 8);
        wprep_kernel<<<128, 256, 0, stream>>>(W2 + (size_t)l * HDIM * 2 * HDIM,
                                              Wt2 + (size_t)l * HDIM * 2 * HDIM, 2 * HDIM, 7);
    }
    wprep_kernel<<<64, 256, 0, stream>>>(dW1, Wtd, HDIM, 7);

    embed_kernel<<<(N_NODES * HDIM + 255) / 256, 256, 0, stream>>>(x, mask, flag, tok, eW, eb, h);

    hipMemsetAsync(deg, 0, (size_t)N_NODES * 4, stream);
    deg_kernel<<<(N_EDGES + 255) / 256, 256, 0, stream>>>(dst, deg);
    scan_partial_kernel<<<SCAN_NB, 256, 0, stream>>>(deg, bsum);
    scan_bsum_kernel<<<1, 128, 0, stream>>>(bsum, ebsum, rowptr);
    scan_final_kernel<<<SCAN_NB, 256, 0, stream>>>(deg, ebsum, rowptr, cursor);
    fill_bucket_kernel<<<2048, 256, 0, stream>>>(src, dst, cursor, col);

    for (int l = 0; l < L_LAYERS; ++l) {
        agg_kernel<<<(N_NODES + 3) / 4, 256, 0, stream>>>(h, rowptr, col, z);
        mfma_gemm_kernel<HDIM, true, true><<<dim3(4, 782), 256, 0, stream>>>(
            z, Wt1 + (size_t)l * HDIM * 2 * HDIM, b1 + (size_t)l * 2 * HDIM, z1, N_NODES,
            2 * HDIM);
        mfma_gemm_kernel<2 * HDIM, false, false><<<dim3(2, 782), 256, 0, stream>>>(
            z1, Wt2 + (size_t)l * HDIM * 2 * HDIM, b2 + (size_t)l * HDIM, zin, N_NODES, HDIM);
        hipMemsetAsync(stats, 0, 2 * HDIM * 4, stream);
        bnstats_kernel<<<256, 256, 0, stream>>>(zin, stats);
        bnfin_kernel<<<1, 128, 0, stream>>>(stats, gm + l * HDIM, bt + l * HDIM, sc);
        bnapply_kernel<<<(N_NODES * HDIM / 4 + 255) / 256, 256, 0, stream>>>(zin, sc, h);
    }

    mfma_gemm_kernel<HDIM, true, true><<<dim3(2, 782), 256, 0, stream>>>(h, Wtd, db1, z1, N_NODES,
                                                                         HDIM);
    hipMemsetAsync(lacc, 0, 8, stream);
    dec2_loss_kernel<<<1024, 256, 0, stream>>>(z1, dW2, db2, x, mask, flag, out + 1, lacc);
    finalize_kernel<<<1, 1, 0, stream>>>(lacc, out);
}

// Round 6
// 963.417 us; speedup vs baseline: 1.6653x; 1.0753x over previous
//
#include <hip/hip_runtime.h>
#include <cstdint>

#define N_NODES 50000
#define N_EDGES 1600000
#define HDIM 128
#define L_LAYERS 4
#define BN_EPS 1e-5f
#define SCAN_NB 98
#define SCAN_CHUNK 512

typedef __attribute__((ext_vector_type(8))) short short8v;
typedef __attribute__((ext_vector_type(4))) float f32x4;

__device__ __forceinline__ unsigned short f2bf(float f) {
    uint32_t u = __builtin_bit_cast(uint32_t, f);
    u += 0x7fff + ((u >> 16) & 1);
    return (unsigned short)(u >> 16);
}
__device__ __forceinline__ float bf2f(unsigned short b) {
    return __builtin_bit_cast(float, (uint32_t)b << 16);
}

// ---------------- mask layout detection ----------------
__global__ void detect_mask_kernel(const uint32_t* __restrict__ mw, int* __restrict__ flag) {
    __shared__ int f;
    if (threadIdx.x == 0) f = 0;
    __syncthreads();
    int found = 0;
    for (int i = threadIdx.x; i < 12500; i += blockDim.x)
        if (mw[i] > 1u) found = 1;
    if (found) f = 1;
    __syncthreads();
    if (threadIdx.x == 0) *flag = f;
}

__device__ __forceinline__ int read_mask(const void* mask, int i, int bytelayout) {
    if (bytelayout) return ((const unsigned char*)mask)[i] != 0;
    return ((const int*)mask)[i] != 0;
}

// ---------------- weight prep: Wt[n][k] = bf16(W[k][n]) ----------------
__global__ void wprep_kernel(const float* __restrict__ W, unsigned short* __restrict__ Wt, int K,
                             int nshift) {
    int idx = blockIdx.x * 256 + threadIdx.x;
    if (idx >= (K << nshift)) return;
    int k = idx >> nshift, n = idx & ((1 << nshift) - 1);
    Wt[n * K + k] = f2bf(W[idx]);
}

// ---------------- embed: h = (mask? token : x) @ W + b  (bf16 out) ----------------
__global__ void embed_kernel(const float* __restrict__ x, const void* __restrict__ mask,
                             const int* __restrict__ flag, const float* __restrict__ tok,
                             const float* __restrict__ W, const float* __restrict__ b,
                             unsigned short* __restrict__ h) {
    int idx = blockIdx.x * blockDim.x + threadIdx.x;
    if (idx >= N_NODES * HDIM) return;
    int i = idx >> 7, c = idx & 127;
    int fl = *flag;
    int m = read_mask(mask, i, fl);
    float x0 = m ? tok[0] : x[i * 3 + 0];
    float x1 = m ? tok[1] : x[i * 3 + 1];
    float x2 = m ? tok[2] : x[i * 3 + 2];
    h[idx] = f2bf(x0 * W[c] + x1 * W[HDIM + c] + x2 * W[2 * HDIM + c] + b[c]);
}

// ---------------- CSR build ----------------
__global__ void deg_kernel(const int* __restrict__ dst, int* __restrict__ deg) {
    int e = blockIdx.x * blockDim.x + threadIdx.x;
    if (e < N_EDGES) atomicAdd(&deg[dst[e]], 1);
}

// hierarchical scan
__global__ __launch_bounds__(256) void scan_partial_kernel(const int* __restrict__ deg,
                                                           int* __restrict__ bsum) {
    __shared__ int red[256];
    int b = blockIdx.x, t = threadIdx.x;
    int base = b * SCAN_CHUNK;
    int s = 0;
    for (int i = t; i < SCAN_CHUNK; i += 256) {
        int idx = base + i;
        if (idx < N_NODES) s += deg[idx];
    }
    red[t] = s;
    __syncthreads();
    for (int o = 128; o > 0; o >>= 1) {
        if (t < o) red[t] += red[t + o];
        __syncthreads();
    }
    if (t == 0) bsum[b] = red[0];
}

__global__ __launch_bounds__(128) void scan_bsum_kernel(const int* __restrict__ bsum,
                                                        int* __restrict__ ebsum,
                                                        int* __restrict__ rowptr) {
    __shared__ int sh[128];
    int t = threadIdx.x;
    int v = (t < SCAN_NB) ? bsum[t] : 0;
    sh[t] = v;
    __syncthreads();
    for (int o = 1; o < 128; o <<= 1) {
        int u = (t >= o) ? sh[t - o] : 0;
        __syncthreads();
        sh[t] += u;
        __syncthreads();
    }
    if (t < SCAN_NB) ebsum[t] = sh[t] - v;
    if (t == 127) rowptr[N_NODES] = sh[127];
}

__global__ __launch_bounds__(256) void scan_final_kernel(const int* __restrict__ deg,
                                                         const int* __restrict__ ebsum,
                                                         int* __restrict__ rowptr,
                                                         int* __restrict__ cursor) {
    __shared__ int sh[256];
    int b = blockIdx.x, t = threadIdx.x;
    int running = ebsum[b];
    for (int t0 = 0; t0 < SCAN_CHUNK; t0 += 256) {
        int idx = b * SCAN_CHUNK + t0 + t;
        int v = (idx < N_NODES) ? deg[idx] : 0;
        sh[t] = v;
        __syncthreads();
        for (int o = 1; o < 256; o <<= 1) {
            int u = (t >= o) ? sh[t - o] : 0;
            __syncthreads();
            sh[t] += u;
            __syncthreads();
        }
        int excl = sh[t] - v + running;
        if (idx < N_NODES) {
            rowptr[idx] = excl;
            cursor[idx] = excl;
        }
        running += sh[255];
        __syncthreads();
    }
}

// bucketed fill
__global__ __launch_bounds__(256) void fill_bucket_kernel(const int* __restrict__ src,
                                                          const int* __restrict__ dst,
                                                          int* __restrict__ cursor,
                                                          int* __restrict__ col) {
    int g = blockIdx.x & 7;
    int nb = gridDim.x >> 3;
    int bg = blockIdx.x >> 3;
    int lo = g * (N_NODES / 8), hi = lo + (N_NODES / 8);
    for (int e = bg * 256 + (int)threadIdx.x; e < N_EDGES; e += nb * 256) {
        int d = dst[e];
        if (d >= lo && d < hi) {
            int pos = atomicAdd(&cursor[d], 1);
            col[pos] = src[e];
        }
    }
}

// ---------------- aggregation (bf16 h): z[i] = h[i] + sum_{j} h[j] ----------------
__global__ __launch_bounds__(256) void agg_kernel(const unsigned short* __restrict__ h,
                                                  const int* __restrict__ rowptr,
                                                  const int* __restrict__ col,
                                                  unsigned short* __restrict__ z) {
    int wid = threadIdx.x >> 6;
    int lane = threadIdx.x & 63;
    int i = blockIdx.x * 4 + wid;
    if (i >= N_NODES) return;
    int start = rowptr[i], end = rowptr[i + 1];
    const uint32_t* h32 = (const uint32_t*)h;
    uint32_t u = h32[(size_t)i * 64 + lane];
    float ax = __builtin_bit_cast(float, u << 16);
    float ay = __builtin_bit_cast(float, u & 0xffff0000u);
    float bx = 0.f, by = 0.f, cx = 0.f, cy = 0.f, dx = 0.f, dy = 0.f;
    int e = start;
    for (; e + 4 <= end; e += 4) {
        int j0 = col[e + 0], j1 = col[e + 1], j2 = col[e + 2], j3 = col[e + 3];
        uint32_t u0 = h32[(size_t)j0 * 64 + lane];
        uint32_t u1 = h32[(size_t)j1 * 64 + lane];
        uint32_t u2 = h32[(size_t)j2 * 64 + lane];
        uint32_t u3 = h32[(size_t)j3 * 64 + lane];
        ax += __builtin_bit_cast(float, u0 << 16);
        ay += __builtin_bit_cast(float, u0 & 0xffff0000u);
        bx += __builtin_bit_cast(float, u1 << 16);
        by += __builtin_bit_cast(float, u1 & 0xffff0000u);
        cx += __builtin_bit_cast(float, u2 << 16);
        cy += __builtin_bit_cast(float, u2 & 0xffff0000u);
        dx += __builtin_bit_cast(float, u3 << 16);
        dy += __builtin_bit_cast(float, u3 & 0xffff0000u);
    }
    for (; e < end; ++e) {
        uint32_t u0 = h32[(size_t)col[e] * 64 + lane];
        ax += __builtin_bit_cast(float, u0 << 16);
        ay += __builtin_bit_cast(float, u0 & 0xffff0000u);
    }
    ax += bx + cx + dx;
    ay += by + cy + dy;
    uint32_t o = (uint32_t)f2bf(ax) | ((uint32_t)f2bf(ay) << 16);
    ((uint32_t*)z)[(size_t)i * 64 + lane] = o;
}

// ---------------- bf16 MFMA GEMM ----------------
template <int K, bool OUT_BF16, bool RELU>
__global__ __launch_bounds__(256) void mfma_gemm_kernel(const unsigned short* __restrict__ A,
                                                        const unsigned short* __restrict__ Wt,
                                                        const float* __restrict__ bias,
                                                        void* __restrict__ C, int M, int ldc) {
    const int lane = threadIdx.x & 63;
    const int w = threadIdx.x >> 6;
    const int row0 = blockIdx.y * 64 + w * 16;
    const int col0 = blockIdx.x * 64;
    const int r = lane & 15;
    const int ks = lane >> 4;
    const int arow = min(row0 + r, M - 1);
    f32x4 acc[4];
#pragma unroll
    for (int n = 0; n < 4; ++n) acc[n] = (f32x4){0.f, 0.f, 0.f, 0.f};
#pragma unroll
    for (int k0 = 0; k0 < K; k0 += 32) {
        short8v a = *(const short8v*)&A[(size_t)arow * K + k0 + ks * 8];
#pragma unroll
        for (int n = 0; n < 4; ++n) {
            short8v b = *(const short8v*)&Wt[(size_t)(col0 + n * 16 + r) * K + k0 + ks * 8];
            acc[n] = __builtin_amdgcn_mfma_f32_16x16x32_bf16(a, b, acc[n], 0, 0, 0);
        }
    }
#pragma unroll
    for (int n = 0; n < 4; ++n) {
        const int col = col0 + n * 16 + r;
        const float bv = bias[col];
#pragma unroll
        for (int i = 0; i < 4; ++i) {
            int row = row0 + ks * 4 + i;
            if (row < M) {
                float o = acc[n][i] + bv;
                if (RELU) o = fmaxf(o, 0.f);
                if (OUT_BF16)
                    ((unsigned short*)C)[(size_t)row * ldc + col] = f2bf(o);
                else
                    ((float*)C)[(size_t)row * ldc + col] = o;
            }
        }
    }
}

// ---------------- BatchNorm ----------------
__global__ void bnstats_kernel(const float* __restrict__ z, float* __restrict__ stats) {
    int c = threadIdx.x & 127;
    int r0 = blockIdx.x * 2 + (threadIdx.x >> 7);
    float s = 0.f, ss = 0.f;
    for (int r = r0; r < N_NODES; r += gridDim.x * 2) {
        float v = z[(size_t)r * HDIM + c];
        s += v;
        ss += v * v;
    }
    atomicAdd(&stats[c], s);
    atomicAdd(&stats[HDIM + c], ss);
}

__global__ void bnfin_kernel(const float* __restrict__ stats, const float* __restrict__ gamma,
                             const float* __restrict__ beta, float* __restrict__ sc) {
    int c = threadIdx.x;
    float mean = stats[c] * (1.f / N_NODES);
    float var = stats[HDIM + c] * (1.f / N_NODES) - mean * mean;
    float rstd = rsqrtf(fmaxf(var, 0.f) + BN_EPS);
    float s = gamma[c] * rstd;
    sc[c] = s;
    sc[HDIM + c] = beta[c] - mean * s;
}

__global__ void bnapply_kernel(const float* __restrict__ z, const float* __restrict__ sc,
                               unsigned short* __restrict__ h) {
    int idx = blockIdx.x * blockDim.x + threadIdx.x;
    if (idx >= N_NODES * HDIM / 4) return;
    float4 v = ((const float4*)z)[idx];
    int c = (idx * 4) & 127;
    float o0 = fmaxf(v.x * sc[c + 0] + sc[HDIM + c + 0], 0.f);
    float o1 = fmaxf(v.y * sc[c + 1] + sc[HDIM + c + 1], 0.f);
    float o2 = fmaxf(v.z * sc[c + 2] + sc[HDIM + c + 2], 0.f);
    float o3 = fmaxf(v.w * sc[c + 3] + sc[HDIM + c + 3], 0.f);
    uint2 p;
    p.x = (uint32_t)f2bf(o0) | ((uint32_t)f2bf(o1) << 16);
    p.y = (uint32_t)f2bf(o2) | ((uint32_t)f2bf(o3) << 16);
    ((uint2*)h)[idx] = p;
}

// ---------------- decoder stage2 + loss: one THREAD per node ----------------
// no cross-lane work per node; 16 independent 16B loads/thread; W2 in LDS
// (broadcast reads); one 2-value wave reduce + 2 atomics per wave at the end.
__global__ __launch_bounds__(256) void dec2_loss_kernel(
    const unsigned short* __restrict__ d1, const float* __restrict__ W2,
    const float* __restrict__ b2, const float* __restrict__ x, const void* __restrict__ mask,
    const int* __restrict__ flag, float* __restrict__ recon, float* __restrict__ acc) {
    __shared__ float w2s[HDIM * 3];
    for (int t = threadIdx.x; t < HDIM * 3; t += 256) w2s[t] = W2[t];
    __syncthreads();
    int i = blockIdx.x * 256 + threadIdx.x;
    int fl = *flag;
    float lsum = 0.f, lcnt = 0.f;
    if (i < N_NODES) {
        float s0 = 0.f, s1 = 0.f, s2 = 0.f;
        const unsigned short* row = &d1[(size_t)i * HDIM];
#pragma unroll
        for (int k0 = 0; k0 < HDIM; k0 += 8) {
            short8v v = *(const short8v*)&row[k0];
#pragma unroll
            for (int q = 0; q < 8; ++q) {
                float a = bf2f((unsigned short)v[q]);
                s0 = fmaf(a, w2s[(k0 + q) * 3 + 0], s0);
                s1 = fmaf(a, w2s[(k0 + q) * 3 + 1], s1);
                s2 = fmaf(a, w2s[(k0 + q) * 3 + 2], s2);
            }
        }
        float r0 = s0 + b2[0], r1 = s1 + b2[1], r2 = s2 + b2[2];
        recon[(size_t)i * 3 + 0] = r0;
        recon[(size_t)i * 3 + 1] = r1;
        recon[(size_t)i * 3 + 2] = r2;
        if (read_mask(mask, i, fl)) {
            float rn = fmaxf(sqrtf(r0 * r0 + r1 * r1 + r2 * r2), 1e-12f);
            float x0 = x[i * 3 + 0], x1 = x[i * 3 + 1], x2 = x[i * 3 + 2];
            float xn = fmaxf(sqrtf(x0 * x0 + x1 * x1 + x2 * x2), 1e-12f);
            float cs = (r0 * x0 + r1 * x1 + r2 * x2) / (rn * xn);
            float d = 1.f - cs;
            lsum = d * d;
            lcnt = 1.f;
        }
    }
#pragma unroll
    for (int o = 32; o > 0; o >>= 1) {
        lsum += __shfl_xor(lsum, o);
        lcnt += __shfl_xor(lcnt, o);
    }
    if ((threadIdx.x & 63) == 0 && lcnt != 0.f) {
        atomicAdd(&acc[0], lsum);
        atomicAdd(&acc[1], lcnt);
    }
}

__global__ void finalize_kernel(const float* __restrict__ acc, float* __restrict__ out) {
    out[0] = acc[0] / fmaxf(acc[1], 1.f);
}

// ---------------- launcher ----------------
extern "C" void kernel_launch(void* const* d_in, const int* in_sizes, int n_in, void* d_out,
                              int out_size, void* d_ws, size_t ws_size, hipStream_t stream) {
    const float* x = (const float*)d_in[0];
    const int* ei = (const int*)d_in[1];
    const int* src = ei;
    const int* dst = ei + N_EDGES;
    const void* mask = d_in[3];
    const float* tok = (const float*)d_in[4];
    const float* eW = (const float*)d_in[5];
    const float* eb = (const float*)d_in[6];
    const float* W1 = (const float*)d_in[7];
    const float* b1 = (const float*)d_in[8];
    const float* W2 = (const float*)d_in[9];
    const float* b2 = (const float*)d_in[10];
    const float* gm = (const float*)d_in[11];
    const float* bt = (const float*)d_in[12];
    const float* dW1 = (const float*)d_in[13];
    const float* db1 = (const float*)d_in[14];
    const float* dW2 = (const float*)d_in[15];
    const float* db2 = (const float*)d_in[16];
    float* out = (float*)d_out;

    char* ws = (char*)d_ws;
    size_t off = 0;
    auto alloc = [&](size_t bytes) -> void* {
        void* p = ws + off;
        off = (off + bytes + 255) & ~(size_t)255;
        return p;
    };
    unsigned short* h = (unsigned short*)alloc((size_t)N_NODES * HDIM * 2);
    unsigned short* z = (unsigned short*)alloc((size_t)N_NODES * HDIM * 2);
    unsigned short* z1 = (unsigned short*)alloc((size_t)N_NODES * 2 * HDIM * 2);
    float* zin = (float*)alloc((size_t)N_NODES * HDIM * 4);
    unsigned short* Wt1 = (unsigned short*)alloc((size_t)L_LAYERS * HDIM * 2 * HDIM * 2);
    unsigned short* Wt2 = (unsigned short*)alloc((size_t)L_LAYERS * HDIM * 2 * HDIM * 2);
    unsigned short* Wtd = (unsigned short*)alloc((size_t)HDIM * HDIM * 2);
    int* deg = (int*)alloc((size_t)N_NODES * 4);
    int* rowptr = (int*)alloc((size_t)(N_NODES + 1) * 4);
    int* cursor = (int*)alloc((size_t)N_NODES * 4);
    int* col = (int*)alloc((size_t)N_EDGES * 4);
    int* bsum = (int*)alloc((size_t)SCAN_NB * 4);
    int* ebsum = (int*)alloc((size_t)SCAN_NB * 4);
    float* stats = (float*)alloc(2 * HDIM * 4);
    float* sc = (float*)alloc(2 * HDIM * 4);
    float* lacc = (float*)alloc(8);
    int* flag = (int*)alloc(4);

    detect_mask_kernel<<<1, 256, 0, stream>>>((const uint32_t*)mask, flag);

    for (int l = 0; l < L_LAYERS; ++l) {
        wprep_kernel<<<128, 256, 0, stream>>>(W1 + (size_t)l * HDIM * 2 * HDIM,
                                              Wt1 + (size_t)l * HDIM * 2 * HDIM, HDIM, 8);
        wprep_kernel<<<128, 256, 0, stream>>>(W2 + (size_t)l * HDIM * 2 * HDIM,
                                              Wt2 + (size_t)l * HDIM * 2 * HDIM, 2 * HDIM, 7);
    }
    wprep_kernel<<<64, 256, 0, stream>>>(dW1, Wtd, HDIM, 7);

    embed_kernel<<<(N_NODES * HDIM + 255) / 256, 256, 0, stream>>>(x, mask, flag, tok, eW, eb, h);

    hipMemsetAsync(deg, 0, (size_t)N_NODES * 4, stream);
    deg_kernel<<<(N_EDGES + 255) / 256, 256, 0, stream>>>(dst, deg);
    scan_partial_kernel<<<SCAN_NB, 256, 0, stream>>>(deg, bsum);
    scan_bsum_kernel<<<1, 128, 0, stream>>>(bsum, ebsum, rowptr);
    scan_final_kernel<<<SCAN_NB, 256, 0, stream>>>(deg, ebsum, rowptr, cursor);
    fill_bucket_kernel<<<2048, 256, 0, stream>>>(src, dst, cursor, col);

    for (int l = 0; l < L_LAYERS; ++l) {
        agg_kernel<<<(N_NODES + 3) / 4, 256, 0, stream>>>(h, rowptr, col, z);
        mfma_gemm_kernel<HDIM, true, true><<<dim3(4, 782), 256, 0, stream>>>(
            z, Wt1 + (size_t)l * HDIM * 2 * HDIM, b1 + (size_t)l * 2 * HDIM, z1, N_NODES,
            2 * HDIM);
        mfma_gemm_kernel<2 * HDIM, false, false><<<dim3(2, 782), 256, 0, stream>>>(
            z1, Wt2 + (size_t)l * HDIM * 2 * HDIM, b2 + (size_t)l * HDIM, zin, N_NODES, HDIM);
        hipMemsetAsync(stats, 0, 2 * HDIM * 4, stream);
        bnstats_kernel<<<256, 256, 0, stream>>>(zin, stats);
        bnfin_kernel<<<1, 128, 0, stream>>>(stats, gm + l * HDIM, bt + l * HDIM, sc);
        bnapply_kernel<<<(N_NODES * HDIM / 4 + 255) / 256, 256, 0, stream>>>(zin, sc, h);
    }

    mfma_gemm_kernel<HDIM, true, true><<<dim3(2, 782), 256, 0, stream>>>(h, Wtd, db1, z1, N_NODES,
                                                                         HDIM);
    hipMemsetAsync(lacc, 0, 8, stream);
    dec2_loss_kernel<<<(N_NODES + 255) / 256, 256, 0, stream>>>(z1, dW2, db2, x, mask, flag,
                                                                out + 1, lacc);
    finalize_kernel<<<1, 1, 0, stream>>>(lacc, out);
}

// Round 7
// 862.429 us; speedup vs baseline: 1.8603x; 1.1171x over previous
//
#include <hip/hip_runtime.h>
#include <cstdint>

#define N_NODES 50000
#define N_EDGES 1600000
#define HDIM 128
#define L_LAYERS 4
#define BN_EPS 1e-5f
#define SCAN_NB 98
#define SCAN_CHUNK 512

typedef __attribute__((ext_vector_type(8))) short short8v;
typedef __attribute__((ext_vector_type(4))) float f32x4;

__device__ __forceinline__ unsigned short f2bf(float f) {
    uint32_t u = __builtin_bit_cast(uint32_t, f);
    u += 0x7fff + ((u >> 16) & 1);
    return (unsigned short)(u >> 16);
}
__device__ __forceinline__ float bf2f(unsigned short b) {
    return __builtin_bit_cast(float, (uint32_t)b << 16);
}

// ---------------- mask layout detection ----------------
__global__ void detect_mask_kernel(const uint32_t* __restrict__ mw, int* __restrict__ flag) {
    __shared__ int f;
    if (threadIdx.x == 0) f = 0;
    __syncthreads();
    int found = 0;
    for (int i = threadIdx.x; i < 12500; i += blockDim.x)
        if (mw[i] > 1u) found = 1;
    if (found) f = 1;
    __syncthreads();
    if (threadIdx.x == 0) *flag = f;
}

__device__ __forceinline__ int read_mask(const void* mask, int i, int bytelayout) {
    if (bytelayout) return ((const unsigned char*)mask)[i] != 0;
    return ((const int*)mask)[i] != 0;
}

// ---------------- unified weight prep: Wt[n][k] = bf16(W[k][n]) ----------------
__global__ void wprep_all_kernel(const float* __restrict__ W1, const float* __restrict__ W2,
                                 const float* __restrict__ dW1, unsigned short* __restrict__ Wt1,
                                 unsigned short* __restrict__ Wt2,
                                 unsigned short* __restrict__ Wtd) {
    int seg = blockIdx.y;
    const float* W;
    unsigned short* Wt;
    int K, nshift;
    if (seg < 4) {
        W = W1 + (size_t)seg * HDIM * 2 * HDIM;
        Wt = Wt1 + (size_t)seg * HDIM * 2 * HDIM;
        K = HDIM;
        nshift = 8;
    } else if (seg < 8) {
        int l = seg - 4;
        W = W2 + (size_t)l * 2 * HDIM * HDIM;
        Wt = Wt2 + (size_t)l * 2 * HDIM * HDIM;
        K = 2 * HDIM;
        nshift = 7;
    } else {
        W = dW1;
        Wt = Wtd;
        K = HDIM;
        nshift = 7;
    }
    int total = K << nshift;
    for (int idx = blockIdx.x * 256 + threadIdx.x; idx < total; idx += gridDim.x * 256) {
        int k = idx >> nshift, n = idx & ((1 << nshift) - 1);
        Wt[(size_t)n * K + k] = f2bf(W[idx]);
    }
}

// ---------------- embed: h = (mask? token : x) @ W + b  (bf16 out) ----------------
__global__ void embed_kernel(const float* __restrict__ x, const void* __restrict__ mask,
                             const int* __restrict__ flag, const float* __restrict__ tok,
                             const float* __restrict__ W, const float* __restrict__ b,
                             unsigned short* __restrict__ h) {
    int idx = blockIdx.x * blockDim.x + threadIdx.x;
    if (idx >= N_NODES * HDIM) return;
    int i = idx >> 7, c = idx & 127;
    int fl = *flag;
    int m = read_mask(mask, i, fl);
    float x0 = m ? tok[0] : x[i * 3 + 0];
    float x1 = m ? tok[1] : x[i * 3 + 1];
    float x2 = m ? tok[2] : x[i * 3 + 2];
    h[idx] = f2bf(x0 * W[c] + x1 * W[HDIM + c] + x2 * W[2 * HDIM + c] + b[c]);
}

// ---------------- CSR build ----------------
__global__ void deg_kernel(const int* __restrict__ dst, int* __restrict__ deg) {
    int e = blockIdx.x * blockDim.x + threadIdx.x;
    if (e < N_EDGES) atomicAdd(&deg[__builtin_nontemporal_load(&dst[e])], 1);
}

__global__ __launch_bounds__(256) void scan_partial_kernel(const int* __restrict__ deg,
                                                           int* __restrict__ bsum) {
    __shared__ int red[256];
    int b = blockIdx.x, t = threadIdx.x;
    int base = b * SCAN_CHUNK;
    int s = 0;
    for (int i = t; i < SCAN_CHUNK; i += 256) {
        int idx = base + i;
        if (idx < N_NODES) s += deg[idx];
    }
    red[t] = s;
    __syncthreads();
    for (int o = 128; o > 0; o >>= 1) {
        if (t < o) red[t] += red[t + o];
        __syncthreads();
    }
    if (t == 0) bsum[b] = red[0];
}

__global__ __launch_bounds__(128) void scan_bsum_kernel(const int* __restrict__ bsum,
                                                        int* __restrict__ ebsum,
                                                        int* __restrict__ rowptr) {
    __shared__ int sh[128];
    int t = threadIdx.x;
    int v = (t < SCAN_NB) ? bsum[t] : 0;
    sh[t] = v;
    __syncthreads();
    for (int o = 1; o < 128; o <<= 1) {
        int u = (t >= o) ? sh[t - o] : 0;
        __syncthreads();
        sh[t] += u;
        __syncthreads();
    }
    if (t < SCAN_NB) ebsum[t] = sh[t] - v;
    if (t == 127) rowptr[N_NODES] = sh[127];
}

__global__ __launch_bounds__(256) void scan_final_kernel(const int* __restrict__ deg,
                                                         const int* __restrict__ ebsum,
                                                         int* __restrict__ rowptr,
                                                         int* __restrict__ cursor) {
    __shared__ int sh[256];
    int b = blockIdx.x, t = threadIdx.x;
    int running = ebsum[b];
    for (int t0 = 0; t0 < SCAN_CHUNK; t0 += 256) {
        int idx = b * SCAN_CHUNK + t0 + t;
        int v = (idx < N_NODES) ? deg[idx] : 0;
        sh[t] = v;
        __syncthreads();
        for (int o = 1; o < 256; o <<= 1) {
            int u = (t >= o) ? sh[t - o] : 0;
            __syncthreads();
            sh[t] += u;
            __syncthreads();
        }
        int excl = sh[t] - v + running;
        if (idx < N_NODES) {
            rowptr[idx] = excl;
            cursor[idx] = excl;
        }
        running += sh[255];
        __syncthreads();
    }
}

// bucketed fill; nontemporal edge reads so the dst/src streams don't evict
// the partially-filled col write lines from the XCD's L2.
__global__ __launch_bounds__(256) void fill_bucket_kernel(const int* __restrict__ src,
                                                          const int* __restrict__ dst,
                                                          int* __restrict__ cursor,
                                                          int* __restrict__ col) {
    int g = blockIdx.x & 7;
    int nb = gridDim.x >> 3;
    int bg = blockIdx.x >> 3;
    int lo = g * (N_NODES / 8), hi = lo + (N_NODES / 8);
    for (int e = bg * 256 + (int)threadIdx.x; e < N_EDGES; e += nb * 256) {
        int d = __builtin_nontemporal_load(&dst[e]);
        if (d >= lo && d < hi) {
            int pos = atomicAdd(&cursor[d], 1);
            col[pos] = __builtin_nontemporal_load(&src[e]);
        }
    }
}

// ---------------- aggregation (bf16 h): z[i] = h[i] + sum_{j} h[j] ----------------
__global__ __launch_bounds__(256) void agg_kernel(const unsigned short* __restrict__ h,
                                                  const int* __restrict__ rowptr,
                                                  const int* __restrict__ col,
                                                  unsigned short* __restrict__ z) {
    int wid = threadIdx.x >> 6;
    int lane = threadIdx.x & 63;
    int i = blockIdx.x * 4 + wid;
    if (i >= N_NODES) return;
    int start = rowptr[i], end = rowptr[i + 1];
    const uint32_t* h32 = (const uint32_t*)h;
    uint32_t u = h32[(size_t)i * 64 + lane];
    float ax = __builtin_bit_cast(float, u << 16);
    float ay = __builtin_bit_cast(float, u & 0xffff0000u);
    float bx = 0.f, by = 0.f, cx = 0.f, cy = 0.f, dx = 0.f, dy = 0.f;
    int e = start;
    for (; e + 4 <= end; e += 4) {
        int j0 = col[e + 0], j1 = col[e + 1], j2 = col[e + 2], j3 = col[e + 3];
        uint32_t u0 = h32[(size_t)j0 * 64 + lane];
        uint32_t u1 = h32[(size_t)j1 * 64 + lane];
        uint32_t u2 = h32[(size_t)j2 * 64 + lane];
        uint32_t u3 = h32[(size_t)j3 * 64 + lane];
        ax += __builtin_bit_cast(float, u0 << 16);
        ay += __builtin_bit_cast(float, u0 & 0xffff0000u);
        bx += __builtin_bit_cast(float, u1 << 16);
        by += __builtin_bit_cast(float, u1 & 0xffff0000u);
        cx += __builtin_bit_cast(float, u2 << 16);
        cy += __builtin_bit_cast(float, u2 & 0xffff0000u);
        dx += __builtin_bit_cast(float, u3 << 16);
        dy += __builtin_bit_cast(float, u3 & 0xffff0000u);
    }
    for (; e < end; ++e) {
        uint32_t u0 = h32[(size_t)col[e] * 64 + lane];
        ax += __builtin_bit_cast(float, u0 << 16);
        ay += __builtin_bit_cast(float, u0 & 0xffff0000u);
    }
    ax += bx + cx + dx;
    ay += by + cy + dy;
    uint32_t o = (uint32_t)f2bf(ax) | ((uint32_t)f2bf(ay) << 16);
    ((uint32_t*)z)[(size_t)i * 64 + lane] = o;
}

// ---------------- bf16 MFMA GEMM (optional fused BN-stats epilogue) ----------------
// C/D frag layout: col = lane&15 (within 16), row = (lane>>4)*4 + reg.
template <int K, bool OUT_BF16, bool RELU, bool STATS>
__global__ __launch_bounds__(256) void mfma_gemm_kernel(const unsigned short* __restrict__ A,
                                                        const unsigned short* __restrict__ Wt,
                                                        const float* __restrict__ bias,
                                                        void* __restrict__ C,
                                                        float* __restrict__ stats, int M,
                                                        int ldc) {
    __shared__ float sred[4][2][64];
    const int lane = threadIdx.x & 63;
    const int w = threadIdx.x >> 6;
    const int row0 = blockIdx.y * 64 + w * 16;
    const int col0 = blockIdx.x * 64;
    const int r = lane & 15;
    const int ks = lane >> 4;
    const int arow = min(row0 + r, M - 1);
    f32x4 acc[4];
#pragma unroll
    for (int n = 0; n < 4; ++n) acc[n] = (f32x4){0.f, 0.f, 0.f, 0.f};
#pragma unroll
    for (int k0 = 0; k0 < K; k0 += 32) {
        short8v a = *(const short8v*)&A[(size_t)arow * K + k0 + ks * 8];
#pragma unroll
        for (int n = 0; n < 4; ++n) {
            short8v b = *(const short8v*)&Wt[(size_t)(col0 + n * 16 + r) * K + k0 + ks * 8];
            acc[n] = __builtin_amdgcn_mfma_f32_16x16x32_bf16(a, b, acc[n], 0, 0, 0);
        }
    }
#pragma unroll
    for (int n = 0; n < 4; ++n) {
        const int col = col0 + n * 16 + r;
        const float bv = bias[col];
        float s = 0.f, ss = 0.f;
#pragma unroll
        for (int i = 0; i < 4; ++i) {
            int row = row0 + ks * 4 + i;
            if (row < M) {
                float o = acc[n][i] + bv;
                if (RELU) o = fmaxf(o, 0.f);
                if (STATS) {
                    s += o;
                    ss += o * o;
                }
                if (OUT_BF16)
                    ((unsigned short*)C)[(size_t)row * ldc + col] = f2bf(o);
                else
                    ((float*)C)[(size_t)row * ldc + col] = o;
            }
        }
        if (STATS) {
            // reduce across the 4 ks-lanes holding the same column
            s += __shfl_xor(s, 16);
            s += __shfl_xor(s, 32);
            ss += __shfl_xor(ss, 16);
            ss += __shfl_xor(ss, 32);
            if (ks == 0) {
                sred[w][0][n * 16 + r] = s;
                sred[w][1][n * 16 + r] = ss;
            }
        }
    }
    if (STATS) {
        __syncthreads();
        int t = threadIdx.x;
        if (t < 64) {
            float s = sred[0][0][t] + sred[1][0][t] + sred[2][0][t] + sred[3][0][t];
            float ss = sred[0][1][t] + sred[1][1][t] + sred[2][1][t] + sred[3][1][t];
            atomicAdd(&stats[col0 + t], s);
            atomicAdd(&stats[HDIM + col0 + t], ss);
        }
    }
}

// ---------------- BN apply (scale/shift recomputed per block from stats) ----------------
__global__ void bnapply_kernel(const float* __restrict__ zin, const float* __restrict__ stats,
                               const float* __restrict__ gamma, const float* __restrict__ beta,
                               unsigned short* __restrict__ h) {
    __shared__ float ssc[2 * HDIM];
    int t = threadIdx.x;
    if (t < HDIM) {
        float mean = stats[t] * (1.f / N_NODES);
        float var = stats[HDIM + t] * (1.f / N_NODES) - mean * mean;
        float rstd = rsqrtf(fmaxf(var, 0.f) + BN_EPS);
        float s = gamma[t] * rstd;
        ssc[t] = s;
        ssc[HDIM + t] = beta[t] - mean * s;
    }
    __syncthreads();
    int idx = blockIdx.x * blockDim.x + threadIdx.x;
    if (idx >= N_NODES * HDIM / 4) return;
    float4 v = ((const float4*)zin)[idx];
    int c = (idx * 4) & 127;
    float o0 = fmaxf(v.x * ssc[c + 0] + ssc[HDIM + c + 0], 0.f);
    float o1 = fmaxf(v.y * ssc[c + 1] + ssc[HDIM + c + 1], 0.f);
    float o2 = fmaxf(v.z * ssc[c + 2] + ssc[HDIM + c + 2], 0.f);
    float o3 = fmaxf(v.w * ssc[c + 3] + ssc[HDIM + c + 3], 0.f);
    uint2 p;
    p.x = (uint32_t)f2bf(o0) | ((uint32_t)f2bf(o1) << 16);
    p.y = (uint32_t)f2bf(o2) | ((uint32_t)f2bf(o3) << 16);
    ((uint2*)h)[idx] = p;
}

// ---------------- decoder stage2 + loss: one thread per node ----------------
__global__ __launch_bounds__(256) void dec2_loss_kernel(
    const unsigned short* __restrict__ d1, const float* __restrict__ W2,
    const float* __restrict__ b2, const float* __restrict__ x, const void* __restrict__ mask,
    const int* __restrict__ flag, float* __restrict__ recon, float* __restrict__ acc) {
    __shared__ float w2s[HDIM * 3];
    for (int t = threadIdx.x; t < HDIM * 3; t += 256) w2s[t] = W2[t];
    __syncthreads();
    int i = blockIdx.x * 256 + threadIdx.x;
    int fl = *flag;
    float lsum = 0.f, lcnt = 0.f;
    if (i < N_NODES) {
        float s0 = 0.f, s1 = 0.f, s2 = 0.f;
        const unsigned short* row = &d1[(size_t)i * HDIM];
#pragma unroll
        for (int k0 = 0; k0 < HDIM; k0 += 8) {
            short8v v = *(const short8v*)&row[k0];
#pragma unroll
            for (int q = 0; q < 8; ++q) {
                float a = bf2f((unsigned short)v[q]);
                s0 = fmaf(a, w2s[(k0 + q) * 3 + 0], s0);
                s1 = fmaf(a, w2s[(k0 + q) * 3 + 1], s1);
                s2 = fmaf(a, w2s[(k0 + q) * 3 + 2], s2);
            }
        }
        float r0 = s0 + b2[0], r1 = s1 + b2[1], r2 = s2 + b2[2];
        recon[(size_t)i * 3 + 0] = r0;
        recon[(size_t)i * 3 + 1] = r1;
        recon[(size_t)i * 3 + 2] = r2;
        if (read_mask(mask, i, fl)) {
            float rn = fmaxf(sqrtf(r0 * r0 + r1 * r1 + r2 * r2), 1e-12f);
            float x0 = x[i * 3 + 0], x1 = x[i * 3 + 1], x2 = x[i * 3 + 2];
            float xn = fmaxf(sqrtf(x0 * x0 + x1 * x1 + x2 * x2), 1e-12f);
            float cs = (r0 * x0 + r1 * x1 + r2 * x2) / (rn * xn);
            float d = 1.f - cs;
            lsum = d * d;
            lcnt = 1.f;
        }
    }
#pragma unroll
    for (int o = 32; o > 0; o >>= 1) {
        lsum += __shfl_xor(lsum, o);
        lcnt += __shfl_xor(lcnt, o);
    }
    if ((threadIdx.x & 63) == 0 && lcnt != 0.f) {
        atomicAdd(&acc[0], lsum);
        atomicAdd(&acc[1], lcnt);
    }
}

__global__ void finalize_kernel(const float* __restrict__ acc, float* __restrict__ out) {
    out[0] = acc[0] / fmaxf(acc[1], 1.f);
}

// ---------------- launcher ----------------
extern "C" void kernel_launch(void* const* d_in, const int* in_sizes, int n_in, void* d_out,
                              int out_size, void* d_ws, size_t ws_size, hipStream_t stream) {
    const float* x = (const float*)d_in[0];
    const int* ei = (const int*)d_in[1];
    const int* src = ei;
    const int* dst = ei + N_EDGES;
    const void* mask = d_in[3];
    const float* tok = (const float*)d_in[4];
    const float* eW = (const float*)d_in[5];
    const float* eb = (const float*)d_in[6];
    const float* W1 = (const float*)d_in[7];
    const float* b1 = (const float*)d_in[8];
    const float* W2 = (const float*)d_in[9];
    const float* b2 = (const float*)d_in[10];
    const float* gm = (const float*)d_in[11];
    const float* bt = (const float*)d_in[12];
    const float* dW1 = (const float*)d_in[13];
    const float* db1 = (const float*)d_in[14];
    const float* dW2 = (const float*)d_in[15];
    const float* db2 = (const float*)d_in[16];
    float* out = (float*)d_out;

    char* ws = (char*)d_ws;
    size_t off = 0;
    auto alloc = [&](size_t bytes) -> void* {
        void* p = ws + off;
        off = (off + bytes + 255) & ~(size_t)255;
        return p;
    };
    unsigned short* h = (unsigned short*)alloc((size_t)N_NODES * HDIM * 2);
    unsigned short* z = (unsigned short*)alloc((size_t)N_NODES * HDIM * 2);
    unsigned short* z1 = (unsigned short*)alloc((size_t)N_NODES * 2 * HDIM * 2);
    float* zin = (float*)alloc((size_t)N_NODES * HDIM * 4);
    unsigned short* Wt1 = (unsigned short*)alloc((size_t)L_LAYERS * HDIM * 2 * HDIM * 2);
    unsigned short* Wt2 = (unsigned short*)alloc((size_t)L_LAYERS * HDIM * 2 * HDIM * 2);
    unsigned short* Wtd = (unsigned short*)alloc((size_t)HDIM * HDIM * 2);
    int* deg = (int*)alloc((size_t)N_NODES * 4);
    int* rowptr = (int*)alloc((size_t)(N_NODES + 1) * 4);
    int* cursor = (int*)alloc((size_t)N_NODES * 4);
    int* col = (int*)alloc((size_t)N_EDGES * 4);
    int* bsum = (int*)alloc((size_t)SCAN_NB * 4);
    int* ebsum = (int*)alloc((size_t)SCAN_NB * 4);
    float* stats = (float*)alloc((size_t)L_LAYERS * 2 * HDIM * 4);
    float* lacc = (float*)alloc(8);
    int* flag = (int*)alloc(4);

    detect_mask_kernel<<<1, 256, 0, stream>>>((const uint32_t*)mask, flag);
    wprep_all_kernel<<<dim3(32, 9), 256, 0, stream>>>(W1, W2, dW1, Wt1, Wt2, Wtd);
    embed_kernel<<<(N_NODES * HDIM + 255) / 256, 256, 0, stream>>>(x, mask, flag, tok, eW, eb, h);

    hipMemsetAsync(deg, 0, (size_t)N_NODES * 4, stream);
    hipMemsetAsync(stats, 0, (size_t)L_LAYERS * 2 * HDIM * 4, stream);
    hipMemsetAsync(lacc, 0, 8, stream);
    deg_kernel<<<(N_EDGES + 255) / 256, 256, 0, stream>>>(dst, deg);
    scan_partial_kernel<<<SCAN_NB, 256, 0, stream>>>(deg, bsum);
    scan_bsum_kernel<<<1, 128, 0, stream>>>(bsum, ebsum, rowptr);
    scan_final_kernel<<<SCAN_NB, 256, 0, stream>>>(deg, ebsum, rowptr, cursor);
    fill_bucket_kernel<<<2048, 256, 0, stream>>>(src, dst, cursor, col);

    for (int l = 0; l < L_LAYERS; ++l) {
        float* lstats = stats + (size_t)l * 2 * HDIM;
        agg_kernel<<<(N_NODES + 3) / 4, 256, 0, stream>>>(h, rowptr, col, z);
        mfma_gemm_kernel<HDIM, true, true, false><<<dim3(4, 782), 256, 0, stream>>>(
            z, Wt1 + (size_t)l * HDIM * 2 * HDIM, b1 + (size_t)l * 2 * HDIM, z1, nullptr, N_NODES,
            2 * HDIM);
        mfma_gemm_kernel<2 * HDIM, false, false, true><<<dim3(2, 782), 256, 0, stream>>>(
            z1, Wt2 + (size_t)l * HDIM * 2 * HDIM, b2 + (size_t)l * HDIM, zin, lstats, N_NODES,
            HDIM);
        bnapply_kernel<<<(N_NODES * HDIM / 4 + 255) / 256, 256, 0, stream>>>(
            zin, lstats, gm + l * HDIM, bt + l * HDIM, h);
    }

    mfma_gemm_kernel<HDIM, true, true, false><<<dim3(2, 782), 256, 0, stream>>>(
        h, Wtd, db1, z1, nullptr, N_NODES, HDIM);
    dec2_loss_kernel<<<(N_NODES + 255) / 256, 256, 0, stream>>>(z1, dW2, db2, x, mask, flag,
                                                                out + 1, lacc);
    finalize_kernel<<<1, 1, 0, stream>>>(lacc, out);
}

// Round 9
// 820.671 us; speedup vs baseline: 1.9550x; 1.0509x over previous
//
#include <hip/hip_runtime.h>
#include <cstdint>

#define N_NODES 50000
#define N_EDGES 1600000
#define HDIM 128
#define L_LAYERS 4
#define BN_EPS 1e-5f
#define SCAN_NB 98
#define SCAN_CHUNK 512
#define NPART 49
#define PART_SHIFT 10
#define PB_CHUNK 6250  // N_EDGES / 256 exactly

typedef __attribute__((ext_vector_type(8))) short short8v;
typedef __attribute__((ext_vector_type(4))) float f32x4;

__device__ __forceinline__ unsigned short f2bf(float f) {
    uint32_t u = __builtin_bit_cast(uint32_t, f);
    u += 0x7fff + ((u >> 16) & 1);
    return (unsigned short)(u >> 16);
}
__device__ __forceinline__ float bf2f(unsigned short b) {
    return __builtin_bit_cast(float, (uint32_t)b << 16);
}

// ---------------- mask layout detection ----------------
__global__ void detect_mask_kernel(const uint32_t* __restrict__ mw, int* __restrict__ flag) {
    __shared__ int f;
    if (threadIdx.x == 0) f = 0;
    __syncthreads();
    int found = 0;
    for (int i = threadIdx.x; i < 12500; i += blockDim.x)
        if (mw[i] > 1u) found = 1;
    if (found) f = 1;
    __syncthreads();
    if (threadIdx.x == 0) *flag = f;
}

__device__ __forceinline__ int read_mask(const void* mask, int i, int bytelayout) {
    if (bytelayout) return ((const unsigned char*)mask)[i] != 0;
    return ((const int*)mask)[i] != 0;
}

// ---------------- unified weight prep: Wt[n][k] = bf16(W[k][n]) ----------------
__global__ void wprep_all_kernel(const float* __restrict__ W1, const float* __restrict__ W2,
                                 const float* __restrict__ dW1, unsigned short* __restrict__ Wt1,
                                 unsigned short* __restrict__ Wt2,
                                 unsigned short* __restrict__ Wtd) {
    int seg = blockIdx.y;
    const float* W;
    unsigned short* Wt;
    int K, nshift;
    if (seg < 4) {
        W = W1 + (size_t)seg * HDIM * 2 * HDIM;
        Wt = Wt1 + (size_t)seg * HDIM * 2 * HDIM;
        K = HDIM;
        nshift = 8;
    } else if (seg < 8) {
        int l = seg - 4;
        W = W2 + (size_t)l * 2 * HDIM * HDIM;
        Wt = Wt2 + (size_t)l * 2 * HDIM * HDIM;
        K = 2 * HDIM;
        nshift = 7;
    } else {
        W = dW1;
        Wt = Wtd;
        K = HDIM;
        nshift = 7;
    }
    int total = K << nshift;
    for (int idx = blockIdx.x * 256 + threadIdx.x; idx < total; idx += gridDim.x * 256) {
        int k = idx >> nshift, n = idx & ((1 << nshift) - 1);
        Wt[(size_t)n * K + k] = f2bf(W[idx]);
    }
}

// ---------------- embed ----------------
__global__ void embed_kernel(const float* __restrict__ x, const void* __restrict__ mask,
                             const int* __restrict__ flag, const float* __restrict__ tok,
                             const float* __restrict__ W, const float* __restrict__ b,
                             unsigned short* __restrict__ h) {
    int idx = blockIdx.x * blockDim.x + threadIdx.x;
    if (idx >= N_NODES * HDIM) return;
    int i = idx >> 7, c = idx & 127;
    int fl = *flag;
    int m = read_mask(mask, i, fl);
    float x0 = m ? tok[0] : x[i * 3 + 0];
    float x1 = m ? tok[1] : x[i * 3 + 1];
    float x2 = m ? tok[2] : x[i * 3 + 2];
    h[idx] = f2bf(x0 * W[c] + x1 * W[HDIM + c] + x2 * W[2 * HDIM + c] + b[c]);
}

// ---------------- CSR build ----------------
__global__ void deg_kernel(const int* __restrict__ dst, int* __restrict__ deg) {
    int e = blockIdx.x * blockDim.x + threadIdx.x;
    if (e < N_EDGES) atomicAdd(&deg[__builtin_nontemporal_load(&dst[e])], 1);
}

__global__ __launch_bounds__(256) void scan_partial_kernel(const int* __restrict__ deg,
                                                           int* __restrict__ bsum) {
    __shared__ int red[256];
    int b = blockIdx.x, t = threadIdx.x;
    int base = b * SCAN_CHUNK;
    int s = 0;
    for (int i = t; i < SCAN_CHUNK; i += 256) {
        int idx = base + i;
        if (idx < N_NODES) s += deg[idx];
    }
    red[t] = s;
    __syncthreads();
    for (int o = 128; o > 0; o >>= 1) {
        if (t < o) red[t] += red[t + o];
        __syncthreads();
    }
    if (t == 0) bsum[b] = red[0];
}

__global__ __launch_bounds__(128) void scan_bsum_kernel(const int* __restrict__ bsum,
                                                        int* __restrict__ ebsum,
                                                        int* __restrict__ rowptr) {
    __shared__ int sh[128];
    int t = threadIdx.x;
    int v = (t < SCAN_NB) ? bsum[t] : 0;
    sh[t] = v;
    __syncthreads();
    for (int o = 1; o < 128; o <<= 1) {
        int u = (t >= o) ? sh[t - o] : 0;
        __syncthreads();
        sh[t] += u;
        __syncthreads();
    }
    if (t < SCAN_NB) ebsum[t] = sh[t] - v;
    if (t == 127) rowptr[N_NODES] = sh[127];
}

__global__ __launch_bounds__(256) void scan_final_kernel(const int* __restrict__ deg,
                                                         const int* __restrict__ ebsum,
                                                         int* __restrict__ rowptr,
                                                         int* __restrict__ cursor) {
    __shared__ int sh[256];
    int b = blockIdx.x, t = threadIdx.x;
    int running = ebsum[b];
    for (int t0 = 0; t0 < SCAN_CHUNK; t0 += 256) {
        int idx = b * SCAN_CHUNK + t0 + t;
        int v = (idx < N_NODES) ? deg[idx] : 0;
        sh[t] = v;
        __syncthreads();
        for (int o = 1; o < 256; o <<= 1) {
            int u = (t >= o) ? sh[t - o] : 0;
            __syncthreads();
            sh[t] += u;
            __syncthreads();
        }
        int excl = sh[t] - v + running;
        if (idx < N_NODES) {
            rowptr[idx] = excl;
            cursor[idx] = excl;
        }
        running += sh[255];
        __syncthreads();
    }
}

__global__ void pcur_init_kernel(const int* __restrict__ rowptr, int* __restrict__ pcursor) {
    int p = threadIdx.x;
    if (p < NPART) pcursor[p] = rowptr[p << PART_SHIFT];
}

// pass 1: radix-partition edges by dst>>10 into (dst,src) packed u64, dense runs.
__global__ __launch_bounds__(256) void partition_kernel(const int* __restrict__ src,
                                                        const int* __restrict__ dst,
                                                        int* __restrict__ pcursor,
                                                        uint64_t* __restrict__ pairs) {
    __shared__ unsigned short dstl[PB_CHUNK];
    __shared__ int srcl[PB_CHUNK];
    __shared__ int hist[NPART];
    __shared__ int off[NPART];
    int b = blockIdx.x, t = threadIdx.x;
    int lo = b * PB_CHUNK;
    for (int i = t; i < NPART; i += 256) hist[i] = 0;
    __syncthreads();
    for (int i = t; i < PB_CHUNK; i += 256) {
        int d = __builtin_nontemporal_load(&dst[lo + i]);
        int s = __builtin_nontemporal_load(&src[lo + i]);
        dstl[i] = (unsigned short)d;
        srcl[i] = s;
        atomicAdd(&hist[d >> PART_SHIFT], 1);
    }
    __syncthreads();
    for (int i = t; i < NPART; i += 256) off[i] = atomicAdd(&pcursor[i], hist[i]);
    __syncthreads();
    for (int i = t; i < PB_CHUNK; i += 256) {
        int d = (int)dstl[i];
        int pos = atomicAdd(&off[d >> PART_SHIFT], 1);
        pairs[pos] = ((uint64_t)(uint32_t)srcl[i] << 32) | (uint32_t)d;
    }
}

// pass 2: scatter within one partition (~130KB col window, ~4KB cursor window).
__global__ __launch_bounds__(256) void fill_part_kernel(const uint64_t* __restrict__ pairs,
                                                        const int* __restrict__ rowptr,
                                                        int* __restrict__ cursor,
                                                        int* __restrict__ col) {
    int p = blockIdx.x >> 4, sub = blockIdx.x & 15;
    int start = rowptr[p << PART_SHIFT];
    int end = rowptr[min((p + 1) << PART_SHIFT, N_NODES)];
    for (int e = start + sub * 256 + (int)threadIdx.x; e < end; e += 16 * 256) {
        uint64_t pr = __builtin_nontemporal_load(&pairs[e]);
        int d = (int)(uint32_t)pr;
        int s = (int)(uint32_t)(pr >> 32);
        int pos = atomicAdd(&cursor[d], 1);
        col[pos] = s;
    }
}

// ---------------- aggregation (bf16 h): z[i] = h[i] + sum_{j} h[j] ----------------
__global__ __launch_bounds__(256) void agg_kernel(const unsigned short* __restrict__ h,
                                                  const int* __restrict__ rowptr,
                                                  const int* __restrict__ col,
                                                  unsigned short* __restrict__ z) {
    int wid = threadIdx.x >> 6;
    int lane = threadIdx.x & 63;
    int i = blockIdx.x * 4 + wid;
    if (i >= N_NODES) return;
    int start = rowptr[i], end = rowptr[i + 1];
    const uint32_t* h32 = (const uint32_t*)h;
    uint32_t u = h32[(size_t)i * 64 + lane];
    float ax = __builtin_bit_cast(float, u << 16);
    float ay = __builtin_bit_cast(float, u & 0xffff0000u);
    float bx = 0.f, by = 0.f, cx = 0.f, cy = 0.f, dx = 0.f, dy = 0.f;
    int e = start;
    for (; e + 4 <= end; e += 4) {
        int j0 = col[e + 0], j1 = col[e + 1], j2 = col[e + 2], j3 = col[e + 3];
        uint32_t u0 = h32[(size_t)j0 * 64 + lane];
        uint32_t u1 = h32[(size_t)j1 * 64 + lane];
        uint32_t u2 = h32[(size_t)j2 * 64 + lane];
        uint32_t u3 = h32[(size_t)j3 * 64 + lane];
        ax += __builtin_bit_cast(float, u0 << 16);
        ay += __builtin_bit_cast(float, u0 & 0xffff0000u);
        bx += __builtin_bit_cast(float, u1 << 16);
        by += __builtin_bit_cast(float, u1 & 0xffff0000u);
        cx += __builtin_bit_cast(float, u2 << 16);
        cy += __builtin_bit_cast(float, u2 & 0xffff0000u);
        dx += __builtin_bit_cast(float, u3 << 16);
        dy += __builtin_bit_cast(float, u3 & 0xffff0000u);
    }
    for (; e < end; ++e) {
        uint32_t u0 = h32[(size_t)col[e] * 64 + lane];
        ax += __builtin_bit_cast(float, u0 << 16);
        ay += __builtin_bit_cast(float, u0 & 0xffff0000u);
    }
    ax += bx + cx + dx;
    ay += by + cy + dy;
    uint32_t o = (uint32_t)f2bf(ax) | ((uint32_t)f2bf(ay) << 16);
    ((uint32_t*)z)[(size_t)i * 64 + lane] = o;
}

// ---------------- fused layer: zin = relu(z@W1+b1)@W2+b2, stats epilogue ----------------
// block = 64-row stripe, 4 waves; z1 stripe lives in LDS (bf16, pad 260 to break banks).
__global__ __launch_bounds__(256) void fused_layer_kernel(
    const unsigned short* __restrict__ z, const unsigned short* __restrict__ Wt1,
    const float* __restrict__ b1, const unsigned short* __restrict__ Wt2,
    const float* __restrict__ b2, float* __restrict__ zin, float* __restrict__ stats, int M) {
    __shared__ unsigned short z1l[64 * 260];
    __shared__ float sred[4][2][HDIM];
    const int lane = threadIdx.x & 63;
    const int w = threadIdx.x >> 6;
    const int r = lane & 15, ks = lane >> 4;
    const int row0 = blockIdx.x * 64 + w * 16;
    const int arow = min(row0 + r, M - 1);
    // phase A: z1[w*16..+16][0..256) = relu(z @ W1 + b1) -> LDS
    short8v a4[4];
#pragma unroll
    for (int kk = 0; kk < 4; ++kk)
        a4[kk] = *(const short8v*)&z[(size_t)arow * HDIM + kk * 32 + ks * 8];
#pragma unroll
    for (int n = 0; n < 16; ++n) {
        f32x4 acc = (f32x4){0.f, 0.f, 0.f, 0.f};
#pragma unroll
        for (int kk = 0; kk < 4; ++kk) {
            short8v bf = *(const short8v*)&Wt1[(size_t)(n * 16 + r) * HDIM + kk * 32 + ks * 8];
            acc = __builtin_amdgcn_mfma_f32_16x16x32_bf16(a4[kk], bf, acc, 0, 0, 0);
        }
        float bv = b1[n * 16 + r];
#pragma unroll
        for (int i = 0; i < 4; ++i) {
            float o = fmaxf(acc[i] + bv, 0.f);
            z1l[(w * 16 + ks * 4 + i) * 260 + n * 16 + r] = f2bf(o);
        }
    }
    __syncthreads();
    // phase B: zin[w*16..+16][0..128) = z1 @ W2 + b2
    f32x4 accb[8];
#pragma unroll
    for (int n = 0; n < 8; ++n) accb[n] = (f32x4){0.f, 0.f, 0.f, 0.f};
#pragma unroll
    for (int k0 = 0; k0 < 256; k0 += 32) {
        short8v a = *(const short8v*)&z1l[(w * 16 + r) * 260 + k0 + ks * 8];
#pragma unroll
        for (int n = 0; n < 8; ++n) {
            short8v bf = *(const short8v*)&Wt2[(size_t)(n * 16 + r) * 256 + k0 + ks * 8];
            accb[n] = __builtin_amdgcn_mfma_f32_16x16x32_bf16(a, bf, accb[n], 0, 0, 0);
        }
    }
#pragma unroll
    for (int n = 0; n < 8; ++n) {
        const int cc = n * 16 + r;
        const float bv = b2[cc];
        float s = 0.f, ss = 0.f;
#pragma unroll
        for (int i = 0; i < 4; ++i) {
            int row = row0 + ks * 4 + i;
            if (row < M) {
                float o = accb[n][i] + bv;
                s += o;
                ss += o * o;
                zin[(size_t)row * HDIM + cc] = o;
            }
        }
        s += __shfl_xor(s, 16);
        s += __shfl_xor(s, 32);
        ss += __shfl_xor(ss, 16);
        ss += __shfl_xor(ss, 32);
        if (ks == 0) {
            sred[w][0][cc] = s;
            sred[w][1][cc] = ss;
        }
    }
    __syncthreads();
    int t = threadIdx.x;
    if (t < HDIM) {
        float s = sred[0][0][t] + sred[1][0][t] + sred[2][0][t] + sred[3][0][t];
        float ss = sred[0][1][t] + sred[1][1][t] + sred[2][1][t] + sred[3][1][t];
        atomicAdd(&stats[t], s);
        atomicAdd(&stats[HDIM + t], ss);
    }
}

// ---------------- plain MFMA GEMM (decoder stage 1) ----------------
template <int K, bool OUT_BF16, bool RELU>
__global__ __launch_bounds__(256) void mfma_gemm_kernel(const unsigned short* __restrict__ A,
                                                        const unsigned short* __restrict__ Wt,
                                                        const float* __restrict__ bias,
                                                        void* __restrict__ C, int M, int ldc) {
    const int lane = threadIdx.x & 63;
    const int w = threadIdx.x >> 6;
    const int row0 = blockIdx.y * 64 + w * 16;
    const int col0 = blockIdx.x * 64;
    const int r = lane & 15;
    const int ks = lane >> 4;
    const int arow = min(row0 + r, M - 1);
    f32x4 acc[4];
#pragma unroll
    for (int n = 0; n < 4; ++n) acc[n] = (f32x4){0.f, 0.f, 0.f, 0.f};
#pragma unroll
    for (int k0 = 0; k0 < K; k0 += 32) {
        short8v a = *(const short8v*)&A[(size_t)arow * K + k0 + ks * 8];
#pragma unroll
        for (int n = 0; n < 4; ++n) {
            short8v b = *(const short8v*)&Wt[(size_t)(col0 + n * 16 + r) * K + k0 + ks * 8];
            acc[n] = __builtin_amdgcn_mfma_f32_16x16x32_bf16(a, b, acc[n], 0, 0, 0);
        }
    }
#pragma unroll
    for (int n = 0; n < 4; ++n) {
        const int col = col0 + n * 16 + r;
        const float bv = bias[col];
#pragma unroll
        for (int i = 0; i < 4; ++i) {
            int row = row0 + ks * 4 + i;
            if (row < M) {
                float o = acc[n][i] + bv;
                if (RELU) o = fmaxf(o, 0.f);
                if (OUT_BF16)
                    ((unsigned short*)C)[(size_t)row * ldc + col] = f2bf(o);
                else
                    ((float*)C)[(size_t)row * ldc + col] = o;
            }
        }
    }
}

// ---------------- BN apply ----------------
__global__ void bnapply_kernel(const float* __restrict__ zin, const float* __restrict__ stats,
                               const float* __restrict__ gamma, const float* __restrict__ beta,
                               unsigned short* __restrict__ h) {
    __shared__ float ssc[2 * HDIM];
    int t = threadIdx.x;
    if (t < HDIM) {
        float mean = stats[t] * (1.f / N_NODES);
        float var = stats[HDIM + t] * (1.f / N_NODES) - mean * mean;
        float rstd = rsqrtf(fmaxf(var, 0.f) + BN_EPS);
        float s = gamma[t] * rstd;
        ssc[t] = s;
        ssc[HDIM + t] = beta[t] - mean * s;
    }
    __syncthreads();
    int idx = blockIdx.x * blockDim.x + threadIdx.x;
    if (idx >= N_NODES * HDIM / 4) return;
    float4 v = ((const float4*)zin)[idx];
    int c = (idx * 4) & 127;
    float o0 = fmaxf(v.x * ssc[c + 0] + ssc[HDIM + c + 0], 0.f);
    float o1 = fmaxf(v.y * ssc[c + 1] + ssc[HDIM + c + 1], 0.f);
    float o2 = fmaxf(v.z * ssc[c + 2] + ssc[HDIM + c + 2], 0.f);
    float o3 = fmaxf(v.w * ssc[c + 3] + ssc[HDIM + c + 3], 0.f);
    uint2 p;
    p.x = (uint32_t)f2bf(o0) | ((uint32_t)f2bf(o1) << 16);
    p.y = (uint32_t)f2bf(o2) | ((uint32_t)f2bf(o3) << 16);
    ((uint2*)h)[idx] = p;
}

// ---------------- decoder stage2 + loss: one thread per node ----------------
__global__ __launch_bounds__(256) void dec2_loss_kernel(
    const unsigned short* __restrict__ d1, const float* __restrict__ W2,
    const float* __restrict__ b2, const float* __restrict__ x, const void* __restrict__ mask,
    const int* __restrict__ flag, float* __restrict__ recon, float* __restrict__ acc) {
    __shared__ float w2s[HDIM * 3];
    for (int t = threadIdx.x; t < HDIM * 3; t += 256) w2s[t] = W2[t];
    __syncthreads();
    int i = blockIdx.x * 256 + threadIdx.x;
    int fl = *flag;
    float lsum = 0.f, lcnt = 0.f;
    if (i < N_NODES) {
        float s0 = 0.f, s1 = 0.f, s2 = 0.f;
        const unsigned short* row = &d1[(size_t)i * HDIM];
#pragma unroll
        for (int k0 = 0; k0 < HDIM; k0 += 8) {
            short8v v = *(const short8v*)&row[k0];
#pragma unroll
            for (int q = 0; q < 8; ++q) {
                float a = bf2f((unsigned short)v[q]);
                s0 = fmaf(a, w2s[(k0 + q) * 3 + 0], s0);
                s1 = fmaf(a, w2s[(k0 + q) * 3 + 1], s1);
                s2 = fmaf(a, w2s[(k0 + q) * 3 + 2], s2);
            }
        }
        float r0 = s0 + b2[0], r1 = s1 + b2[1], r2 = s2 + b2[2];
        recon[(size_t)i * 3 + 0] = r0;
        recon[(size_t)i * 3 + 1] = r1;
        recon[(size_t)i * 3 + 2] = r2;
        if (read_mask(mask, i, fl)) {
            float rn = fmaxf(sqrtf(r0 * r0 + r1 * r1 + r2 * r2), 1e-12f);
            float x0 = x[i * 3 + 0], x1 = x[i * 3 + 1], x2 = x[i * 3 + 2];
            float xn = fmaxf(sqrtf(x0 * x0 + x1 * x1 + x2 * x2), 1e-12f);
            float cs = (r0 * x0 + r1 * x1 + r2 * x2) / (rn * xn);
            float d = 1.f - cs;
            lsum = d * d;
            lcnt = 1.f;
        }
    }
#pragma unroll
    for (int o = 32; o > 0; o >>= 1) {
        lsum += __shfl_xor(lsum, o);
        lcnt += __shfl_xor(lcnt, o);
    }
    if ((threadIdx.x & 63) == 0 && lcnt != 0.f) {
        atomicAdd(&acc[0], lsum);
        atomicAdd(&acc[1], lcnt);
    }
}

__global__ void finalize_kernel(const float* __restrict__ acc, float* __restrict__ out) {
    out[0] = acc[0] / fmaxf(acc[1], 1.f);
}

// ---------------- launcher ----------------
extern "C" void kernel_launch(void* const* d_in, const int* in_sizes, int n_in, void* d_out,
                              int out_size, void* d_ws, size_t ws_size, hipStream_t stream) {
    const float* x = (const float*)d_in[0];
    const int* ei = (const int*)d_in[1];
    const int* src = ei;
    const int* dst = ei + N_EDGES;
    const void* mask = d_in[3];
    const float* tok = (const float*)d_in[4];
    const float* eW = (const float*)d_in[5];
    const float* eb = (const float*)d_in[6];
    const float* W1 = (const float*)d_in[7];
    const float* b1 = (const float*)d_in[8];
    const float* W2 = (const float*)d_in[9];
    const float* b2 = (const float*)d_in[10];
    const float* gm = (const float*)d_in[11];
    const float* bt = (const float*)d_in[12];
    const float* dW1 = (const float*)d_in[13];
    const float* db1 = (const float*)d_in[14];
    const float* dW2 = (const float*)d_in[15];
    const float* db2 = (const float*)d_in[16];
    float* out = (float*)d_out;

    char* ws = (char*)d_ws;
    size_t off = 0;
    auto alloc = [&](size_t bytes) -> void* {
        void* p = ws + off;
        off = (off + bytes + 255) & ~(size_t)255;
        return p;
    };
    unsigned short* h = (unsigned short*)alloc((size_t)N_NODES * HDIM * 2);
    unsigned short* z = (unsigned short*)alloc((size_t)N_NODES * HDIM * 2);
    unsigned short* z1 = (unsigned short*)alloc((size_t)N_NODES * 2 * HDIM * 2);
    float* zin = (float*)alloc((size_t)N_NODES * HDIM * 4);
    unsigned short* Wt1 = (unsigned short*)alloc((size_t)L_LAYERS * HDIM * 2 * HDIM * 2);
    unsigned short* Wt2 = (unsigned short*)alloc((size_t)L_LAYERS * HDIM * 2 * HDIM * 2);
    unsigned short* Wtd = (unsigned short*)alloc((size_t)HDIM * HDIM * 2);
    int* deg = (int*)alloc((size_t)N_NODES * 4);
    int* rowptr = (int*)alloc((size_t)(N_NODES + 1) * 4);
    int* cursor = (int*)alloc((size_t)N_NODES * 4);
    int* col = (int*)alloc((size_t)N_EDGES * 4);
    uint64_t* pairs = (uint64_t*)alloc((size_t)N_EDGES * 8);
    int* bsum = (int*)alloc((size_t)SCAN_NB * 4);
    int* ebsum = (int*)alloc((size_t)SCAN_NB * 4);
    int* pcursor = (int*)alloc((size_t)NPART * 4);
    float* stats = (float*)alloc((size_t)L_LAYERS * 2 * HDIM * 4);
    float* lacc = (float*)alloc(8);
    int* flag = (int*)alloc(4);

    detect_mask_kernel<<<1, 256, 0, stream>>>((const uint32_t*)mask, flag);
    wprep_all_kernel<<<dim3(32, 9), 256, 0, stream>>>(W1, W2, dW1, Wt1, Wt2, Wtd);
    embed_kernel<<<(N_NODES * HDIM + 255) / 256, 256, 0, stream>>>(x, mask, flag, tok, eW, eb, h);

    hipMemsetAsync(deg, 0, (size_t)N_NODES * 4, stream);
    hipMemsetAsync(stats, 0, (size_t)L_LAYERS * 2 * HDIM * 4, stream);
    hipMemsetAsync(lacc, 0, 8, stream);
    deg_kernel<<<(N_EDGES + 255) / 256, 256, 0, stream>>>(dst, deg);
    scan_partial_kernel<<<SCAN_NB, 256, 0, stream>>>(deg, bsum);
    scan_bsum_kernel<<<1, 128, 0, stream>>>(bsum, ebsum, rowptr);
    scan_final_kernel<<<SCAN_NB, 256, 0, stream>>>(deg, ebsum, rowptr, cursor);
    pcur_init_kernel<<<1, 64, 0, stream>>>(rowptr, pcursor);
    partition_kernel<<<256, 256, 0, stream>>>(src, dst, pcursor, pairs);
    fill_part_kernel<<<NPART * 16, 256, 0, stream>>>(pairs, rowptr, cursor, col);

    for (int l = 0; l < L_LAYERS; ++l) {
        float* lstats = stats + (size_t)l * 2 * HDIM;
        agg_kernel<<<(N_NODES + 3) / 4, 256, 0, stream>>>(h, rowptr, col, z);
        fused_layer_kernel<<<782, 256, 0, stream>>>(z, Wt1 + (size_t)l * HDIM * 2 * HDIM,
                                                    b1 + (size_t)l * 2 * HDIM,
                                                    Wt2 + (size_t)l * HDIM * 2 * HDIM,
                                                    b2 + (size_t)l * HDIM, zin, lstats, N_NODES);
        bnapply_kernel<<<(N_NODES * HDIM / 4 + 255) / 256, 256, 0, stream>>>(
            zin, lstats, gm + l * HDIM, bt + l * HDIM, h);
    }

    mfma_gemm_kernel<HDIM, true, true><<<dim3(2, 782), 256, 0, stream>>>(h, Wtd, db1, z1, N_NODES,
                                                                         HDIM);
    dec2_loss_kernel<<<(N_NODES + 255) / 256, 256, 0, stream>>>(z1, dW2, db2, x, mask, flag,
                                                                out + 1, lacc);
    finalize_kernel<<<1, 1, 0, stream>>>(lacc, out);
}

// Round 10
// 764.877 us; speedup vs baseline: 2.0976x; 1.0729x over previous
//
#include <hip/hip_runtime.h>
#include <cstdint>

#define N_NODES 50000
#define N_EDGES 1600000
#define HDIM 128
#define L_LAYERS 4
#define BN_EPS 1e-5f
#define SCAN_NB 98
#define SCAN_CHUNK 512
#define NPART 196
#define PART_SHIFT 8
#define PB_CHUNK 6250  // N_EDGES / 256 exactly
#define FP_CAP 16384

typedef __attribute__((ext_vector_type(8))) short short8v;
typedef __attribute__((ext_vector_type(4))) float f32x4;

__device__ __forceinline__ unsigned short f2bf(float f) {
    uint32_t u = __builtin_bit_cast(uint32_t, f);
    u += 0x7fff + ((u >> 16) & 1);
    return (unsigned short)(u >> 16);
}
__device__ __forceinline__ float bf2f(unsigned short b) {
    return __builtin_bit_cast(float, (uint32_t)b << 16);
}

// ---------------- mask layout detection ----------------
__global__ void detect_mask_kernel(const uint32_t* __restrict__ mw, int* __restrict__ flag) {
    __shared__ int f;
    if (threadIdx.x == 0) f = 0;
    __syncthreads();
    int found = 0;
    for (int i = threadIdx.x; i < 12500; i += blockDim.x)
        if (mw[i] > 1u) found = 1;
    if (found) f = 1;
    __syncthreads();
    if (threadIdx.x == 0) *flag = f;
}

__device__ __forceinline__ int read_mask(const void* mask, int i, int bytelayout) {
    if (bytelayout) return ((const unsigned char*)mask)[i] != 0;
    return ((const int*)mask)[i] != 0;
}

// ---------------- unified weight prep: Wt[n][k] = bf16(W[k][n]) ----------------
__global__ void wprep_all_kernel(const float* __restrict__ W1, const float* __restrict__ W2,
                                 const float* __restrict__ dW1, unsigned short* __restrict__ Wt1,
                                 unsigned short* __restrict__ Wt2,
                                 unsigned short* __restrict__ Wtd) {
    int seg = blockIdx.y;
    const float* W;
    unsigned short* Wt;
    int K, nshift;
    if (seg < 4) {
        W = W1 + (size_t)seg * HDIM * 2 * HDIM;
        Wt = Wt1 + (size_t)seg * HDIM * 2 * HDIM;
        K = HDIM;
        nshift = 8;
    } else if (seg < 8) {
        int l = seg - 4;
        W = W2 + (size_t)l * 2 * HDIM * HDIM;
        Wt = Wt2 + (size_t)l * 2 * HDIM * HDIM;
        K = 2 * HDIM;
        nshift = 7;
    } else {
        W = dW1;
        Wt = Wtd;
        K = HDIM;
        nshift = 7;
    }
    int total = K << nshift;
    for (int idx = blockIdx.x * 256 + threadIdx.x; idx < total; idx += gridDim.x * 256) {
        int k = idx >> nshift, n = idx & ((1 << nshift) - 1);
        Wt[(size_t)n * K + k] = f2bf(W[idx]);
    }
}

// ---------------- embed ----------------
__global__ void embed_kernel(const float* __restrict__ x, const void* __restrict__ mask,
                             const int* __restrict__ flag, const float* __restrict__ tok,
                             const float* __restrict__ W, const float* __restrict__ b,
                             unsigned short* __restrict__ h) {
    int idx = blockIdx.x * blockDim.x + threadIdx.x;
    if (idx >= N_NODES * HDIM) return;
    int i = idx >> 7, c = idx & 127;
    int fl = *flag;
    int m = read_mask(mask, i, fl);
    float x0 = m ? tok[0] : x[i * 3 + 0];
    float x1 = m ? tok[1] : x[i * 3 + 1];
    float x2 = m ? tok[2] : x[i * 3 + 2];
    h[idx] = f2bf(x0 * W[c] + x1 * W[HDIM + c] + x2 * W[2 * HDIM + c] + b[c]);
}

// ---------------- CSR build ----------------
__global__ void deg_kernel(const int* __restrict__ dst, int* __restrict__ deg) {
    int e = blockIdx.x * blockDim.x + threadIdx.x;
    if (e < N_EDGES) atomicAdd(&deg[__builtin_nontemporal_load(&dst[e])], 1);
}

__global__ __launch_bounds__(256) void scan_partial_kernel(const int* __restrict__ deg,
                                                           int* __restrict__ bsum) {
    __shared__ int red[256];
    int b = blockIdx.x, t = threadIdx.x;
    int base = b * SCAN_CHUNK;
    int s = 0;
    for (int i = t; i < SCAN_CHUNK; i += 256) {
        int idx = base + i;
        if (idx < N_NODES) s += deg[idx];
    }
    red[t] = s;
    __syncthreads();
    for (int o = 128; o > 0; o >>= 1) {
        if (t < o) red[t] += red[t + o];
        __syncthreads();
    }
    if (t == 0) bsum[b] = red[0];
}

__global__ __launch_bounds__(128) void scan_bsum_kernel(const int* __restrict__ bsum,
                                                        int* __restrict__ ebsum,
                                                        int* __restrict__ rowptr) {
    __shared__ int sh[128];
    int t = threadIdx.x;
    int v = (t < SCAN_NB) ? bsum[t] : 0;
    sh[t] = v;
    __syncthreads();
    for (int o = 1; o < 128; o <<= 1) {
        int u = (t >= o) ? sh[t - o] : 0;
        __syncthreads();
        sh[t] += u;
        __syncthreads();
    }
    if (t < SCAN_NB) ebsum[t] = sh[t] - v;
    if (t == 127) rowptr[N_NODES] = sh[127];
}

__global__ __launch_bounds__(256) void scan_final_kernel(const int* __restrict__ deg,
                                                         const int* __restrict__ ebsum,
                                                         int* __restrict__ rowptr,
                                                         int* __restrict__ cursor) {
    __shared__ int sh[256];
    int b = blockIdx.x, t = threadIdx.x;
    int running = ebsum[b];
    for (int t0 = 0; t0 < SCAN_CHUNK; t0 += 256) {
        int idx = b * SCAN_CHUNK + t0 + t;
        int v = (idx < N_NODES) ? deg[idx] : 0;
        sh[t] = v;
        __syncthreads();
        for (int o = 1; o < 256; o <<= 1) {
            int u = (t >= o) ? sh[t - o] : 0;
            __syncthreads();
            sh[t] += u;
            __syncthreads();
        }
        int excl = sh[t] - v + running;
        if (idx < N_NODES) {
            rowptr[idx] = excl;
            cursor[idx] = excl;
        }
        running += sh[255];
        __syncthreads();
    }
}

__global__ void pcur_init_kernel(const int* __restrict__ rowptr, int* __restrict__ pcursor) {
    int p = threadIdx.x;
    if (p < NPART) pcursor[p] = rowptr[p << PART_SHIFT];
}

// pass 1: radix-partition edges by dst>>8 into packed u32 (src | d_local<<16).
// LDS = hist/off only (1.5KB); two passes over the block's L1-resident chunk.
__global__ __launch_bounds__(256) void partition_kernel(const int* __restrict__ src,
                                                        const int* __restrict__ dst,
                                                        int* __restrict__ pcursor,
                                                        uint32_t* __restrict__ pairs) {
    __shared__ int hist[NPART];
    __shared__ int off[NPART];
    int b = blockIdx.x, t = threadIdx.x;
    int lo = b * PB_CHUNK;
    for (int i = t; i < NPART; i += 256) hist[i] = 0;
    __syncthreads();
    for (int i = t; i < PB_CHUNK; i += 256) {
        int d = dst[lo + i];
        atomicAdd(&hist[d >> PART_SHIFT], 1);
    }
    __syncthreads();
    for (int i = t; i < NPART; i += 256) off[i] = atomicAdd(&pcursor[i], hist[i]);
    __syncthreads();
    for (int i = t; i < PB_CHUNK; i += 256) {
        int d = dst[lo + i];
        int s = src[lo + i];
        int pos = atomicAdd(&off[d >> PART_SHIFT], 1);
        pairs[pos] = (uint32_t)s | ((uint32_t)(d & 255) << 16);
    }
}

// pass 2: one block per partition; scatter within a 64KB LDS window, then
// stream out coalesced (write amplification = 1x). Fallback to global scatter
// if a partition exceeds capacity (deterministically impossible for this input,
// but keeps correctness unconditional).
__global__ __launch_bounds__(256) void fill_part_kernel(const uint32_t* __restrict__ pairs,
                                                        const int* __restrict__ rowptr,
                                                        int* __restrict__ cursor,
                                                        int* __restrict__ col) {
    __shared__ int colw[FP_CAP];
    __shared__ int lcur[256];
    int p = blockIdx.x, t = threadIdx.x;
    int base = p << PART_SHIFT;
    int nlocal = min(256, N_NODES - base);
    int start = rowptr[base];
    int end = rowptr[base + nlocal];
    int cnt = end - start;
    if (cnt <= FP_CAP) {
        if (t < nlocal) lcur[t] = rowptr[base + t] - start;
        __syncthreads();
        for (int e = start + t; e < end; e += 256) {
            uint32_t v = __builtin_nontemporal_load(&pairs[e]);
            int pos = atomicAdd(&lcur[(v >> 16) & 255], 1);
            colw[pos] = (int)(v & 0xFFFFu);
        }
        __syncthreads();
        for (int e = t; e < cnt; e += 256) col[start + e] = colw[e];
    } else {
        for (int e = start + t; e < end; e += 256) {
            uint32_t v = __builtin_nontemporal_load(&pairs[e]);
            int pos = atomicAdd(&cursor[base + ((v >> 16) & 255)], 1);
            col[pos] = (int)(v & 0xFFFFu);
        }
    }
}

// ---------------- aggregation (bf16 h): z[i] = h[i] + sum_{j} h[j] ----------------
__global__ __launch_bounds__(256) void agg_kernel(const unsigned short* __restrict__ h,
                                                  const int* __restrict__ rowptr,
                                                  const int* __restrict__ col,
                                                  unsigned short* __restrict__ z) {
    int wid = threadIdx.x >> 6;
    int lane = threadIdx.x & 63;
    int i = blockIdx.x * 4 + wid;
    if (i >= N_NODES) return;
    int start = rowptr[i], end = rowptr[i + 1];
    const uint32_t* h32 = (const uint32_t*)h;
    uint32_t u = h32[(size_t)i * 64 + lane];
    float ax = __builtin_bit_cast(float, u << 16);
    float ay = __builtin_bit_cast(float, u & 0xffff0000u);
    float bx = 0.f, by = 0.f, cx = 0.f, cy = 0.f, dx = 0.f, dy = 0.f;
    int e = start;
    for (; e + 4 <= end; e += 4) {
        int j0 = col[e + 0], j1 = col[e + 1], j2 = col[e + 2], j3 = col[e + 3];
        uint32_t u0 = h32[(size_t)j0 * 64 + lane];
        uint32_t u1 = h32[(size_t)j1 * 64 + lane];
        uint32_t u2 = h32[(size_t)j2 * 64 + lane];
        uint32_t u3 = h32[(size_t)j3 * 64 + lane];
        ax += __builtin_bit_cast(float, u0 << 16);
        ay += __builtin_bit_cast(float, u0 & 0xffff0000u);
        bx += __builtin_bit_cast(float, u1 << 16);
        by += __builtin_bit_cast(float, u1 & 0xffff0000u);
        cx += __builtin_bit_cast(float, u2 << 16);
        cy += __builtin_bit_cast(float, u2 & 0xffff0000u);
        dx += __builtin_bit_cast(float, u3 << 16);
        dy += __builtin_bit_cast(float, u3 & 0xffff0000u);
    }
    for (; e < end; ++e) {
        uint32_t u0 = h32[(size_t)col[e] * 64 + lane];
        ax += __builtin_bit_cast(float, u0 << 16);
        ay += __builtin_bit_cast(float, u0 & 0xffff0000u);
    }
    ax += bx + cx + dx;
    ay += by + cy + dy;
    uint32_t o = (uint32_t)f2bf(ax) | ((uint32_t)f2bf(ay) << 16);
    ((uint32_t*)z)[(size_t)i * 64 + lane] = o;
}

// ---------------- fused layer: zin = relu(z@W1+b1)@W2+b2, stats epilogue ----------------
__global__ __launch_bounds__(256) void fused_layer_kernel(
    const unsigned short* __restrict__ z, const unsigned short* __restrict__ Wt1,
    const float* __restrict__ b1, const unsigned short* __restrict__ Wt2,
    const float* __restrict__ b2, float* __restrict__ zin, float* __restrict__ stats, int M) {
    __shared__ unsigned short z1l[64 * 260];
    __shared__ float sred[4][2][HDIM];
    const int lane = threadIdx.x & 63;
    const int w = threadIdx.x >> 6;
    const int r = lane & 15, ks = lane >> 4;
    const int row0 = blockIdx.x * 64 + w * 16;
    const int arow = min(row0 + r, M - 1);
    short8v a4[4];
#pragma unroll
    for (int kk = 0; kk < 4; ++kk)
        a4[kk] = *(const short8v*)&z[(size_t)arow * HDIM + kk * 32 + ks * 8];
#pragma unroll
    for (int n = 0; n < 16; ++n) {
        f32x4 acc = (f32x4){0.f, 0.f, 0.f, 0.f};
#pragma unroll
        for (int kk = 0; kk < 4; ++kk) {
            short8v bf = *(const short8v*)&Wt1[(size_t)(n * 16 + r) * HDIM + kk * 32 + ks * 8];
            acc = __builtin_amdgcn_mfma_f32_16x16x32_bf16(a4[kk], bf, acc, 0, 0, 0);
        }
        float bv = b1[n * 16 + r];
#pragma unroll
        for (int i = 0; i < 4; ++i) {
            float o = fmaxf(acc[i] + bv, 0.f);
            z1l[(w * 16 + ks * 4 + i) * 260 + n * 16 + r] = f2bf(o);
        }
    }
    __syncthreads();
    f32x4 accb[8];
#pragma unroll
    for (int n = 0; n < 8; ++n) accb[n] = (f32x4){0.f, 0.f, 0.f, 0.f};
#pragma unroll
    for (int k0 = 0; k0 < 256; k0 += 32) {
        short8v a = *(const short8v*)&z1l[(w * 16 + r) * 260 + k0 + ks * 8];
#pragma unroll
        for (int n = 0; n < 8; ++n) {
            short8v bf = *(const short8v*)&Wt2[(size_t)(n * 16 + r) * 256 + k0 + ks * 8];
            accb[n] = __builtin_amdgcn_mfma_f32_16x16x32_bf16(a, bf, accb[n], 0, 0, 0);
        }
    }
#pragma unroll
    for (int n = 0; n < 8; ++n) {
        const int cc = n * 16 + r;
        const float bv = b2[cc];
        float s = 0.f, ss = 0.f;
#pragma unroll
        for (int i = 0; i < 4; ++i) {
            int row = row0 + ks * 4 + i;
            if (row < M) {
                float o = accb[n][i] + bv;
                s += o;
                ss += o * o;
                zin[(size_t)row * HDIM + cc] = o;
            }
        }
        s += __shfl_xor(s, 16);
        s += __shfl_xor(s, 32);
        ss += __shfl_xor(ss, 16);
        ss += __shfl_xor(ss, 32);
        if (ks == 0) {
            sred[w][0][cc] = s;
            sred[w][1][cc] = ss;
        }
    }
    __syncthreads();
    int t = threadIdx.x;
    if (t < HDIM) {
        float s = sred[0][0][t] + sred[1][0][t] + sred[2][0][t] + sred[3][0][t];
        float ss = sred[0][1][t] + sred[1][1][t] + sred[2][1][t] + sred[3][1][t];
        atomicAdd(&stats[t], s);
        atomicAdd(&stats[HDIM + t], ss);
    }
}

// ---------------- plain MFMA GEMM (decoder stage 1) ----------------
template <int K, bool OUT_BF16, bool RELU>
__global__ __launch_bounds__(256) void mfma_gemm_kernel(const unsigned short* __restrict__ A,
                                                        const unsigned short* __restrict__ Wt,
                                                        const float* __restrict__ bias,
                                                        void* __restrict__ C, int M, int ldc) {
    const int lane = threadIdx.x & 63;
    const int w = threadIdx.x >> 6;
    const int row0 = blockIdx.y * 64 + w * 16;
    const int col0 = blockIdx.x * 64;
    const int r = lane & 15;
    const int ks = lane >> 4;
    const int arow = min(row0 + r, M - 1);
    f32x4 acc[4];
#pragma unroll
    for (int n = 0; n < 4; ++n) acc[n] = (f32x4){0.f, 0.f, 0.f, 0.f};
#pragma unroll
    for (int k0 = 0; k0 < K; k0 += 32) {
        short8v a = *(const short8v*)&A[(size_t)arow * K + k0 + ks * 8];
#pragma unroll
        for (int n = 0; n < 4; ++n) {
            short8v b = *(const short8v*)&Wt[(size_t)(col0 + n * 16 + r) * K + k0 + ks * 8];
            acc[n] = __builtin_amdgcn_mfma_f32_16x16x32_bf16(a, b, acc[n], 0, 0, 0);
        }
    }
#pragma unroll
    for (int n = 0; n < 4; ++n) {
        const int col = col0 + n * 16 + r;
        const float bv = bias[col];
#pragma unroll
        for (int i = 0; i < 4; ++i) {
            int row = row0 + ks * 4 + i;
            if (row < M) {
                float o = acc[n][i] + bv;
                if (RELU) o = fmaxf(o, 0.f);
                if (OUT_BF16)
                    ((unsigned short*)C)[(size_t)row * ldc + col] = f2bf(o);
                else
                    ((float*)C)[(size_t)row * ldc + col] = o;
            }
        }
    }
}

// ---------------- BN apply ----------------
__global__ void bnapply_kernel(const float* __restrict__ zin, const float* __restrict__ stats,
                               const float* __restrict__ gamma, const float* __restrict__ beta,
                               unsigned short* __restrict__ h) {
    __shared__ float ssc[2 * HDIM];
    int t = threadIdx.x;
    if (t < HDIM) {
        float mean = stats[t] * (1.f / N_NODES);
        float var = stats[HDIM + t] * (1.f / N_NODES) - mean * mean;
        float rstd = rsqrtf(fmaxf(var, 0.f) + BN_EPS);
        float s = gamma[t] * rstd;
        ssc[t] = s;
        ssc[HDIM + t] = beta[t] - mean * s;
    }
    __syncthreads();
    int idx = blockIdx.x * blockDim.x + threadIdx.x;
    if (idx >= N_NODES * HDIM / 4) return;
    float4 v = ((const float4*)zin)[idx];
    int c = (idx * 4) & 127;
    float o0 = fmaxf(v.x * ssc[c + 0] + ssc[HDIM + c + 0], 0.f);
    float o1 = fmaxf(v.y * ssc[c + 1] + ssc[HDIM + c + 1], 0.f);
    float o2 = fmaxf(v.z * ssc[c + 2] + ssc[HDIM + c + 2], 0.f);
    float o3 = fmaxf(v.w * ssc[c + 3] + ssc[HDIM + c + 3], 0.f);
    uint2 p;
    p.x = (uint32_t)f2bf(o0) | ((uint32_t)f2bf(o1) << 16);
    p.y = (uint32_t)f2bf(o2) | ((uint32_t)f2bf(o3) << 16);
    ((uint2*)h)[idx] = p;
}

// ---------------- decoder stage2 + loss: one thread per node ----------------
__global__ __launch_bounds__(256) void dec2_loss_kernel(
    const unsigned short* __restrict__ d1, const float* __restrict__ W2,
    const float* __restrict__ b2, const float* __restrict__ x, const void* __restrict__ mask,
    const int* __restrict__ flag, float* __restrict__ recon, float* __restrict__ acc) {
    __shared__ float w2s[HDIM * 3];
    for (int t = threadIdx.x; t < HDIM * 3; t += 256) w2s[t] = W2[t];
    __syncthreads();
    int i = blockIdx.x * 256 + threadIdx.x;
    int fl = *flag;
    float lsum = 0.f, lcnt = 0.f;
    if (i < N_NODES) {
        float s0 = 0.f, s1 = 0.f, s2 = 0.f;
        const unsigned short* row = &d1[(size_t)i * HDIM];
#pragma unroll
        for (int k0 = 0; k0 < HDIM; k0 += 8) {
            short8v v = *(const short8v*)&row[k0];
#pragma unroll
            for (int q = 0; q < 8; ++q) {
                float a = bf2f((unsigned short)v[q]);
                s0 = fmaf(a, w2s[(k0 + q) * 3 + 0], s0);
                s1 = fmaf(a, w2s[(k0 + q) * 3 + 1], s1);
                s2 = fmaf(a, w2s[(k0 + q) * 3 + 2], s2);
            }
        }
        float r0 = s0 + b2[0], r1 = s1 + b2[1], r2 = s2 + b2[2];
        recon[(size_t)i * 3 + 0] = r0;
        recon[(size_t)i * 3 + 1] = r1;
        recon[(size_t)i * 3 + 2] = r2;
        if (read_mask(mask, i, fl)) {
            float rn = fmaxf(sqrtf(r0 * r0 + r1 * r1 + r2 * r2), 1e-12f);
            float x0 = x[i * 3 + 0], x1 = x[i * 3 + 1], x2 = x[i * 3 + 2];
            float xn = fmaxf(sqrtf(x0 * x0 + x1 * x1 + x2 * x2), 1e-12f);
            float cs = (r0 * x0 + r1 * x1 + r2 * x2) / (rn * xn);
            float d = 1.f - cs;
            lsum = d * d;
            lcnt = 1.f;
        }
    }
#pragma unroll
    for (int o = 32; o > 0; o >>= 1) {
        lsum += __shfl_xor(lsum, o);
        lcnt += __shfl_xor(lcnt, o);
    }
    if ((threadIdx.x & 63) == 0 && lcnt != 0.f) {
        atomicAdd(&acc[0], lsum);
        atomicAdd(&acc[1], lcnt);
    }
}

__global__ void finalize_kernel(const float* __restrict__ acc, float* __restrict__ out) {
    out[0] = acc[0] / fmaxf(acc[1], 1.f);
}

// ---------------- launcher ----------------
extern "C" void kernel_launch(void* const* d_in, const int* in_sizes, int n_in, void* d_out,
                              int out_size, void* d_ws, size_t ws_size, hipStream_t stream) {
    const float* x = (const float*)d_in[0];
    const int* ei = (const int*)d_in[1];
    const int* src = ei;
    const int* dst = ei + N_EDGES;
    const void* mask = d_in[3];
    const float* tok = (const float*)d_in[4];
    const float* eW = (const float*)d_in[5];
    const float* eb = (const float*)d_in[6];
    const float* W1 = (const float*)d_in[7];
    const float* b1 = (const float*)d_in[8];
    const float* W2 = (const float*)d_in[9];
    const float* b2 = (const float*)d_in[10];
    const float* gm = (const float*)d_in[11];
    const float* bt = (const float*)d_in[12];
    const float* dW1 = (const float*)d_in[13];
    const float* db1 = (const float*)d_in[14];
    const float* dW2 = (const float*)d_in[15];
    const float* db2 = (const float*)d_in[16];
    float* out = (float*)d_out;

    char* ws = (char*)d_ws;
    size_t off = 0;
    auto alloc = [&](size_t bytes) -> void* {
        void* p = ws + off;
        off = (off + bytes + 255) & ~(size_t)255;
        return p;
    };
    unsigned short* h = (unsigned short*)alloc((size_t)N_NODES * HDIM * 2);
    unsigned short* z = (unsigned short*)alloc((size_t)N_NODES * HDIM * 2);
    unsigned short* z1 = (unsigned short*)alloc((size_t)N_NODES * 2 * HDIM * 2);
    float* zin = (float*)alloc((size_t)N_NODES * HDIM * 4);
    unsigned short* Wt1 = (unsigned short*)alloc((size_t)L_LAYERS * HDIM * 2 * HDIM * 2);
    unsigned short* Wt2 = (unsigned short*)alloc((size_t)L_LAYERS * HDIM * 2 * HDIM * 2);
    unsigned short* Wtd = (unsigned short*)alloc((size_t)HDIM * HDIM * 2);
    int* deg = (int*)alloc((size_t)N_NODES * 4);
    int* rowptr = (int*)alloc((size_t)(N_NODES + 1) * 4);
    int* cursor = (int*)alloc((size_t)N_NODES * 4);
    int* col = (int*)alloc((size_t)N_EDGES * 4);
    uint32_t* pairs = (uint32_t*)alloc((size_t)N_EDGES * 4);
    int* bsum = (int*)alloc((size_t)SCAN_NB * 4);
    int* ebsum = (int*)alloc((size_t)SCAN_NB * 4);
    int* pcursor = (int*)alloc((size_t)NPART * 4);
    float* stats = (float*)alloc((size_t)L_LAYERS * 2 * HDIM * 4);
    float* lacc = (float*)alloc(8);
    int* flag = (int*)alloc(4);

    detect_mask_kernel<<<1, 256, 0, stream>>>((const uint32_t*)mask, flag);
    wprep_all_kernel<<<dim3(32, 9), 256, 0, stream>>>(W1, W2, dW1, Wt1, Wt2, Wtd);
    embed_kernel<<<(N_NODES * HDIM + 255) / 256, 256, 0, stream>>>(x, mask, flag, tok, eW, eb, h);

    hipMemsetAsync(deg, 0, (size_t)N_NODES * 4, stream);
    hipMemsetAsync(stats, 0, (size_t)L_LAYERS * 2 * HDIM * 4, stream);
    hipMemsetAsync(lacc, 0, 8, stream);
    deg_kernel<<<(N_EDGES + 255) / 256, 256, 0, stream>>>(dst, deg);
    scan_partial_kernel<<<SCAN_NB, 256, 0, stream>>>(deg, bsum);
    scan_bsum_kernel<<<1, 128, 0, stream>>>(bsum, ebsum, rowptr);
    scan_final_kernel<<<SCAN_NB, 256, 0, stream>>>(deg, ebsum, rowptr, cursor);
    pcur_init_kernel<<<1, 256, 0, stream>>>(rowptr, pcursor);
    partition_kernel<<<256, 256, 0, stream>>>(src, dst, pcursor, pairs);
    fill_part_kernel<<<NPART, 256, 0, stream>>>(pairs, rowptr, cursor, col);

    for (int l = 0; l < L_LAYERS; ++l) {
        float* lstats = stats + (size_t)l * 2 * HDIM;
        agg_kernel<<<(N_NODES + 3) / 4, 256, 0, stream>>>(h, rowptr, col, z);
        fused_layer_kernel<<<782, 256, 0, stream>>>(z, Wt1 + (size_t)l * HDIM * 2 * HDIM,
                                                    b1 + (size_t)l * 2 * HDIM,
                                                    Wt2 + (size_t)l * HDIM * 2 * HDIM,
                                                    b2 + (size_t)l * HDIM, zin, lstats, N_NODES);
        bnapply_kernel<<<(N_NODES * HDIM / 4 + 255) / 256, 256, 0, stream>>>(
            zin, lstats, gm + l * HDIM, bt + l * HDIM, h);
    }

    mfma_gemm_kernel<HDIM, true, true><<<dim3(2, 782), 256, 0, stream>>>(h, Wtd, db1, z1, N_NODES,
                                                                         HDIM);
    dec2_loss_kernel<<<(N_NODES + 255) / 256, 256, 0, stream>>>(z1, dW2, db2, x, mask, flag,
                                                                out + 1, lacc);
    finalize_kernel<<<1, 1, 0, stream>>>(lacc, out);
}

// Round 11
// 606.677 us; speedup vs baseline: 2.6446x; 1.2608x over previous
//
#include <hip/hip_runtime.h>
#include <cstdint>

#define N_NODES 50000
#define N_EDGES 1600000
#define HDIM 128
#define L_LAYERS 4
#define BN_EPS 1e-5f
#define SCAN_NB 98
#define SCAN_CHUNK 512
#define NPART 196
#define PART_SHIFT 8
#define PB_CHUNK 6250  // N_EDGES / 256 exactly
#define FP_CAP 16384
#define FL_RB 128

typedef __attribute__((ext_vector_type(8))) short short8v;
typedef __attribute__((ext_vector_type(4))) float f32x4;

__device__ __forceinline__ unsigned short f2bf(float f) {
    uint32_t u = __builtin_bit_cast(uint32_t, f);
    u += 0x7fff + ((u >> 16) & 1);
    return (unsigned short)(u >> 16);
}
__device__ __forceinline__ float bf2f(unsigned short b) {
    return __builtin_bit_cast(float, (uint32_t)b << 16);
}

// ---------------- mask layout detection ----------------
__global__ void detect_mask_kernel(const uint32_t* __restrict__ mw, int* __restrict__ flag) {
    __shared__ int f;
    if (threadIdx.x == 0) f = 0;
    __syncthreads();
    int found = 0;
    for (int i = threadIdx.x; i < 12500; i += blockDim.x)
        if (mw[i] > 1u) found = 1;
    if (found) f = 1;
    __syncthreads();
    if (threadIdx.x == 0) *flag = f;
}

__device__ __forceinline__ int read_mask(const void* mask, int i, int bytelayout) {
    if (bytelayout) return ((const unsigned char*)mask)[i] != 0;
    return ((const int*)mask)[i] != 0;
}

// ---------------- unified weight prep: Wt[n][k] = bf16(W[k][n]) ----------------
__global__ void wprep_all_kernel(const float* __restrict__ W1, const float* __restrict__ W2,
                                 const float* __restrict__ dW1, unsigned short* __restrict__ Wt1,
                                 unsigned short* __restrict__ Wt2,
                                 unsigned short* __restrict__ Wtd) {
    int seg = blockIdx.y;
    const float* W;
    unsigned short* Wt;
    int K, nshift;
    if (seg < 4) {
        W = W1 + (size_t)seg * HDIM * 2 * HDIM;
        Wt = Wt1 + (size_t)seg * HDIM * 2 * HDIM;
        K = HDIM;
        nshift = 8;
    } else if (seg < 8) {
        int l = seg - 4;
        W = W2 + (size_t)l * 2 * HDIM * HDIM;
        Wt = Wt2 + (size_t)l * 2 * HDIM * HDIM;
        K = 2 * HDIM;
        nshift = 7;
    } else {
        W = dW1;
        Wt = Wtd;
        K = HDIM;
        nshift = 7;
    }
    int total = K << nshift;
    for (int idx = blockIdx.x * 256 + threadIdx.x; idx < total; idx += gridDim.x * 256) {
        int k = idx >> nshift, n = idx & ((1 << nshift) - 1);
        Wt[(size_t)n * K + k] = f2bf(W[idx]);
    }
}

// ---------------- embed ----------------
__global__ void embed_kernel(const float* __restrict__ x, const void* __restrict__ mask,
                             const int* __restrict__ flag, const float* __restrict__ tok,
                             const float* __restrict__ W, const float* __restrict__ b,
                             unsigned short* __restrict__ h) {
    int idx = blockIdx.x * blockDim.x + threadIdx.x;
    if (idx >= N_NODES * HDIM) return;
    int i = idx >> 7, c = idx & 127;
    int fl = *flag;
    int m = read_mask(mask, i, fl);
    float x0 = m ? tok[0] : x[i * 3 + 0];
    float x1 = m ? tok[1] : x[i * 3 + 1];
    float x2 = m ? tok[2] : x[i * 3 + 2];
    h[idx] = f2bf(x0 * W[c] + x1 * W[HDIM + c] + x2 * W[2 * HDIM + c] + b[c]);
}

// ---------------- CSR build ----------------
__global__ void deg_kernel(const int* __restrict__ dst, int* __restrict__ deg) {
    int e = blockIdx.x * blockDim.x + threadIdx.x;
    if (e < N_EDGES) atomicAdd(&deg[__builtin_nontemporal_load(&dst[e])], 1);
}

__global__ __launch_bounds__(256) void scan_partial_kernel(const int* __restrict__ deg,
                                                           int* __restrict__ bsum) {
    __shared__ int red[256];
    int b = blockIdx.x, t = threadIdx.x;
    int base = b * SCAN_CHUNK;
    int s = 0;
    for (int i = t; i < SCAN_CHUNK; i += 256) {
        int idx = base + i;
        if (idx < N_NODES) s += deg[idx];
    }
    red[t] = s;
    __syncthreads();
    for (int o = 128; o > 0; o >>= 1) {
        if (t < o) red[t] += red[t + o];
        __syncthreads();
    }
    if (t == 0) bsum[b] = red[0];
}

__global__ __launch_bounds__(128) void scan_bsum_kernel(const int* __restrict__ bsum,
                                                        int* __restrict__ ebsum,
                                                        int* __restrict__ rowptr) {
    __shared__ int sh[128];
    int t = threadIdx.x;
    int v = (t < SCAN_NB) ? bsum[t] : 0;
    sh[t] = v;
    __syncthreads();
    for (int o = 1; o < 128; o <<= 1) {
        int u = (t >= o) ? sh[t - o] : 0;
        __syncthreads();
        sh[t] += u;
        __syncthreads();
    }
    if (t < SCAN_NB) ebsum[t] = sh[t] - v;
    if (t == 127) rowptr[N_NODES] = sh[127];
}

__global__ __launch_bounds__(256) void scan_final_kernel(const int* __restrict__ deg,
                                                         const int* __restrict__ ebsum,
                                                         int* __restrict__ rowptr,
                                                         int* __restrict__ cursor) {
    __shared__ int sh[256];
    int b = blockIdx.x, t = threadIdx.x;
    int running = ebsum[b];
    for (int t0 = 0; t0 < SCAN_CHUNK; t0 += 256) {
        int idx = b * SCAN_CHUNK + t0 + t;
        int v = (idx < N_NODES) ? deg[idx] : 0;
        sh[t] = v;
        __syncthreads();
        for (int o = 1; o < 256; o <<= 1) {
            int u = (t >= o) ? sh[t - o] : 0;
            __syncthreads();
            sh[t] += u;
            __syncthreads();
        }
        int excl = sh[t] - v + running;
        if (idx < N_NODES) {
            rowptr[idx] = excl;
            cursor[idx] = excl;
        }
        running += sh[255];
        __syncthreads();
    }
}

__global__ void pcur_init_kernel(const int* __restrict__ rowptr, int* __restrict__ pcursor) {
    int p = threadIdx.x;
    if (p < NPART) pcursor[p] = rowptr[p << PART_SHIFT];
}

// pass 1: radix-partition edges by dst>>8 into packed u32 (src | d_local<<16).
__global__ __launch_bounds__(256) void partition_kernel(const int* __restrict__ src,
                                                        const int* __restrict__ dst,
                                                        int* __restrict__ pcursor,
                                                        uint32_t* __restrict__ pairs) {
    __shared__ int hist[NPART];
    __shared__ int off[NPART];
    int b = blockIdx.x, t = threadIdx.x;
    int lo = b * PB_CHUNK;
    for (int i = t; i < NPART; i += 256) hist[i] = 0;
    __syncthreads();
    for (int i = t; i < PB_CHUNK; i += 256) {
        int d = dst[lo + i];
        atomicAdd(&hist[d >> PART_SHIFT], 1);
    }
    __syncthreads();
    for (int i = t; i < NPART; i += 256) off[i] = atomicAdd(&pcursor[i], hist[i]);
    __syncthreads();
    for (int i = t; i < PB_CHUNK; i += 256) {
        int d = dst[lo + i];
        int s = src[lo + i];
        int pos = atomicAdd(&off[d >> PART_SHIFT], 1);
        pairs[pos] = (uint32_t)s | ((uint32_t)(d & 255) << 16);
    }
}

// pass 2: one block per partition; LDS-window scatter then coalesced stream-out.
__global__ __launch_bounds__(256) void fill_part_kernel(const uint32_t* __restrict__ pairs,
                                                        const int* __restrict__ rowptr,
                                                        int* __restrict__ cursor,
                                                        int* __restrict__ col) {
    __shared__ int colw[FP_CAP];
    __shared__ int lcur[256];
    int p = blockIdx.x, t = threadIdx.x;
    int base = p << PART_SHIFT;
    int nlocal = min(256, N_NODES - base);
    int start = rowptr[base];
    int end = rowptr[base + nlocal];
    int cnt = end - start;
    if (cnt <= FP_CAP) {
        if (t < nlocal) lcur[t] = rowptr[base + t] - start;
        __syncthreads();
        for (int e = start + t; e < end; e += 256) {
            uint32_t v = __builtin_nontemporal_load(&pairs[e]);
            int pos = atomicAdd(&lcur[(v >> 16) & 255], 1);
            colw[pos] = (int)(v & 0xFFFFu);
        }
        __syncthreads();
        for (int e = t; e < cnt; e += 256) col[start + e] = colw[e];
    } else {
        for (int e = start + t; e < end; e += 256) {
            uint32_t v = __builtin_nontemporal_load(&pairs[e]);
            int pos = atomicAdd(&cursor[base + ((v >> 16) & 255)], 1);
            col[pos] = (int)(v & 0xFFFFu);
        }
    }
}

// ---------------- aggregation (bf16 h): z[i] = h[i] + sum_{j} h[j] ----------------
__global__ __launch_bounds__(256) void agg_kernel(const unsigned short* __restrict__ h,
                                                  const int* __restrict__ rowptr,
                                                  const int* __restrict__ col,
                                                  unsigned short* __restrict__ z) {
    int wid = threadIdx.x >> 6;
    int lane = threadIdx.x & 63;
    int i = blockIdx.x * 4 + wid;
    if (i >= N_NODES) return;
    int start = rowptr[i], end = rowptr[i + 1];
    const uint32_t* h32 = (const uint32_t*)h;
    uint32_t u = h32[(size_t)i * 64 + lane];
    float ax = __builtin_bit_cast(float, u << 16);
    float ay = __builtin_bit_cast(float, u & 0xffff0000u);
    float bx = 0.f, by = 0.f, cx = 0.f, cy = 0.f, dx = 0.f, dy = 0.f;
    int e = start;
    for (; e + 4 <= end; e += 4) {
        int j0 = col[e + 0], j1 = col[e + 1], j2 = col[e + 2], j3 = col[e + 3];
        uint32_t u0 = h32[(size_t)j0 * 64 + lane];
        uint32_t u1 = h32[(size_t)j1 * 64 + lane];
        uint32_t u2 = h32[(size_t)j2 * 64 + lane];
        uint32_t u3 = h32[(size_t)j3 * 64 + lane];
        ax += __builtin_bit_cast(float, u0 << 16);
        ay += __builtin_bit_cast(float, u0 & 0xffff0000u);
        bx += __builtin_bit_cast(float, u1 << 16);
        by += __builtin_bit_cast(float, u1 & 0xffff0000u);
        cx += __builtin_bit_cast(float, u2 << 16);
        cy += __builtin_bit_cast(float, u2 & 0xffff0000u);
        dx += __builtin_bit_cast(float, u3 << 16);
        dy += __builtin_bit_cast(float, u3 & 0xffff0000u);
    }
    for (; e < end; ++e) {
        uint32_t u0 = h32[(size_t)col[e] * 64 + lane];
        ax += __builtin_bit_cast(float, u0 << 16);
        ay += __builtin_bit_cast(float, u0 & 0xffff0000u);
    }
    ax += bx + cx + dx;
    ay += by + cy + dy;
    uint32_t o = (uint32_t)f2bf(ax) | ((uint32_t)f2bf(ay) << 16);
    ((uint32_t*)z)[(size_t)i * 64 + lane] = o;
}

// ---------------- fused layer (weight-stationary LDS) ----------------
// 512 thr / 8 waves / 128 rows per block. Wt1 staged in LDS for phase A,
// same buffer overwritten with Wt2 for phase B. Row strides padded to keep
// 16B alignment and <=2-way LDS banks (136 = 128+8, 264 = 256+8 elems).
__global__ __launch_bounds__(512) void fused_layer_kernel(
    const unsigned short* __restrict__ z, const unsigned short* __restrict__ Wt1,
    const float* __restrict__ b1, const unsigned short* __restrict__ Wt2,
    const float* __restrict__ b2, float* __restrict__ zin, float* __restrict__ stats, int M) {
    __shared__ unsigned short wbuf[256 * 136];  // 69632 B; also aliased as sred after phase B
    __shared__ unsigned short z1l[FL_RB * 264];  // 67584 B
    const int t = threadIdx.x;
    const int lane = t & 63;
    const int w = t >> 6;
    const int r = lane & 15, ks = lane >> 4;
    const int row0 = blockIdx.x * FL_RB + w * 16;
    const int arow = min(row0 + r, M - 1);
    // stage Wt1 [256][128] -> wbuf [256][136] (bulk coalesced)
    for (int i = t; i < 256 * 16; i += 512) {
        int row = i >> 4, seg = i & 15;
        *(short8v*)&wbuf[row * 136 + seg * 8] = *(const short8v*)&Wt1[(size_t)row * 128 + seg * 8];
    }
    short8v a4[4];
#pragma unroll
    for (int kk = 0; kk < 4; ++kk)
        a4[kk] = *(const short8v*)&z[(size_t)arow * HDIM + kk * 32 + ks * 8];
    __syncthreads();
    // phase A: z1l[w*16..+16][0..256) = relu(z @ W1 + b1)
#pragma unroll
    for (int n = 0; n < 16; ++n) {
        f32x4 acc = (f32x4){0.f, 0.f, 0.f, 0.f};
#pragma unroll
        for (int kk = 0; kk < 4; ++kk) {
            short8v bf = *(const short8v*)&wbuf[(n * 16 + r) * 136 + kk * 32 + ks * 8];
            acc = __builtin_amdgcn_mfma_f32_16x16x32_bf16(a4[kk], bf, acc, 0, 0, 0);
        }
        float bv = b1[n * 16 + r];
#pragma unroll
        for (int i = 0; i < 4; ++i) {
            float o = fmaxf(acc[i] + bv, 0.f);
            z1l[(w * 16 + ks * 4 + i) * 264 + n * 16 + r] = f2bf(o);
        }
    }
    __syncthreads();
    // stage Wt2 [128][256] -> wbuf [128][264]
    for (int i = t; i < 128 * 32; i += 512) {
        int row = i >> 5, seg = i & 31;
        *(short8v*)&wbuf[row * 264 + seg * 8] = *(const short8v*)&Wt2[(size_t)row * 256 + seg * 8];
    }
    __syncthreads();
    // phase B: zin[w*16..+16][0..128) = z1 @ W2 + b2
    f32x4 accb[8];
#pragma unroll
    for (int n = 0; n < 8; ++n) accb[n] = (f32x4){0.f, 0.f, 0.f, 0.f};
#pragma unroll
    for (int k0 = 0; k0 < 256; k0 += 32) {
        short8v a = *(const short8v*)&z1l[(w * 16 + r) * 264 + k0 + ks * 8];
#pragma unroll
        for (int n = 0; n < 8; ++n) {
            short8v bf = *(const short8v*)&wbuf[(n * 16 + r) * 264 + k0 + ks * 8];
            accb[n] = __builtin_amdgcn_mfma_f32_16x16x32_bf16(a, bf, accb[n], 0, 0, 0);
        }
    }
    __syncthreads();  // all wbuf reads done; alias as sred
    float* sred = (float*)wbuf;  // [8 waves][2][128]
#pragma unroll
    for (int n = 0; n < 8; ++n) {
        const int cc = n * 16 + r;
        const float bv = b2[cc];
        float s = 0.f, ss = 0.f;
#pragma unroll
        for (int i = 0; i < 4; ++i) {
            int row = row0 + ks * 4 + i;
            if (row < M) {
                float o = accb[n][i] + bv;
                s += o;
                ss += o * o;
                zin[(size_t)row * HDIM + cc] = o;
            }
        }
        s += __shfl_xor(s, 16);
        s += __shfl_xor(s, 32);
        ss += __shfl_xor(ss, 16);
        ss += __shfl_xor(ss, 32);
        if (ks == 0) {
            sred[(w * 2 + 0) * HDIM + cc] = s;
            sred[(w * 2 + 1) * HDIM + cc] = ss;
        }
    }
    __syncthreads();
    if (t < HDIM) {
        float s = 0.f, ss = 0.f;
#pragma unroll
        for (int ww = 0; ww < 8; ++ww) {
            s += sred[(ww * 2 + 0) * HDIM + t];
            ss += sred[(ww * 2 + 1) * HDIM + t];
        }
        atomicAdd(&stats[t], s);
        atomicAdd(&stats[HDIM + t], ss);
    }
}

// ---------------- plain MFMA GEMM (decoder stage 1) ----------------
template <int K, bool OUT_BF16, bool RELU>
__global__ __launch_bounds__(256) void mfma_gemm_kernel(const unsigned short* __restrict__ A,
                                                        const unsigned short* __restrict__ Wt,
                                                        const float* __restrict__ bias,
                                                        void* __restrict__ C, int M, int ldc) {
    const int lane = threadIdx.x & 63;
    const int w = threadIdx.x >> 6;
    const int row0 = blockIdx.y * 64 + w * 16;
    const int col0 = blockIdx.x * 64;
    const int r = lane & 15;
    const int ks = lane >> 4;
    const int arow = min(row0 + r, M - 1);
    f32x4 acc[4];
#pragma unroll
    for (int n = 0; n < 4; ++n) acc[n] = (f32x4){0.f, 0.f, 0.f, 0.f};
#pragma unroll
    for (int k0 = 0; k0 < K; k0 += 32) {
        short8v a = *(const short8v*)&A[(size_t)arow * K + k0 + ks * 8];
#pragma unroll
        for (int n = 0; n < 4; ++n) {
            short8v b = *(const short8v*)&Wt[(size_t)(col0 + n * 16 + r) * K + k0 + ks * 8];
            acc[n] = __builtin_amdgcn_mfma_f32_16x16x32_bf16(a, b, acc[n], 0, 0, 0);
        }
    }
#pragma unroll
    for (int n = 0; n < 4; ++n) {
        const int col = col0 + n * 16 + r;
        const float bv = bias[col];
#pragma unroll
        for (int i = 0; i < 4; ++i) {
            int row = row0 + ks * 4 + i;
            if (row < M) {
                float o = acc[n][i] + bv;
                if (RELU) o = fmaxf(o, 0.f);
                if (OUT_BF16)
                    ((unsigned short*)C)[(size_t)row * ldc + col] = f2bf(o);
                else
                    ((float*)C)[(size_t)row * ldc + col] = o;
            }
        }
    }
}

// ---------------- BN apply ----------------
__global__ void bnapply_kernel(const float* __restrict__ zin, const float* __restrict__ stats,
                               const float* __restrict__ gamma, const float* __restrict__ beta,
                               unsigned short* __restrict__ h) {
    __shared__ float ssc[2 * HDIM];
    int t = threadIdx.x;
    if (t < HDIM) {
        float mean = stats[t] * (1.f / N_NODES);
        float var = stats[HDIM + t] * (1.f / N_NODES) - mean * mean;
        float rstd = rsqrtf(fmaxf(var, 0.f) + BN_EPS);
        float s = gamma[t] * rstd;
        ssc[t] = s;
        ssc[HDIM + t] = beta[t] - mean * s;
    }
    __syncthreads();
    int idx = blockIdx.x * blockDim.x + threadIdx.x;
    if (idx >= N_NODES * HDIM / 4) return;
    float4 v = ((const float4*)zin)[idx];
    int c = (idx * 4) & 127;
    float o0 = fmaxf(v.x * ssc[c + 0] + ssc[HDIM + c + 0], 0.f);
    float o1 = fmaxf(v.y * ssc[c + 1] + ssc[HDIM + c + 1], 0.f);
    float o2 = fmaxf(v.z * ssc[c + 2] + ssc[HDIM + c + 2], 0.f);
    float o3 = fmaxf(v.w * ssc[c + 3] + ssc[HDIM + c + 3], 0.f);
    uint2 p;
    p.x = (uint32_t)f2bf(o0) | ((uint32_t)f2bf(o1) << 16);
    p.y = (uint32_t)f2bf(o2) | ((uint32_t)f2bf(o3) << 16);
    ((uint2*)h)[idx] = p;
}

// ---------------- decoder stage2 + loss: one thread per node ----------------
__global__ __launch_bounds__(256) void dec2_loss_kernel(
    const unsigned short* __restrict__ d1, const float* __restrict__ W2,
    const float* __restrict__ b2, const float* __restrict__ x, const void* __restrict__ mask,
    const int* __restrict__ flag, float* __restrict__ recon, float* __restrict__ acc) {
    __shared__ float w2s[HDIM * 3];
    for (int t = threadIdx.x; t < HDIM * 3; t += 256) w2s[t] = W2[t];
    __syncthreads();
    int i = blockIdx.x * 256 + threadIdx.x;
    int fl = *flag;
    float lsum = 0.f, lcnt = 0.f;
    if (i < N_NODES) {
        float s0 = 0.f, s1 = 0.f, s2 = 0.f;
        const unsigned short* row = &d1[(size_t)i * HDIM];
#pragma unroll
        for (int k0 = 0; k0 < HDIM; k0 += 8) {
            short8v v = *(const short8v*)&row[k0];
#pragma unroll
            for (int q = 0; q < 8; ++q) {
                float a = bf2f((unsigned short)v[q]);
                s0 = fmaf(a, w2s[(k0 + q) * 3 + 0], s0);
                s1 = fmaf(a, w2s[(k0 + q) * 3 + 1], s1);
                s2 = fmaf(a, w2s[(k0 + q) * 3 + 2], s2);
            }
        }
        float r0 = s0 + b2[0], r1 = s1 + b2[1], r2 = s2 + b2[2];
        recon[(size_t)i * 3 + 0] = r0;
        recon[(size_t)i * 3 + 1] = r1;
        recon[(size_t)i * 3 + 2] = r2;
        if (read_mask(mask, i, fl)) {
            float rn = fmaxf(sqrtf(r0 * r0 + r1 * r1 + r2 * r2), 1e-12f);
            float x0 = x[i * 3 + 0], x1 = x[i * 3 + 1], x2 = x[i * 3 + 2];
            float xn = fmaxf(sqrtf(x0 * x0 + x1 * x1 + x2 * x2), 1e-12f);
            float cs = (r0 * x0 + r1 * x1 + r2 * x2) / (rn * xn);
            float d = 1.f - cs;
            lsum = d * d;
            lcnt = 1.f;
        }
    }
#pragma unroll
    for (int o = 32; o > 0; o >>= 1) {
        lsum += __shfl_xor(lsum, o);
        lcnt += __shfl_xor(lcnt, o);
    }
    if ((threadIdx.x & 63) == 0 && lcnt != 0.f) {
        atomicAdd(&acc[0], lsum);
        atomicAdd(&acc[1], lcnt);
    }
}

__global__ void finalize_kernel(const float* __restrict__ acc, float* __restrict__ out) {
    out[0] = acc[0] / fmaxf(acc[1], 1.f);
}

// ---------------- launcher ----------------
extern "C" void kernel_launch(void* const* d_in, const int* in_sizes, int n_in, void* d_out,
                              int out_size, void* d_ws, size_t ws_size, hipStream_t stream) {
    const float* x = (const float*)d_in[0];
    const int* ei = (const int*)d_in[1];
    const int* src = ei;
    const int* dst = ei + N_EDGES;
    const void* mask = d_in[3];
    const float* tok = (const float*)d_in[4];
    const float* eW = (const float*)d_in[5];
    const float* eb = (const float*)d_in[6];
    const float* W1 = (const float*)d_in[7];
    const float* b1 = (const float*)d_in[8];
    const float* W2 = (const float*)d_in[9];
    const float* b2 = (const float*)d_in[10];
    const float* gm = (const float*)d_in[11];
    const float* bt = (const float*)d_in[12];
    const float* dW1 = (const float*)d_in[13];
    const float* db1 = (const float*)d_in[14];
    const float* dW2 = (const float*)d_in[15];
    const float* db2 = (const float*)d_in[16];
    float* out = (float*)d_out;

    char* ws = (char*)d_ws;
    size_t off = 0;
    auto alloc = [&](size_t bytes) -> void* {
        void* p = ws + off;
        off = (off + bytes + 255) & ~(size_t)255;
        return p;
    };
    unsigned short* h = (unsigned short*)alloc((size_t)N_NODES * HDIM * 2);
    unsigned short* z = (unsigned short*)alloc((size_t)N_NODES * HDIM * 2);
    unsigned short* z1 = (unsigned short*)alloc((size_t)N_NODES * 2 * HDIM * 2);
    float* zin = (float*)alloc((size_t)N_NODES * HDIM * 4);
    unsigned short* Wt1 = (unsigned short*)alloc((size_t)L_LAYERS * HDIM * 2 * HDIM * 2);
    unsigned short* Wt2 = (unsigned short*)alloc((size_t)L_LAYERS * HDIM * 2 * HDIM * 2);
    unsigned short* Wtd = (unsigned short*)alloc((size_t)HDIM * HDIM * 2);
    int* deg = (int*)alloc((size_t)N_NODES * 4);
    int* rowptr = (int*)alloc((size_t)(N_NODES + 1) * 4);
    int* cursor = (int*)alloc((size_t)N_NODES * 4);
    int* col = (int*)alloc((size_t)N_EDGES * 4);
    uint32_t* pairs = (uint32_t*)alloc((size_t)N_EDGES * 4);
    int* bsum = (int*)alloc((size_t)SCAN_NB * 4);
    int* ebsum = (int*)alloc((size_t)SCAN_NB * 4);
    int* pcursor = (int*)alloc((size_t)NPART * 4);
    float* stats = (float*)alloc((size_t)L_LAYERS * 2 * HDIM * 4);
    float* lacc = (float*)alloc(8);
    int* flag = (int*)alloc(4);

    detect_mask_kernel<<<1, 256, 0, stream>>>((const uint32_t*)mask, flag);
    wprep_all_kernel<<<dim3(32, 9), 256, 0, stream>>>(W1, W2, dW1, Wt1, Wt2, Wtd);
    embed_kernel<<<(N_NODES * HDIM + 255) / 256, 256, 0, stream>>>(x, mask, flag, tok, eW, eb, h);

    hipMemsetAsync(deg, 0, (size_t)N_NODES * 4, stream);
    hipMemsetAsync(stats, 0, (size_t)L_LAYERS * 2 * HDIM * 4, stream);
    hipMemsetAsync(lacc, 0, 8, stream);
    deg_kernel<<<(N_EDGES + 255) / 256, 256, 0, stream>>>(dst, deg);
    scan_partial_kernel<<<SCAN_NB, 256, 0, stream>>>(deg, bsum);
    scan_bsum_kernel<<<1, 128, 0, stream>>>(bsum, ebsum, rowptr);
    scan_final_kernel<<<SCAN_NB, 256, 0, stream>>>(deg, ebsum, rowptr, cursor);
    pcur_init_kernel<<<1, 256, 0, stream>>>(rowptr, pcursor);
    partition_kernel<<<256, 256, 0, stream>>>(src, dst, pcursor, pairs);
    fill_part_kernel<<<NPART, 256, 0, stream>>>(pairs, rowptr, cursor, col);

    for (int l = 0; l < L_LAYERS; ++l) {
        float* lstats = stats + (size_t)l * 2 * HDIM;
        agg_kernel<<<(N_NODES + 3) / 4, 256, 0, stream>>>(h, rowptr, col, z);
        fused_layer_kernel<<<(N_NODES + FL_RB - 1) / FL_RB, 512, 0, stream>>>(
            z, Wt1 + (size_t)l * HDIM * 2 * HDIM, b1 + (size_t)l * 2 * HDIM,
            Wt2 + (size_t)l * HDIM * 2 * HDIM, b2 + (size_t)l * HDIM, zin, lstats, N_NODES);
        bnapply_kernel<<<(N_NODES * HDIM / 4 + 255) / 256, 256, 0, stream>>>(
            zin, lstats, gm + l * HDIM, bt + l * HDIM, h);
    }

    mfma_gemm_kernel<HDIM, true, true><<<dim3(2, 782), 256, 0, stream>>>(h, Wtd, db1, z1, N_NODES,
                                                                         HDIM);
    dec2_loss_kernel<<<(N_NODES + 255) / 256, 256, 0, stream>>>(z1, dW2, db2, x, mask, flag,
                                                                out + 1, lacc);
    finalize_kernel<<<1, 1, 0, stream>>>(lacc, out);
}

// Round 12
// 542.207 us; speedup vs baseline: 2.9590x; 1.1189x over previous
//
#include <hip/hip_runtime.h>
#include <cstdint>

#define N_NODES 50000
#define N_EDGES 1600000
#define HDIM 128
#define L_LAYERS 4
#define BN_EPS 1e-5f
#define NPART 196
#define PART_SHIFT 8
#define PB_CHUNK 6250  // N_EDGES / 256 exactly
#define FP_CAP 16384
#define FL_RB 128

typedef __attribute__((ext_vector_type(8))) short short8v;
typedef __attribute__((ext_vector_type(4))) float f32x4;

__device__ __forceinline__ unsigned short f2bf(float f) {
    uint32_t u = __builtin_bit_cast(uint32_t, f);
    u += 0x7fff + ((u >> 16) & 1);
    return (unsigned short)(u >> 16);
}
__device__ __forceinline__ float bf2f(unsigned short b) {
    return __builtin_bit_cast(float, (uint32_t)b << 16);
}

// ---------------- mask layout detection ----------------
__global__ void detect_mask_kernel(const uint32_t* __restrict__ mw, int* __restrict__ flag) {
    __shared__ int f;
    if (threadIdx.x == 0) f = 0;
    __syncthreads();
    int found = 0;
    for (int i = threadIdx.x; i < 12500; i += blockDim.x)
        if (mw[i] > 1u) found = 1;
    if (found) f = 1;
    __syncthreads();
    if (threadIdx.x == 0) *flag = f;
}

__device__ __forceinline__ int read_mask(const void* mask, int i, int bytelayout) {
    if (bytelayout) return ((const unsigned char*)mask)[i] != 0;
    return ((const int*)mask)[i] != 0;
}

// ---------------- unified weight prep: Wt[n][k] = bf16(W[k][n]) ----------------
__global__ void wprep_all_kernel(const float* __restrict__ W1, const float* __restrict__ W2,
                                 const float* __restrict__ dW1, unsigned short* __restrict__ Wt1,
                                 unsigned short* __restrict__ Wt2,
                                 unsigned short* __restrict__ Wtd) {
    int seg = blockIdx.y;
    const float* W;
    unsigned short* Wt;
    int K, nshift;
    if (seg < 4) {
        W = W1 + (size_t)seg * HDIM * 2 * HDIM;
        Wt = Wt1 + (size_t)seg * HDIM * 2 * HDIM;
        K = HDIM;
        nshift = 8;
    } else if (seg < 8) {
        int l = seg - 4;
        W = W2 + (size_t)l * 2 * HDIM * HDIM;
        Wt = Wt2 + (size_t)l * 2 * HDIM * HDIM;
        K = 2 * HDIM;
        nshift = 7;
    } else {
        W = dW1;
        Wt = Wtd;
        K = HDIM;
        nshift = 7;
    }
    int total = K << nshift;
    for (int idx = blockIdx.x * 256 + threadIdx.x; idx < total; idx += gridDim.x * 256) {
        int k = idx >> nshift, n = idx & ((1 << nshift) - 1);
        Wt[(size_t)n * K + k] = f2bf(W[idx]);
    }
}

// ---------------- embed ----------------
__global__ void embed_kernel(const float* __restrict__ x, const void* __restrict__ mask,
                             const int* __restrict__ flag, const float* __restrict__ tok,
                             const float* __restrict__ W, const float* __restrict__ b,
                             unsigned short* __restrict__ h) {
    int idx = blockIdx.x * blockDim.x + threadIdx.x;
    if (idx >= N_NODES * HDIM) return;
    int i = idx >> 7, c = idx & 127;
    int fl = *flag;
    int m = read_mask(mask, i, fl);
    float x0 = m ? tok[0] : x[i * 3 + 0];
    float x1 = m ? tok[1] : x[i * 3 + 1];
    float x2 = m ? tok[2] : x[i * 3 + 2];
    h[idx] = f2bf(x0 * W[c] + x1 * W[HDIM + c] + x2 * W[2 * HDIM + c] + b[c]);
}

// ---------------- CSR build (partition-first, no per-node deg kernel) ----------------
// step 1: per-partition edge counts (LDS hist -> 196 global atomics per block)
__global__ __launch_bounds__(256) void pcount_kernel(const int* __restrict__ dst,
                                                     int* __restrict__ pcount) {
    __shared__ int hist[NPART];
    for (int i = threadIdx.x; i < NPART; i += 256) hist[i] = 0;
    __syncthreads();
    int lo = blockIdx.x * PB_CHUNK;
    for (int i = threadIdx.x; i < PB_CHUNK; i += 256)
        atomicAdd(&hist[dst[lo + i] >> PART_SHIFT], 1);
    __syncthreads();
    for (int i = threadIdx.x; i < NPART; i += 256)
        if (hist[i]) atomicAdd(&pcount[i], hist[i]);
}

// step 2: scan 196 counts -> poff / pcursor; rowptr[N]
__global__ __launch_bounds__(256) void pscan_kernel(const int* __restrict__ pcount,
                                                    int* __restrict__ poff,
                                                    int* __restrict__ pcursor,
                                                    int* __restrict__ rowptr) {
    __shared__ int sh[256];
    int t = threadIdx.x;
    int v = (t < NPART) ? pcount[t] : 0;
    sh[t] = v;
    __syncthreads();
    for (int o = 1; o < 256; o <<= 1) {
        int u = (t >= o) ? sh[t - o] : 0;
        __syncthreads();
        sh[t] += u;
        __syncthreads();
    }
    if (t < NPART) {
        int e = sh[t] - v;
        poff[t] = e;
        pcursor[t] = e;
    }
    if (t == NPART - 1) {
        poff[NPART] = sh[t];
        rowptr[N_NODES] = sh[t];
    }
}

// step 3: radix-partition edges by dst>>8 into packed u32 (src | d_local<<16)
__global__ __launch_bounds__(256) void partition_kernel(const int* __restrict__ src,
                                                        const int* __restrict__ dst,
                                                        int* __restrict__ pcursor,
                                                        uint32_t* __restrict__ pairs) {
    __shared__ int hist[NPART];
    __shared__ int off[NPART];
    int b = blockIdx.x, t = threadIdx.x;
    int lo = b * PB_CHUNK;
    for (int i = t; i < NPART; i += 256) hist[i] = 0;
    __syncthreads();
    for (int i = t; i < PB_CHUNK; i += 256) {
        int d = dst[lo + i];
        atomicAdd(&hist[d >> PART_SHIFT], 1);
    }
    __syncthreads();
    for (int i = t; i < NPART; i += 256) off[i] = atomicAdd(&pcursor[i], hist[i]);
    __syncthreads();
    for (int i = t; i < PB_CHUNK; i += 256) {
        int d = dst[lo + i];
        int s = src[lo + i];
        int pos = atomicAdd(&off[d >> PART_SHIFT], 1);
        pairs[pos] = (uint32_t)s | ((uint32_t)(d & 255) << 16);
    }
}

// step 4: one block per partition. Local deg hist -> local scan -> write rowptr
// slice; LDS-window scatter; coalesced stream-out (write amp = 1x).
__global__ __launch_bounds__(256) void fill_part_kernel(const uint32_t* __restrict__ pairs,
                                                        const int* __restrict__ poff,
                                                        int* __restrict__ rowptr,
                                                        int* __restrict__ col) {
    __shared__ int colw[FP_CAP];
    __shared__ int lscan[256];
    __shared__ int lcur[256];
    int p = blockIdx.x, t = threadIdx.x;
    int base = p << PART_SHIFT;
    int nlocal = min(256, N_NODES - base);
    int pstart = poff[p], pend = poff[p + 1];
    int cnt = pend - pstart;
    lcur[t] = 0;
    __syncthreads();
    for (int e = pstart + t; e < pend; e += 256)
        atomicAdd(&lcur[(__builtin_nontemporal_load(&pairs[e]) >> 16) & 255], 1);
    __syncthreads();
    int v = lcur[t];
    lscan[t] = v;
    __syncthreads();
    for (int o = 1; o < 256; o <<= 1) {
        int u = (t >= o) ? lscan[t - o] : 0;
        __syncthreads();
        lscan[t] += u;
        __syncthreads();
    }
    int excl = lscan[t] - v;
    if (t < nlocal) rowptr[base + t] = pstart + excl;
    lcur[t] = excl;
    __syncthreads();
    if (cnt <= FP_CAP) {
        for (int e = pstart + t; e < pend; e += 256) {
            uint32_t pv = pairs[e];
            int pos = atomicAdd(&lcur[(pv >> 16) & 255], 1);
            colw[pos] = (int)(pv & 0xFFFFu);
        }
        __syncthreads();
        for (int e = t; e < cnt; e += 256) col[pstart + e] = colw[e];
    } else {  // statistically unreachable fallback, keeps correctness unconditional
        for (int e = pstart + t; e < pend; e += 256) {
            uint32_t pv = pairs[e];
            int pos = atomicAdd(&lcur[(pv >> 16) & 255], 1);
            col[pstart + pos] = (int)(pv & 0xFFFFu);
        }
    }
}

// ---------------- aggregation (bf16 h): z[i] = h[i] + sum_{j} h[j] ----------------
__global__ __launch_bounds__(256) void agg_kernel(const unsigned short* __restrict__ h,
                                                  const int* __restrict__ rowptr,
                                                  const int* __restrict__ col,
                                                  unsigned short* __restrict__ z) {
    int wid = threadIdx.x >> 6;
    int lane = threadIdx.x & 63;
    int i = blockIdx.x * 4 + wid;
    if (i >= N_NODES) return;
    int start = rowptr[i], end = rowptr[i + 1];
    const uint32_t* h32 = (const uint32_t*)h;
    uint32_t u = h32[(size_t)i * 64 + lane];
    float ax = __builtin_bit_cast(float, u << 16);
    float ay = __builtin_bit_cast(float, u & 0xffff0000u);
    float bx = 0.f, by = 0.f, cx = 0.f, cy = 0.f, dx = 0.f, dy = 0.f;
    int e = start;
    for (; e + 4 <= end; e += 4) {
        int j0 = col[e + 0], j1 = col[e + 1], j2 = col[e + 2], j3 = col[e + 3];
        uint32_t u0 = h32[(size_t)j0 * 64 + lane];
        uint32_t u1 = h32[(size_t)j1 * 64 + lane];
        uint32_t u2 = h32[(size_t)j2 * 64 + lane];
        uint32_t u3 = h32[(size_t)j3 * 64 + lane];
        ax += __builtin_bit_cast(float, u0 << 16);
        ay += __builtin_bit_cast(float, u0 & 0xffff0000u);
        bx += __builtin_bit_cast(float, u1 << 16);
        by += __builtin_bit_cast(float, u1 & 0xffff0000u);
        cx += __builtin_bit_cast(float, u2 << 16);
        cy += __builtin_bit_cast(float, u2 & 0xffff0000u);
        dx += __builtin_bit_cast(float, u3 << 16);
        dy += __builtin_bit_cast(float, u3 & 0xffff0000u);
    }
    for (; e < end; ++e) {
        uint32_t u0 = h32[(size_t)col[e] * 64 + lane];
        ax += __builtin_bit_cast(float, u0 << 16);
        ay += __builtin_bit_cast(float, u0 & 0xffff0000u);
    }
    ax += bx + cx + dx;
    ay += by + cy + dy;
    uint32_t o = (uint32_t)f2bf(ax) | ((uint32_t)f2bf(ay) << 16);
    ((uint32_t*)z)[(size_t)i * 64 + lane] = o;
}

// ---------------- fused layer (weight-stationary LDS) ----------------
__global__ __launch_bounds__(512) void fused_layer_kernel(
    const unsigned short* __restrict__ z, const unsigned short* __restrict__ Wt1,
    const float* __restrict__ b1, const unsigned short* __restrict__ Wt2,
    const float* __restrict__ b2, float* __restrict__ zin, float* __restrict__ stats, int M) {
    __shared__ unsigned short wbuf[256 * 136];   // 69632 B; aliased as sred after phase B
    __shared__ unsigned short z1l[FL_RB * 264];  // 67584 B
    const int t = threadIdx.x;
    const int lane = t & 63;
    const int w = t >> 6;
    const int r = lane & 15, ks = lane >> 4;
    const int row0 = blockIdx.x * FL_RB + w * 16;
    const int arow = min(row0 + r, M - 1);
    for (int i = t; i < 256 * 16; i += 512) {
        int row = i >> 4, seg = i & 15;
        *(short8v*)&wbuf[row * 136 + seg * 8] = *(const short8v*)&Wt1[(size_t)row * 128 + seg * 8];
    }
    short8v a4[4];
#pragma unroll
    for (int kk = 0; kk < 4; ++kk)
        a4[kk] = *(const short8v*)&z[(size_t)arow * HDIM + kk * 32 + ks * 8];
    __syncthreads();
#pragma unroll
    for (int n = 0; n < 16; ++n) {
        f32x4 acc = (f32x4){0.f, 0.f, 0.f, 0.f};
#pragma unroll
        for (int kk = 0; kk < 4; ++kk) {
            short8v bf = *(const short8v*)&wbuf[(n * 16 + r) * 136 + kk * 32 + ks * 8];
            acc = __builtin_amdgcn_mfma_f32_16x16x32_bf16(a4[kk], bf, acc, 0, 0, 0);
        }
        float bv = b1[n * 16 + r];
#pragma unroll
        for (int i = 0; i < 4; ++i) {
            float o = fmaxf(acc[i] + bv, 0.f);
            z1l[(w * 16 + ks * 4 + i) * 264 + n * 16 + r] = f2bf(o);
        }
    }
    __syncthreads();
    for (int i = t; i < 128 * 32; i += 512) {
        int row = i >> 5, seg = i & 31;
        *(short8v*)&wbuf[row * 264 + seg * 8] = *(const short8v*)&Wt2[(size_t)row * 256 + seg * 8];
    }
    __syncthreads();
    f32x4 accb[8];
#pragma unroll
    for (int n = 0; n < 8; ++n) accb[n] = (f32x4){0.f, 0.f, 0.f, 0.f};
#pragma unroll
    for (int k0 = 0; k0 < 256; k0 += 32) {
        short8v a = *(const short8v*)&z1l[(w * 16 + r) * 264 + k0 + ks * 8];
#pragma unroll
        for (int n = 0; n < 8; ++n) {
            short8v bf = *(const short8v*)&wbuf[(n * 16 + r) * 264 + k0 + ks * 8];
            accb[n] = __builtin_amdgcn_mfma_f32_16x16x32_bf16(a, bf, accb[n], 0, 0, 0);
        }
    }
    __syncthreads();
    float* sred = (float*)wbuf;
#pragma unroll
    for (int n = 0; n < 8; ++n) {
        const int cc = n * 16 + r;
        const float bv = b2[cc];
        float s = 0.f, ss = 0.f;
#pragma unroll
        for (int i = 0; i < 4; ++i) {
            int row = row0 + ks * 4 + i;
            if (row < M) {
                float o = accb[n][i] + bv;
                s += o;
                ss += o * o;
                zin[(size_t)row * HDIM + cc] = o;
            }
        }
        s += __shfl_xor(s, 16);
        s += __shfl_xor(s, 32);
        ss += __shfl_xor(ss, 16);
        ss += __shfl_xor(ss, 32);
        if (ks == 0) {
            sred[(w * 2 + 0) * HDIM + cc] = s;
            sred[(w * 2 + 1) * HDIM + cc] = ss;
        }
    }
    __syncthreads();
    if (t < HDIM) {
        float s = 0.f, ss = 0.f;
#pragma unroll
        for (int ww = 0; ww < 8; ++ww) {
            s += sred[(ww * 2 + 0) * HDIM + t];
            ss += sred[(ww * 2 + 1) * HDIM + t];
        }
        atomicAdd(&stats[t], s);
        atomicAdd(&stats[HDIM + t], ss);
    }
}

// ---------------- plain MFMA GEMM (decoder stage 1) ----------------
template <int K, bool OUT_BF16, bool RELU>
__global__ __launch_bounds__(256) void mfma_gemm_kernel(const unsigned short* __restrict__ A,
                                                        const unsigned short* __restrict__ Wt,
                                                        const float* __restrict__ bias,
                                                        void* __restrict__ C, int M, int ldc) {
    const int lane = threadIdx.x & 63;
    const int w = threadIdx.x >> 6;
    const int row0 = blockIdx.y * 64 + w * 16;
    const int col0 = blockIdx.x * 64;
    const int r = lane & 15;
    const int ks = lane >> 4;
    const int arow = min(row0 + r, M - 1);
    f32x4 acc[4];
#pragma unroll
    for (int n = 0; n < 4; ++n) acc[n] = (f32x4){0.f, 0.f, 0.f, 0.f};
#pragma unroll
    for (int k0 = 0; k0 < K; k0 += 32) {
        short8v a = *(const short8v*)&A[(size_t)arow * K + k0 + ks * 8];
#pragma unroll
        for (int n = 0; n < 4; ++n) {
            short8v b = *(const short8v*)&Wt[(size_t)(col0 + n * 16 + r) * K + k0 + ks * 8];
            acc[n] = __builtin_amdgcn_mfma_f32_16x16x32_bf16(a, b, acc[n], 0, 0, 0);
        }
    }
#pragma unroll
    for (int n = 0; n < 4; ++n) {
        const int col = col0 + n * 16 + r;
        const float bv = bias[col];
#pragma unroll
        for (int i = 0; i < 4; ++i) {
            int row = row0 + ks * 4 + i;
            if (row < M) {
                float o = acc[n][i] + bv;
                if (RELU) o = fmaxf(o, 0.f);
                if (OUT_BF16)
                    ((unsigned short*)C)[(size_t)row * ldc + col] = f2bf(o);
                else
                    ((float*)C)[(size_t)row * ldc + col] = o;
            }
        }
    }
}

// ---------------- BN apply ----------------
__global__ void bnapply_kernel(const float* __restrict__ zin, const float* __restrict__ stats,
                               const float* __restrict__ gamma, const float* __restrict__ beta,
                               unsigned short* __restrict__ h) {
    __shared__ float ssc[2 * HDIM];
    int t = threadIdx.x;
    if (t < HDIM) {
        float mean = stats[t] * (1.f / N_NODES);
        float var = stats[HDIM + t] * (1.f / N_NODES) - mean * mean;
        float rstd = rsqrtf(fmaxf(var, 0.f) + BN_EPS);
        float s = gamma[t] * rstd;
        ssc[t] = s;
        ssc[HDIM + t] = beta[t] - mean * s;
    }
    __syncthreads();
    int idx = blockIdx.x * blockDim.x + threadIdx.x;
    if (idx >= N_NODES * HDIM / 4) return;
    float4 v = ((const float4*)zin)[idx];
    int c = (idx * 4) & 127;
    float o0 = fmaxf(v.x * ssc[c + 0] + ssc[HDIM + c + 0], 0.f);
    float o1 = fmaxf(v.y * ssc[c + 1] + ssc[HDIM + c + 1], 0.f);
    float o2 = fmaxf(v.z * ssc[c + 2] + ssc[HDIM + c + 2], 0.f);
    float o3 = fmaxf(v.w * ssc[c + 3] + ssc[HDIM + c + 3], 0.f);
    uint2 p;
    p.x = (uint32_t)f2bf(o0) | ((uint32_t)f2bf(o1) << 16);
    p.y = (uint32_t)f2bf(o2) | ((uint32_t)f2bf(o3) << 16);
    ((uint2*)h)[idx] = p;
}

// ---------------- decoder stage2 + loss: one thread per node ----------------
__global__ __launch_bounds__(256) void dec2_loss_kernel(
    const unsigned short* __restrict__ d1, const float* __restrict__ W2,
    const float* __restrict__ b2, const float* __restrict__ x, const void* __restrict__ mask,
    const int* __restrict__ flag, float* __restrict__ recon, float* __restrict__ acc) {
    __shared__ float w2s[HDIM * 3];
    for (int t = threadIdx.x; t < HDIM * 3; t += 256) w2s[t] = W2[t];
    __syncthreads();
    int i = blockIdx.x * 256 + threadIdx.x;
    int fl = *flag;
    float lsum = 0.f, lcnt = 0.f;
    if (i < N_NODES) {
        float s0 = 0.f, s1 = 0.f, s2 = 0.f;
        const unsigned short* row = &d1[(size_t)i * HDIM];
#pragma unroll
        for (int k0 = 0; k0 < HDIM; k0 += 8) {
            short8v v = *(const short8v*)&row[k0];
#pragma unroll
            for (int q = 0; q < 8; ++q) {
                float a = bf2f((unsigned short)v[q]);
                s0 = fmaf(a, w2s[(k0 + q) * 3 + 0], s0);
                s1 = fmaf(a, w2s[(k0 + q) * 3 + 1], s1);
                s2 = fmaf(a, w2s[(k0 + q) * 3 + 2], s2);
            }
        }
        float r0 = s0 + b2[0], r1 = s1 + b2[1], r2 = s2 + b2[2];
        recon[(size_t)i * 3 + 0] = r0;
        recon[(size_t)i * 3 + 1] = r1;
        recon[(size_t)i * 3 + 2] = r2;
        if (read_mask(mask, i, fl)) {
            float rn = fmaxf(sqrtf(r0 * r0 + r1 * r1 + r2 * r2), 1e-12f);
            float x0 = x[i * 3 + 0], x1 = x[i * 3 + 1], x2 = x[i * 3 + 2];
            float xn = fmaxf(sqrtf(x0 * x0 + x1 * x1 + x2 * x2), 1e-12f);
            float cs = (r0 * x0 + r1 * x1 + r2 * x2) / (rn * xn);
            float d = 1.f - cs;
            lsum = d * d;
            lcnt = 1.f;
        }
    }
#pragma unroll
    for (int o = 32; o > 0; o >>= 1) {
        lsum += __shfl_xor(lsum, o);
        lcnt += __shfl_xor(lcnt, o);
    }
    if ((threadIdx.x & 63) == 0 && lcnt != 0.f) {
        atomicAdd(&acc[0], lsum);
        atomicAdd(&acc[1], lcnt);
    }
}

__global__ void finalize_kernel(const float* __restrict__ acc, float* __restrict__ out) {
    out[0] = acc[0] / fmaxf(acc[1], 1.f);
}

// ---------------- launcher ----------------
extern "C" void kernel_launch(void* const* d_in, const int* in_sizes, int n_in, void* d_out,
                              int out_size, void* d_ws, size_t ws_size, hipStream_t stream) {
    const float* x = (const float*)d_in[0];
    const int* ei = (const int*)d_in[1];
    const int* src = ei;
    const int* dst = ei + N_EDGES;
    const void* mask = d_in[3];
    const float* tok = (const float*)d_in[4];
    const float* eW = (const float*)d_in[5];
    const float* eb = (const float*)d_in[6];
    const float* W1 = (const float*)d_in[7];
    const float* b1 = (const float*)d_in[8];
    const float* W2 = (const float*)d_in[9];
    const float* b2 = (const float*)d_in[10];
    const float* gm = (const float*)d_in[11];
    const float* bt = (const float*)d_in[12];
    const float* dW1 = (const float*)d_in[13];
    const float* db1 = (const float*)d_in[14];
    const float* dW2 = (const float*)d_in[15];
    const float* db2 = (const float*)d_in[16];
    float* out = (float*)d_out;

    char* ws = (char*)d_ws;
    size_t off = 0;
    auto alloc = [&](size_t bytes) -> void* {
        void* p = ws + off;
        off = (off + bytes + 255) & ~(size_t)255;
        return p;
    };
    unsigned short* h = (unsigned short*)alloc((size_t)N_NODES * HDIM * 2);
    unsigned short* z = (unsigned short*)alloc((size_t)N_NODES * HDIM * 2);
    unsigned short* z1 = (unsigned short*)alloc((size_t)N_NODES * 2 * HDIM * 2);
    float* zin = (float*)alloc((size_t)N_NODES * HDIM * 4);
    unsigned short* Wt1 = (unsigned short*)alloc((size_t)L_LAYERS * HDIM * 2 * HDIM * 2);
    unsigned short* Wt2 = (unsigned short*)alloc((size_t)L_LAYERS * HDIM * 2 * HDIM * 2);
    unsigned short* Wtd = (unsigned short*)alloc((size_t)HDIM * HDIM * 2);
    int* rowptr = (int*)alloc((size_t)(N_NODES + 1) * 4);
    int* col = (int*)alloc((size_t)N_EDGES * 4);
    uint32_t* pairs = (uint32_t*)alloc((size_t)N_EDGES * 4);
    int* pcount = (int*)alloc((size_t)NPART * 4);
    int* poff = (int*)alloc((size_t)(NPART + 1) * 4);
    int* pcursor = (int*)alloc((size_t)NPART * 4);
    float* stats = (float*)alloc((size_t)L_LAYERS * 2 * HDIM * 4);
    float* lacc = (float*)alloc(8);
    int* flag = (int*)alloc(4);

    detect_mask_kernel<<<1, 256, 0, stream>>>((const uint32_t*)mask, flag);
    wprep_all_kernel<<<dim3(32, 9), 256, 0, stream>>>(W1, W2, dW1, Wt1, Wt2, Wtd);
    embed_kernel<<<(N_NODES * HDIM + 255) / 256, 256, 0, stream>>>(x, mask, flag, tok, eW, eb, h);

    hipMemsetAsync(pcount, 0, (size_t)NPART * 4, stream);
    hipMemsetAsync(stats, 0, (size_t)L_LAYERS * 2 * HDIM * 4, stream);
    hipMemsetAsync(lacc, 0, 8, stream);
    pcount_kernel<<<256, 256, 0, stream>>>(dst, pcount);
    pscan_kernel<<<1, 256, 0, stream>>>(pcount, poff, pcursor, rowptr);
    partition_kernel<<<256, 256, 0, stream>>>(src, dst, pcursor, pairs);
    fill_part_kernel<<<NPART, 256, 0, stream>>>(pairs, poff, rowptr, col);

    for (int l = 0; l < L_LAYERS; ++l) {
        float* lstats = stats + (size_t)l * 2 * HDIM;
        agg_kernel<<<(N_NODES + 3) / 4, 256, 0, stream>>>(h, rowptr, col, z);
        fused_layer_kernel<<<(N_NODES + FL_RB - 1) / FL_RB, 512, 0, stream>>>(
            z, Wt1 + (size_t)l * HDIM * 2 * HDIM, b1 + (size_t)l * 2 * HDIM,
            Wt2 + (size_t)l * HDIM * 2 * HDIM, b2 + (size_t)l * HDIM, zin, lstats, N_NODES);
        bnapply_kernel<<<(N_NODES * HDIM / 4 + 255) / 256, 256, 0, stream>>>(
            zin, lstats, gm + l * HDIM, bt + l * HDIM, h);
    }

    mfma_gemm_kernel<HDIM, true, true><<<dim3(2, 782), 256, 0, stream>>>(h, Wtd, db1, z1, N_NODES,
                                                                         HDIM);
    dec2_loss_kernel<<<(N_NODES + 255) / 256, 256, 0, stream>>>(z1, dW2, db2, x, mask, flag,
                                                                out + 1, lacc);
    finalize_kernel<<<1, 1, 0, stream>>>(lacc, out);
}